// Round 8
// baseline (450.826 us; speedup 1.0000x reference)
//
#include <hip/hip_runtime.h>
#include <hip/hip_fp16.h>

#define BATCH_N   2048
#define EMB_D_    768
#define PROJ_D_   128
#define QUEUE_N   32768
#define HARD_K_   512
static constexpr float INV_T = 1.0f / 0.07f;
static constexpr float WLO   = 0.12f;    // hist window low (512th opp val ~0.164 +/- 0.002)

typedef __attribute__((ext_vector_type(8))) short short8;
typedef __attribute__((ext_vector_type(4))) short short4v;
typedef __attribute__((ext_vector_type(4))) float f32x4;

__device__ __forceinline__ unsigned short f2bf(float f) {
    unsigned u = __float_as_uint(f);
    unsigned r = u + 0x7fffu + ((u >> 16) & 1u);   // RNE
    return (unsigned short)(r >> 16);
}
__device__ __forceinline__ float bf2f(short s) {
    return __uint_as_float(((unsigned)(unsigned short)s) << 16);
}
__device__ __forceinline__ int opp_of(int mylab, const int* __restrict__ qcnt) {
    const int same = (mylab == 0) ? qcnt[0] : ((mylab == 1) ? qcnt[1] : 0);
    return qcnt[2] - same;
}

// ---------------------------------------------------------------------------
// bf16 MFMA NT GEMM, K=128 in LDS, plain fp32 store (S matrix). Verified r2-r7.
// ---------------------------------------------------------------------------
__global__ void __launch_bounds__(256) mfma_nt_plain(const short* __restrict__ Ab,
                                                     const short* __restrict__ Bb,
                                                     float* __restrict__ C, int N) {
    __shared__ __align__(16) short As[128 * 128];
    __shared__ __align__(16) short Bs[128 * 128];
    const int t = threadIdx.x;
    const int lane = t & 63, wv = t >> 6;
    const int l16 = lane & 15, l4 = lane >> 4;
    const int m0 = blockIdx.y * 128, n0 = blockIdx.x * 128;

    #pragma unroll
    for (int it = 0; it < 8; ++it) {
        const int r = it * 4 + wv, row = r * 4 + l4, cg = l16 ^ (row & 15);
        __builtin_amdgcn_global_load_lds(
            (const __attribute__((address_space(1))) void*)(Ab + (size_t)(m0 + row) * 128 + cg * 8),
            (__attribute__((address_space(3))) void*)(As + r * 512), 16, 0, 0);
    }
    #pragma unroll
    for (int it = 0; it < 8; ++it) {
        const int r = it * 4 + wv, row = r * 4 + l4, cg = l16 ^ (row & 15);
        __builtin_amdgcn_global_load_lds(
            (const __attribute__((address_space(1))) void*)(Bb + (size_t)(n0 + row) * 128 + cg * 8),
            (__attribute__((address_space(3))) void*)(Bs + r * 512), 16, 0, 0);
    }
    __syncthreads();

    const int wm = (wv & 1) * 64, wn = (wv >> 1) * 64;
    f32x4 acc[4][4];
    #pragma unroll
    for (int i = 0; i < 4; ++i)
        #pragma unroll
        for (int j = 0; j < 4; ++j) acc[i][j] = f32x4{0.f, 0.f, 0.f, 0.f};

    #pragma unroll
    for (int ks = 0; ks < 4; ++ks) {
        short8 af[4], bfr[4];
        const int ch = (ks * 4 + l4) ^ l16;
        #pragma unroll
        for (int i = 0; i < 4; ++i) {
            af[i]  = *(const short8*)(As + (wm + i * 16 + l16) * 128 + ch * 8);
            bfr[i] = *(const short8*)(Bs + (wn + i * 16 + l16) * 128 + ch * 8);
        }
        #pragma unroll
        for (int i = 0; i < 4; ++i)
            #pragma unroll
            for (int j = 0; j < 4; ++j)
                acc[i][j] = __builtin_amdgcn_mfma_f32_16x16x32_bf16(af[i], bfr[j], acc[i][j], 0, 0, 0);
    }
    #pragma unroll
    for (int i = 0; i < 4; ++i)
        #pragma unroll
        for (int r = 0; r < 4; ++r) {
            const int m = m0 + wm + i * 16 + l4 * 4 + r;
            #pragma unroll
            for (int j = 0; j < 4; ++j)
                C[(size_t)m * N + n0 + wn + j * 16 + l16] = acc[i][j][r];
        }
}

// ---------------------------------------------------------------------------
// FUSED masked queue GEMM + top-k histogram accumulation. No sims buffer:
// opposite-label values >= WLO update per-row global (count, expsum) hists
// via fire-and-forget atomics (low contention: ~1.4K pairs/block over
// 2048x1024 bins; NOT r4's value-returning slot atomics).
// ---------------------------------------------------------------------------
__global__ void __launch_bounds__(256) mfma_nt_hist(const short* __restrict__ Ab,
                                                    const short* __restrict__ Bb,
                                                    int* __restrict__ ghist,
                                                    float* __restrict__ gfexp,
                                                    const int* __restrict__ labA,
                                                    const int* __restrict__ labB) {
    __shared__ __align__(16) short As[128 * 128];
    __shared__ __align__(16) short Bs[128 * 128];
    const int t = threadIdx.x;
    const int lane = t & 63, wv = t >> 6;
    const int l16 = lane & 15, l4 = lane >> 4;
    const int m0 = blockIdx.y * 128, n0 = blockIdx.x * 128;

    #pragma unroll
    for (int it = 0; it < 8; ++it) {
        const int r = it * 4 + wv, row = r * 4 + l4, cg = l16 ^ (row & 15);
        __builtin_amdgcn_global_load_lds(
            (const __attribute__((address_space(1))) void*)(Ab + (size_t)(m0 + row) * 128 + cg * 8),
            (__attribute__((address_space(3))) void*)(As + r * 512), 16, 0, 0);
    }
    #pragma unroll
    for (int it = 0; it < 8; ++it) {
        const int r = it * 4 + wv, row = r * 4 + l4, cg = l16 ^ (row & 15);
        __builtin_amdgcn_global_load_lds(
            (const __attribute__((address_space(1))) void*)(Bb + (size_t)(n0 + row) * 128 + cg * 8),
            (__attribute__((address_space(3))) void*)(Bs + r * 512), 16, 0, 0);
    }
    __syncthreads();

    const int wm = (wv & 1) * 64, wn = (wv >> 1) * 64;
    f32x4 acc[4][4];
    #pragma unroll
    for (int i = 0; i < 4; ++i)
        #pragma unroll
        for (int j = 0; j < 4; ++j) acc[i][j] = f32x4{0.f, 0.f, 0.f, 0.f};

    #pragma unroll
    for (int ks = 0; ks < 4; ++ks) {
        short8 af[4], bfr[4];
        const int ch = (ks * 4 + l4) ^ l16;
        #pragma unroll
        for (int i = 0; i < 4; ++i) {
            af[i]  = *(const short8*)(As + (wm + i * 16 + l16) * 128 + ch * 8);
            bfr[i] = *(const short8*)(Bs + (wn + i * 16 + l16) * 128 + ch * 8);
        }
        #pragma unroll
        for (int i = 0; i < 4; ++i)
            #pragma unroll
            for (int j = 0; j < 4; ++j)
                acc[i][j] = __builtin_amdgcn_mfma_f32_16x16x32_bf16(af[i], bfr[j], acc[i][j], 0, 0, 0);
    }

    const float scale = 1024.0f / (1.0f - WLO);
    int qn[4];
    #pragma unroll
    for (int j = 0; j < 4; ++j) qn[j] = labB[n0 + wn + j * 16 + l16];
    #pragma unroll
    for (int i = 0; i < 4; ++i) {
        #pragma unroll
        for (int r = 0; r < 4; ++r) {
            const int m  = m0 + wm + i * 16 + l4 * 4 + r;
            const int lm = labA[m];
            int*   hrow = ghist + (size_t)m * 1024;
            float* frow = gfexp + (size_t)m * 1024;
            #pragma unroll
            for (int j = 0; j < 4; ++j) {
                const float v = acc[i][j][r];
                if (qn[j] != lm && qn[j] >= 0 && v >= WLO) {
                    const int b = min((int)((v - WLO) * scale), 1023);
                    atomicAdd(hrow + b, 1);
                    atomicAdd(frow + b, __expf((v - 1.0f) * INV_T));
                }
            }
        }
    }
}

// ---------------------------------------------------------------------------
// bf16 MFMA NT GEMM with K-loop, fused bias(+ReLU). Verified r3-r7 (MLP).
// ---------------------------------------------------------------------------
template<typename OutT, bool RELU>
__global__ void __launch_bounds__(256) mfma_nt_k(const short* __restrict__ Ab,
                                                 const short* __restrict__ Bb,
                                                 const float* __restrict__ bias,
                                                 OutT* __restrict__ C,
                                                 int N, int K) {
    __shared__ __align__(16) short As[128 * 128];
    __shared__ __align__(16) short Bs[128 * 128];
    const int t = threadIdx.x;
    const int lane = t & 63, wv = t >> 6;
    const int l16 = lane & 15, l4 = lane >> 4;
    const int m0 = blockIdx.y * 128, n0 = blockIdx.x * 128;
    const int wm = (wv & 1) * 64, wn = (wv >> 1) * 64;

    f32x4 acc[4][4];
    #pragma unroll
    for (int i = 0; i < 4; ++i)
        #pragma unroll
        for (int j = 0; j < 4; ++j) acc[i][j] = f32x4{0.f, 0.f, 0.f, 0.f};

    for (int kb = 0; kb < K; kb += 128) {
        __syncthreads();
        #pragma unroll
        for (int it = 0; it < 8; ++it) {
            const int r = it * 4 + wv, row = r * 4 + l4, cg = l16 ^ (row & 15);
            __builtin_amdgcn_global_load_lds(
                (const __attribute__((address_space(1))) void*)(Ab + (size_t)(m0 + row) * K + kb + cg * 8),
                (__attribute__((address_space(3))) void*)(As + r * 512), 16, 0, 0);
        }
        #pragma unroll
        for (int it = 0; it < 8; ++it) {
            const int r = it * 4 + wv, row = r * 4 + l4, cg = l16 ^ (row & 15);
            __builtin_amdgcn_global_load_lds(
                (const __attribute__((address_space(1))) void*)(Bb + (size_t)(n0 + row) * K + kb + cg * 8),
                (__attribute__((address_space(3))) void*)(Bs + r * 512), 16, 0, 0);
        }
        __syncthreads();
        #pragma unroll
        for (int ks = 0; ks < 4; ++ks) {
            short8 af[4], bfr[4];
            const int ch = (ks * 4 + l4) ^ l16;
            #pragma unroll
            for (int i = 0; i < 4; ++i) {
                af[i]  = *(const short8*)(As + (wm + i * 16 + l16) * 128 + ch * 8);
                bfr[i] = *(const short8*)(Bs + (wn + i * 16 + l16) * 128 + ch * 8);
            }
            #pragma unroll
            for (int i = 0; i < 4; ++i)
                #pragma unroll
                for (int j = 0; j < 4; ++j)
                    acc[i][j] = __builtin_amdgcn_mfma_f32_16x16x32_bf16(af[i], bfr[j], acc[i][j], 0, 0, 0);
        }
    }

    float bsv[4];
    #pragma unroll
    for (int j = 0; j < 4; ++j) bsv[j] = bias[n0 + wn + j * 16 + l16];
    #pragma unroll
    for (int i = 0; i < 4; ++i)
        #pragma unroll
        for (int r = 0; r < 4; ++r) {
            const int m = m0 + wm + i * 16 + l4 * 4 + r;
            #pragma unroll
            for (int j = 0; j < 4; ++j) {
                const int n = n0 + wn + j * 16 + l16;
                float v = acc[i][j][r] + bsv[j];
                if (RELU) v = fmaxf(v, 0.0f);
                if constexpr (sizeof(OutT) == 2) ((short*)C)[(size_t)m * N + n] = (short)f2bf(v);
                else                             ((float*)C)[(size_t)m * N + n] = v;
            }
        }
}

// ---------------------------------------------------------------------------
__global__ void __launch_bounds__(256) transpose_cast(const float* __restrict__ A,
                                                      short* __restrict__ At,
                                                      int R, int C) {
    __shared__ float tile[64][65];
    const int bx = blockIdx.x * 64, by = blockIdx.y * 64;
    const int t = threadIdx.x, tc = t & 63, tg = t >> 6;
    #pragma unroll
    for (int i = 0; i < 16; i++) {
        const int r = tg * 16 + i;
        tile[r][tc] = A[(size_t)(by + r) * C + bx + tc];
    }
    __syncthreads();
    #pragma unroll
    for (int i = 0; i < 16; i++) {
        const int r = tg * 16 + i;
        At[(size_t)(bx + r) * R + by + tc] = (short)f2bf(tile[tc][r]);
    }
}

__global__ void normalize_cast(const float* __restrict__ z, short* __restrict__ zb) {
    const int row = blockIdx.x, t = threadIdx.x;
    const float v = z[(size_t)row * PROJ_D_ + t];
    float ss = v * v;
    #pragma unroll
    for (int o = 32; o > 0; o >>= 1) ss += __shfl_down(ss, o);
    __shared__ float s2[2];
    if ((t & 63) == 0) s2[t >> 6] = ss;
    __syncthreads();
    zb[(size_t)row * PROJ_D_ + t] = (short)f2bf(v / sqrtf(s2[0] + s2[1]));
}

__global__ void cast_bf16_vec(const float* __restrict__ src, short* __restrict__ dst, int n4) {
    const int i = blockIdx.x * blockDim.x + threadIdx.x;
    if (i < n4) {
        const float4 f = ((const float4*)src)[i];
        short4v o = {(short)f2bf(f.x), (short)f2bf(f.y), (short)f2bf(f.z), (short)f2bf(f.w)};
        ((short4v*)dst)[i] = o;
    }
}

// queue-label census: qcnt[0]=#{==0}, qcnt[1]=#{==1}, qcnt[2]=#{>=0}
__global__ void count_qlab(const int* __restrict__ qlab, int* __restrict__ qcnt) {
    const int i = blockIdx.x * 256 + threadIdx.x;
    int c0 = 0, c1 = 0, cv = 0;
    for (int j = i; j < QUEUE_N; j += 8192) {
        const int q = qlab[j];
        c0 += (q == 0); c1 += (q == 1); cv += (q >= 0);
    }
    #pragma unroll
    for (int o = 32; o > 0; o >>= 1) {
        c0 += __shfl_xor(c0, o); c1 += __shfl_xor(c1, o); cv += __shfl_xor(cv, o);
    }
    if ((threadIdx.x & 63) == 0) {
        atomicAdd(&qcnt[0], c0); atomicAdd(&qcnt[1], c1); atomicAdd(&qcnt[2], cv);
    }
}

// ---------------------------------------------------------------------------
// Histogram crossing search (verified r1-r7)
// ---------------------------------------------------------------------------
__device__ __forceinline__ void find_crossing(int* hist, int* grp, int target,
                                              int* s_bin, int* s_chi) {
    const int t = threadIdx.x;
    const int b0 = hist[4*t], b1 = hist[4*t+1], b2 = hist[4*t+2], b3 = hist[4*t+3];
    grp[t] = b0 + b1 + b2 + b3;
    __syncthreads();
    for (int off = 1; off < 256; off <<= 1) {
        int add = (t + off < 256) ? grp[t + off] : 0;
        __syncthreads();
        grp[t] += add;
        __syncthreads();
    }
    int cab = (t < 255) ? grp[t + 1] : 0;
    const int hb[4] = {b0, b1, b2, b3};
    #pragma unroll
    for (int i = 3; i >= 0; i--) {
        const int h = hb[i];
        if (cab < target && cab + h >= target) { *s_bin = 4*t + i; *s_chi = cab; }
        cab += h;
    }
    __syncthreads();
}

// ---------------------------------------------------------------------------
// Per-row reduce over fused-GEMM histograms -> lse_queue (r5-verified math).
// One block per row: load 8 KB hist/fexp, suffix-scan, crossing, compose.
// ---------------------------------------------------------------------------
__global__ void __launch_bounds__(256) queue_lse_reduce(const int* __restrict__ ghist,
                                                        const float* __restrict__ gfexp,
                                                        const int* __restrict__ qcnt,
                                                        const int* __restrict__ labels,
                                                        float* __restrict__ lseq,
                                                        int* __restrict__ flag) {
    const int row = blockIdx.x, t = threadIdx.x;
    __shared__ int   hist[1024];
    __shared__ float fexp[1024];
    __shared__ int   grp[256];
    __shared__ int   s_bin, s_chi;
    __shared__ float scf[4];

    ((int4*)  hist)[t] = ((const int4*)  (ghist + (size_t)row * 1024))[t];
    ((float4*)fexp)[t] = ((const float4*)(gfexp + (size_t)row * 1024))[t];
    __syncthreads();

    const int b0 = hist[4*t], b1 = hist[4*t+1], b2 = hist[4*t+2], b3 = hist[4*t+3];
    grp[t] = b0 + b1 + b2 + b3;
    __syncthreads();
    for (int off = 1; off < 256; off <<= 1) {
        int add = (t + off < 256) ? grp[t + off] : 0;
        __syncthreads();
        grp[t] += add;
        __syncthreads();
    }
    const int total = grp[0];
    const int opp   = opp_of(labels[row], qcnt);
    if (total < HARD_K_ || opp < HARD_K_) {
        if (t == 0) flag[row] = 0;
        return;
    }
    {
        int cab = (t < 255) ? grp[t + 1] : 0;
        const int hb[4] = {b0, b1, b2, b3};
        #pragma unroll
        for (int i = 3; i >= 0; i--) {
            const int h = hb[i];
            if (cab < HARD_K_ && cab + h >= HARD_K_) { s_bin = 4*t + i; s_chi = cab; }
            cab += h;
        }
    }
    __syncthreads();
    const int bin1 = s_bin, cab1 = s_chi;

    float fs = 0.0f;
    #pragma unroll
    for (int i = 0; i < 4; i++) {
        const int idx = 4*t + i;
        if (idx > bin1) fs += fexp[idx];
    }
    #pragma unroll
    for (int o = 32; o > 0; o >>= 1) fs += __shfl_xor(fs, o);
    if ((t & 63) == 0) scf[t >> 6] = fs;
    __syncthreads();
    if (t == 0) {
        const float Sabove = scf[0] + scf[1] + scf[2] + scf[3];
        const int   take   = HARD_K_ - cab1;
        const float sadj   = Sabove + fexp[bin1] * ((float)take / (float)hist[bin1]);
        lseq[row] = INV_T + __logf(sadj);
        flag[row] = 1;
    }
}

// iterate all 128 packed-half2 values
#define FOR_ALL_VALS(BODY)                                                   \
    _Pragma("unroll")                                                        \
    for (int _k = 0; _k < 64; _k++) {                                        \
        const float2 _f = __half22float2(*(const __half2*)&dv[_k]);          \
        { const float v = _f.x; BODY }                                       \
        { const float v = _f.y; BODY }                                       \
    }

// ---------------------------------------------------------------------------
// Exact fallback (verified r5-r7; normally zero rows). Recomputes from zb/qb.
// ---------------------------------------------------------------------------
__global__ void __launch_bounds__(256) topk_lse_fallback(const short* __restrict__ zb,
                                                         const short* __restrict__ qb,
                                                         const int* __restrict__ labels,
                                                         const int* __restrict__ qlab,
                                                         const int* __restrict__ qcnt,
                                                         const int* __restrict__ flag,
                                                         float* __restrict__ lseq) {
    const int row = blockIdx.x, t = threadIdx.x;
    if (flag[row]) return;
    const int opp = opp_of(labels[row], qcnt);

    __shared__ float zrow[128];
    __shared__ int hist[1024];
    __shared__ int grp[256];
    __shared__ int s_bin, s_chi, s_bin2, s_chi2;
    __shared__ float scf[4]; __shared__ int sci[4];
    if (t < 128) zrow[t] = bf2f(zb[(size_t)row * 128 + t]);
    __syncthreads();

    const int mylab = labels[row];
    unsigned dv[64];
    float rm = -1e30f, rs = 0.0f;
    for (int k = 0; k < 128; k++) {
        const int j = t + 256 * k;
        float d = 0.0f;
        #pragma unroll
        for (int c = 0; c < 16; ++c) {
            const short8 qv = *(const short8*)(qb + (size_t)j * 128 + c * 8);
            #pragma unroll
            for (int e = 0; e < 8; ++e) d += zrow[c * 8 + e] * bf2f(qv[e]);
        }
        if (j < HARD_K_) {
            const float sv = d * INV_T;
            if (sv > rm) { rs = rs * __expf(rm - sv) + 1.0f; rm = sv; }
            else         { rs += __expf(sv - rm); }
        }
        const int q = qlab[j];
        const float mv = (q != mylab && q >= 0) ? d : -65504.0f;
        const __half h = __float2half(mv);
        unsigned short* p = (unsigned short*)&dv[k >> 1];
        p[k & 1] = *(const unsigned short*)&h;
    }

    if (opp == 0) {
        #pragma unroll
        for (int o = 32; o > 0; o >>= 1) {
            const float om = __shfl_xor(rm, o), os = __shfl_xor(rs, o);
            const float nm = fmaxf(rm, om);
            rs = rs * __expf(rm - nm) + os * __expf(om - nm);
            rm = nm;
        }
        if ((t & 63) == 0) { scf[t >> 6] = rm; ((float*)sci)[t >> 6] = rs; }
        __syncthreads();
        if (t == 0) {
            float M = -1e30f, Sx = 0.0f;
            for (int w = 0; w < 4; w++) {
                const float nm = fmaxf(M, scf[w]);
                Sx = Sx * __expf(M - nm) + ((float*)sci)[w] * __expf(scf[w] - nm);
                M = nm;
            }
            lseq[row] = M + __logf(Sx);
        }
        return;
    }
    if (opp < HARD_K_) {
        float mm = -1e30f, ss = 0.0f;
        FOR_ALL_VALS(
            if (v > -60000.0f) {
                const float sv = v * INV_T;
                if (sv > mm) { ss = ss * __expf(mm - sv) + 1.0f; mm = sv; }
                else         { ss += __expf(sv - mm); }
            } )
        #pragma unroll
        for (int o = 32; o > 0; o >>= 1) {
            const float om = __shfl_xor(mm, o), os = __shfl_xor(ss, o);
            const float nm = fmaxf(mm, om);
            ss = ss * __expf(mm - nm) + os * __expf(om - nm);
            mm = nm;
        }
        if ((t & 63) == 0) { scf[t >> 6] = mm; ((float*)sci)[t >> 6] = ss; }
        __syncthreads();
        if (t == 0) {
            float M = -1e30f, Sx = 0.0f;
            for (int w = 0; w < 4; w++) {
                const float nm = fmaxf(M, scf[w]);
                Sx = Sx * __expf(M - nm) + ((float*)sci)[w] * __expf(scf[w] - nm);
                M = nm;
            }
            lseq[row] = M + __logf(Sx);
        }
        return;
    }

    float mloc = -1e30f;
    FOR_ALL_VALS( mloc = fmaxf(mloc, v); )
    #pragma unroll
    for (int o = 32; o > 0; o >>= 1) mloc = fmaxf(mloc, __shfl_xor(mloc, o));
    if ((t & 63) == 0) scf[t >> 6] = mloc;
    __syncthreads();
    const float m = fmaxf(fmaxf(scf[0], scf[1]), fmaxf(scf[2], scf[3]));

    int c1 = 0, c2 = 0;
    const float w1 = m - 0.25f, w2 = m - 1.0f;
    FOR_ALL_VALS( c1 += (v >= w1); c2 += (v >= w2); )
    #pragma unroll
    for (int o = 32; o > 0; o >>= 1) { c1 += __shfl_xor(c1, o); c2 += __shfl_xor(c2, o); }
    if ((t & 63) == 0) { sci[t >> 6] = c1; }
    __syncthreads();
    const int C1 = sci[0] + sci[1] + sci[2] + sci[3];
    __syncthreads();
    if ((t & 63) == 0) { sci[t >> 6] = c2; }
    __syncthreads();
    const int C2 = sci[0] + sci[1] + sci[2] + sci[3];

    float lo;
    if      (C1 >= HARD_K_) lo = w1;
    else if (C2 >= HARD_K_) lo = w2;
    else                    lo = -1.01f;
    const float range = m - lo;
    const float scale = 1024.0f / range;

    for (int k = t; k < 1024; k += 256) hist[k] = 0;
    __syncthreads();
    FOR_ALL_VALS(
        if (v >= lo) {
            const float bf = fminf((v - lo) * scale, 1023.0f);
            atomicAdd(&hist[(int)bf], 1);
        } )
    __syncthreads();
    find_crossing(hist, grp, HARD_K_, &s_bin, &s_chi);
    const int   bin1 = s_bin, chi1 = s_chi;
    const float binw = range * (1.0f / 1024.0f);
    const float lo1  = lo + bin1 * binw;
    const float ssc  = 1024.0f / binw;

    for (int k = t; k < 1024; k += 256) hist[k] = 0;
    __syncthreads();
    FOR_ALL_VALS(
        if (v >= lo) {
            const float bf = fminf((v - lo) * scale, 1023.0f);
            if ((int)bf == bin1) {
                const float sf = fminf(fmaxf((v - lo1) * ssc, 0.0f), 1023.0f);
                atomicAdd(&hist[(int)sf], 1);
            }
        } )
    __syncthreads();
    find_crossing(hist, grp, HARD_K_ - chi1, &s_bin2, &s_chi2);
    const float thr = lo1 + s_bin2 * (binw * (1.0f / 1024.0f));

    float sl = 0.0f; int cg = 0;
    FOR_ALL_VALS( if (v > thr) { cg++; sl += __expf((v - m) * INV_T); } )
    #pragma unroll
    for (int o = 32; o > 0; o >>= 1) { sl += __shfl_xor(sl, o); cg += __shfl_xor(cg, o); }
    if ((t & 63) == 0) { scf[t >> 6] = sl; sci[t >> 6] = cg; }
    __syncthreads();
    if (t == 0) {
        const float slt = scf[0] + scf[1] + scf[2] + scf[3];
        const int   cgt = sci[0] + sci[1] + sci[2] + sci[3];
        const float sadj = slt + ((float)HARD_K_ - (float)cgt) * __expf((thr - m) * INV_T);
        lseq[row] = m * INV_T + __logf(sadj);
    }
}

// ---------------------------------------------------------------------------
// Batch lse + positive-pair loss, one WAVE per row (verified r6/r7).
// ---------------------------------------------------------------------------
__global__ void __launch_bounds__(256) batch_row_loss(const float* __restrict__ S,
                                                      const int* __restrict__ labels,
                                                      const float* __restrict__ lse_queue,
                                                      float* __restrict__ part_out,
                                                      int* __restrict__ cnt_out) {
    const int t = threadIdx.x;
    const int wv = t >> 6, lane = t & 63;
    const int row = blockIdx.x * 4 + wv;
    __shared__ int lab[BATCH_N];
    for (int k = t; k < BATCH_N; k += 256) lab[k] = labels[k];
    __syncthreads();
    const int myLab = lab[row];
    const float4* rp4 = (const float4*)(S + (size_t)row * BATCH_N);
    const int4*   lb4 = (const int4*)lab;

    float v[32]; int lb[32];
    #pragma unroll
    for (int kk = 0; kk < 8; kk++) {
        const float4 f = rp4[lane + 64 * kk];
        const int4   l = lb4[lane + 64 * kk];
        v[4*kk+0] = f.x; v[4*kk+1] = f.y; v[4*kk+2] = f.z; v[4*kk+3] = f.w;
        lb[4*kk+0] = l.x; lb[4*kk+1] = l.y; lb[4*kk+2] = l.z; lb[4*kk+3] = l.w;
    }

    const float REF = INV_T;
    float sneg = 0.0f;
    #pragma unroll
    for (int k = 0; k < 32; k++) {
        const float ev = __expf(v[k] * INV_T - REF);
        sneg += (lb[k] != myLab) ? ev : 0.0f;
    }
    #pragma unroll
    for (int o = 32; o > 0; o >>= 1) sneg += __shfl_xor(sneg, o);
    const float lseb = (sneg > 0.0f) ? REF + __logf(sneg) : -1e30f;
    const float Lq = lse_queue[row];
    const float mx0 = fmaxf(lseb, Lq), mn0 = fminf(lseb, Lq);
    const float L = mx0 + __logf(1.0f + __expf(mn0 - mx0));

    float part = 0.0f; int cnt = 0;
    #pragma unroll
    for (int k = 0; k < 32; k++) {
        const int j = (lane + 64 * (k >> 2)) * 4 + (k & 3);
        if (lb[k] == myLab && j != row) {
            const float sv = v[k] * INV_T;
            const float mx = fmaxf(sv, L), mn = fminf(sv, L);
            part += (mx - sv) + __logf(1.0f + __expf(mn - mx));
            cnt++;
        }
    }
    #pragma unroll
    for (int o = 32; o > 0; o >>= 1) { part += __shfl_xor(part, o); cnt += __shfl_xor(cnt, o); }
    if (lane == 0) { part_out[row] = part; cnt_out[row] = cnt; }
}

// reduce 2048 per-row partials -> scalar loss. One block.
__global__ void __launch_bounds__(256) finalize_loss(const float* __restrict__ part,
                                                     const int* __restrict__ cnt,
                                                     float* __restrict__ out) {
    const int t = threadIdx.x;
    float s = 0.0f; int c = 0;
    #pragma unroll
    for (int k = 0; k < 8; k++) { s += part[t + 256 * k]; c += cnt[t + 256 * k]; }
    #pragma unroll
    for (int o = 32; o > 0; o >>= 1) { s += __shfl_xor(s, o); c += __shfl_xor(c, o); }
    __shared__ float sf[4]; __shared__ int sc[4];
    if ((t & 63) == 0) { sf[t >> 6] = s; sc[t >> 6] = c; }
    __syncthreads();
    if (t == 0) {
        const float st = sf[0] + sf[1] + sf[2] + sf[3];
        const int   ct = sc[0] + sc[1] + sc[2] + sc[3];
        out[0] = (ct > 0) ? (st / (float)ct) : 0.0f;
    }
}

// ---------------------------------------------------------------------------
extern "C" void kernel_launch(void* const* d_in, const int* in_sizes, int n_in,
                              void* d_out, int out_size, void* d_ws, size_t ws_size,
                              hipStream_t stream) {
    const float* emb    = (const float*)d_in[0];
    const int*   labels = (const int*)  d_in[1];
    const float* W1     = (const float*)d_in[2];
    const float* b1     = (const float*)d_in[3];
    const float* W2     = (const float*)d_in[4];
    const float* b2     = (const float*)d_in[5];
    const float* queue  = (const float*)d_in[6];
    const int*   qlab   = (const int*)  d_in[7];

    char* ws = (char*)d_ws;
    float* Sbuf  = (float*)(ws);                         // 16777216
    int*   ghist = (int*)  (ws + 16777216);              // 8388608
    float* gfexp = (float*)(ws + 25165824);              // 8388608
    short* embb  = (short*)(ws + 33554432);              // 3145728
    short* hbf   = (short*)(ws + 36700160);              // 3145728
    float* z     = (float*)(ws + 39845888);              // 1048576
    short* zb    = (short*)(ws + 40894464);              // 524288
    short* qb    = (short*)(ws + 41418752);              // 8388608
    short* w1t   = (short*)(ws + 49807360);              // 1179648
    short* w2t   = (short*)(ws + 50987008);              // 196608
    float* lseq  = (float*)(ws + 51183616);              // 8192
    int*   flag  = (int*)  (ws + 51191808);              // 8192
    int*   qcnt  = (int*)  (ws + 51200000);              // 64
    float* partb = (float*)(ws + 51200064);              // 8192
    int*   cntb  = (int*)  (ws + 51208256);              // 8192

    hipMemsetAsync(ws + 16777216, 0, 16777216, stream);  // ghist + gfexp
    hipMemsetAsync(ws + 51191808, 0, 8192 + 64, stream); // flag + qcnt

    dim3 blk(256);
    cast_bf16_vec<<<dim3(BATCH_N * EMB_D_ / 4 / 256), blk, 0, stream>>>(emb, embb, BATCH_N * EMB_D_ / 4);
    cast_bf16_vec<<<dim3(QUEUE_N * PROJ_D_ / 4 / 256), blk, 0, stream>>>(queue, qb, QUEUE_N * PROJ_D_ / 4);
    transpose_cast<<<dim3(EMB_D_ / 64, EMB_D_ / 64), blk, 0, stream>>>(W1, w1t, EMB_D_, EMB_D_);
    transpose_cast<<<dim3(PROJ_D_ / 64, EMB_D_ / 64), blk, 0, stream>>>(W2, w2t, EMB_D_, PROJ_D_);
    count_qlab<<<dim3(32), blk, 0, stream>>>(qlab, qcnt);
    mfma_nt_k<short, true ><<<dim3(EMB_D_ / 128, BATCH_N / 128), blk, 0, stream>>>(embb, w1t, b1, hbf, EMB_D_, EMB_D_);
    mfma_nt_k<float, false><<<dim3(PROJ_D_ / 128, BATCH_N / 128), blk, 0, stream>>>(hbf, w2t, b2, z, PROJ_D_, EMB_D_);
    normalize_cast<<<BATCH_N, PROJ_D_, 0, stream>>>(z, zb);
    // fused masked queue GEMM + histogram accumulation (no sims buffer)
    mfma_nt_hist<<<dim3(QUEUE_N / 128, BATCH_N / 128), blk, 0, stream>>>(zb, qb, ghist, gfexp, labels, qlab);
    queue_lse_reduce<<<BATCH_N, 256, 0, stream>>>(ghist, gfexp, qcnt, labels, lseq, flag);
    topk_lse_fallback<<<BATCH_N, 256, 0, stream>>>(zb, qb, labels, qlab, qcnt, flag, lseq);
    mfma_nt_plain<<<dim3(BATCH_N / 128, BATCH_N / 128), blk, 0, stream>>>(zb, zb, Sbuf, BATCH_N);
    batch_row_loss<<<BATCH_N / 4, 256, 0, stream>>>(Sbuf, labels, lseq, partb, cntb);
    finalize_loss<<<1, 256, 0, stream>>>(partb, cntb, (float*)d_out);
}

// Round 9
// 258.690 us; speedup vs baseline: 1.7427x; 1.7427x over previous
//
#include <hip/hip_runtime.h>
#include <hip/hip_fp16.h>

#define BATCH_N   2048
#define EMB_D_    768
#define PROJ_D_   128
#define QUEUE_N   32768
#define HARD_K_   512
#define NCHUNK    16
#define NBIN      64
static constexpr float INV_T = 1.0f / 0.07f;
static constexpr float WLO   = 0.12f;    // hist window low (512th opp val ~0.164)

typedef __attribute__((ext_vector_type(8))) short short8;
typedef __attribute__((ext_vector_type(4))) short short4v;
typedef __attribute__((ext_vector_type(4))) float f32x4;

__device__ __forceinline__ unsigned short f2bf(float f) {
    unsigned u = __float_as_uint(f);
    unsigned r = u + 0x7fffu + ((u >> 16) & 1u);   // RNE
    return (unsigned short)(r >> 16);
}
__device__ __forceinline__ float bf2f(short s) {
    return __uint_as_float(((unsigned)(unsigned short)s) << 16);
}
__device__ __forceinline__ int opp_of(int mylab, const int* __restrict__ qcnt) {
    const int same = (mylab == 0) ? qcnt[0] : ((mylab == 1) ? qcnt[1] : 0);
    return qcnt[2] - same;
}

// ---------------------------------------------------------------------------
// bf16 MFMA NT GEMM, K=128 in LDS, plain fp32 store (S matrix). Verified r2-r8.
// ---------------------------------------------------------------------------
__global__ void __launch_bounds__(256) mfma_nt_plain(const short* __restrict__ Ab,
                                                     const short* __restrict__ Bb,
                                                     float* __restrict__ C, int N) {
    __shared__ __align__(16) short As[128 * 128];
    __shared__ __align__(16) short Bs[128 * 128];
    const int t = threadIdx.x;
    const int lane = t & 63, wv = t >> 6;
    const int l16 = lane & 15, l4 = lane >> 4;
    const int m0 = blockIdx.y * 128, n0 = blockIdx.x * 128;

    #pragma unroll
    for (int it = 0; it < 8; ++it) {
        const int r = it * 4 + wv, row = r * 4 + l4, cg = l16 ^ (row & 15);
        __builtin_amdgcn_global_load_lds(
            (const __attribute__((address_space(1))) void*)(Ab + (size_t)(m0 + row) * 128 + cg * 8),
            (__attribute__((address_space(3))) void*)(As + r * 512), 16, 0, 0);
    }
    #pragma unroll
    for (int it = 0; it < 8; ++it) {
        const int r = it * 4 + wv, row = r * 4 + l4, cg = l16 ^ (row & 15);
        __builtin_amdgcn_global_load_lds(
            (const __attribute__((address_space(1))) void*)(Bb + (size_t)(n0 + row) * 128 + cg * 8),
            (__attribute__((address_space(3))) void*)(Bs + r * 512), 16, 0, 0);
    }
    __syncthreads();

    const int wm = (wv & 1) * 64, wn = (wv >> 1) * 64;
    f32x4 acc[4][4];
    #pragma unroll
    for (int i = 0; i < 4; ++i)
        #pragma unroll
        for (int j = 0; j < 4; ++j) acc[i][j] = f32x4{0.f, 0.f, 0.f, 0.f};

    #pragma unroll
    for (int ks = 0; ks < 4; ++ks) {
        short8 af[4], bfr[4];
        const int ch = (ks * 4 + l4) ^ l16;
        #pragma unroll
        for (int i = 0; i < 4; ++i) {
            af[i]  = *(const short8*)(As + (wm + i * 16 + l16) * 128 + ch * 8);
            bfr[i] = *(const short8*)(Bs + (wn + i * 16 + l16) * 128 + ch * 8);
        }
        #pragma unroll
        for (int i = 0; i < 4; ++i)
            #pragma unroll
            for (int j = 0; j < 4; ++j)
                acc[i][j] = __builtin_amdgcn_mfma_f32_16x16x32_bf16(af[i], bfr[j], acc[i][j], 0, 0, 0);
    }
    #pragma unroll
    for (int i = 0; i < 4; ++i)
        #pragma unroll
        for (int r = 0; r < 4; ++r) {
            const int m = m0 + wm + i * 16 + l4 * 4 + r;
            #pragma unroll
            for (int j = 0; j < 4; ++j)
                C[(size_t)m * N + n0 + wn + j * 16 + l16] = acc[i][j][r];
        }
}

// ---------------------------------------------------------------------------
// FUSED queue GEMM + per-row histogram, LDS-aggregated (r8 lesson: NO global
// atomics). Block = 128 rows x 2048-col chunk (16 tiles in-loop). Private
// 128x64-bin (cnt,expsum) hist in LDS, LDS atomics only, one plain-store
// flush to per-chunk slabs. 128 KB LDS -> 1 block/CU, grid 16x16 = 256.
// ---------------------------------------------------------------------------
__global__ void __launch_bounds__(256) mfma_qhist(const short* __restrict__ Ab,
                                                  const short* __restrict__ Bb,
                                                  int* __restrict__ ghist,
                                                  float* __restrict__ gfexp,
                                                  const int* __restrict__ labA,
                                                  const int* __restrict__ labB) {
    __shared__ __align__(16) short As[128 * 128];
    __shared__ __align__(16) short Bs[128 * 128];
    __shared__ __align__(16) int   hcnt[128 * NBIN];
    __shared__ __align__(16) float hexp[128 * NBIN];
    const int t = threadIdx.x;
    const int lane = t & 63, wv = t >> 6;
    const int l16 = lane & 15, l4 = lane >> 4;
    const int m0 = blockIdx.y * 128;

    for (int k = t; k < 128 * NBIN; k += 256) { hcnt[k] = 0; hexp[k] = 0.0f; }

    #pragma unroll
    for (int it = 0; it < 8; ++it) {
        const int r = it * 4 + wv, row = r * 4 + l4, cg = l16 ^ (row & 15);
        __builtin_amdgcn_global_load_lds(
            (const __attribute__((address_space(1))) void*)(Ab + (size_t)(m0 + row) * 128 + cg * 8),
            (__attribute__((address_space(3))) void*)(As + r * 512), 16, 0, 0);
    }

    const int wm = (wv & 1) * 64, wn = (wv >> 1) * 64;
    int la[16];
    #pragma unroll
    for (int i = 0; i < 4; ++i)
        #pragma unroll
        for (int r = 0; r < 4; ++r)
            la[i * 4 + r] = labA[m0 + wm + i * 16 + l4 * 4 + r];
    const float scale = (float)NBIN / (1.0f - WLO);

    for (int tt = 0; tt < 16; ++tt) {
        const int n0 = (blockIdx.x * 16 + tt) * 128;
        __syncthreads();                       // protect Bs + hist-init visibility
        #pragma unroll
        for (int it = 0; it < 8; ++it) {
            const int r = it * 4 + wv, row = r * 4 + l4, cg = l16 ^ (row & 15);
            __builtin_amdgcn_global_load_lds(
                (const __attribute__((address_space(1))) void*)(Bb + (size_t)(n0 + row) * 128 + cg * 8),
                (__attribute__((address_space(3))) void*)(Bs + r * 512), 16, 0, 0);
        }
        __syncthreads();

        f32x4 acc[4][4];
        #pragma unroll
        for (int i = 0; i < 4; ++i)
            #pragma unroll
            for (int j = 0; j < 4; ++j) acc[i][j] = f32x4{0.f, 0.f, 0.f, 0.f};
        #pragma unroll
        for (int ks = 0; ks < 4; ++ks) {
            short8 af[4], bfr[4];
            const int ch = (ks * 4 + l4) ^ l16;
            #pragma unroll
            for (int i = 0; i < 4; ++i) {
                af[i]  = *(const short8*)(As + (wm + i * 16 + l16) * 128 + ch * 8);
                bfr[i] = *(const short8*)(Bs + (wn + i * 16 + l16) * 128 + ch * 8);
            }
            #pragma unroll
            for (int i = 0; i < 4; ++i)
                #pragma unroll
                for (int j = 0; j < 4; ++j)
                    acc[i][j] = __builtin_amdgcn_mfma_f32_16x16x32_bf16(af[i], bfr[j], acc[i][j], 0, 0, 0);
        }

        int qn[4];
        #pragma unroll
        for (int j = 0; j < 4; ++j) qn[j] = labB[n0 + wn + j * 16 + l16];
        #pragma unroll
        for (int i = 0; i < 4; ++i) {
            #pragma unroll
            for (int r = 0; r < 4; ++r) {
                const int lm  = wm + i * 16 + l4 * 4 + r;
                const int lab = la[i * 4 + r];
                #pragma unroll
                for (int j = 0; j < 4; ++j) {
                    const float v = acc[i][j][r];
                    if (qn[j] != lab && qn[j] >= 0 && v >= WLO) {
                        const int b = min((int)((v - WLO) * scale), NBIN - 1);
                        atomicAdd(&hcnt[lm * NBIN + b], 1);
                        atomicAdd(&hexp[lm * NBIN + b], __expf((v - 1.0f) * INV_T));
                    }
                }
            }
        }
    }
    __syncthreads();
    // flush: plain coalesced stores to this block's private slab
    const size_t gbase = ((size_t)blockIdx.x * BATCH_N + (size_t)blockIdx.y * 128) * NBIN;
    for (int k = t * 4; k < 128 * NBIN; k += 1024) {
        *(int4*)  (ghist + gbase + k) = *(const int4*)  (hcnt + k);
        *(float4*)(gfexp + gbase + k) = *(const float4*)(hexp + k);
    }
}

// ---------------------------------------------------------------------------
// bf16 MFMA NT GEMM with K-loop, fused bias(+ReLU). Verified r3-r8 (MLP).
// ---------------------------------------------------------------------------
template<typename OutT, bool RELU>
__global__ void __launch_bounds__(256) mfma_nt_k(const short* __restrict__ Ab,
                                                 const short* __restrict__ Bb,
                                                 const float* __restrict__ bias,
                                                 OutT* __restrict__ C,
                                                 int N, int K) {
    __shared__ __align__(16) short As[128 * 128];
    __shared__ __align__(16) short Bs[128 * 128];
    const int t = threadIdx.x;
    const int lane = t & 63, wv = t >> 6;
    const int l16 = lane & 15, l4 = lane >> 4;
    const int m0 = blockIdx.y * 128, n0 = blockIdx.x * 128;
    const int wm = (wv & 1) * 64, wn = (wv >> 1) * 64;

    f32x4 acc[4][4];
    #pragma unroll
    for (int i = 0; i < 4; ++i)
        #pragma unroll
        for (int j = 0; j < 4; ++j) acc[i][j] = f32x4{0.f, 0.f, 0.f, 0.f};

    for (int kb = 0; kb < K; kb += 128) {
        __syncthreads();
        #pragma unroll
        for (int it = 0; it < 8; ++it) {
            const int r = it * 4 + wv, row = r * 4 + l4, cg = l16 ^ (row & 15);
            __builtin_amdgcn_global_load_lds(
                (const __attribute__((address_space(1))) void*)(Ab + (size_t)(m0 + row) * K + kb + cg * 8),
                (__attribute__((address_space(3))) void*)(As + r * 512), 16, 0, 0);
        }
        #pragma unroll
        for (int it = 0; it < 8; ++it) {
            const int r = it * 4 + wv, row = r * 4 + l4, cg = l16 ^ (row & 15);
            __builtin_amdgcn_global_load_lds(
                (const __attribute__((address_space(1))) void*)(Bb + (size_t)(n0 + row) * K + kb + cg * 8),
                (__attribute__((address_space(3))) void*)(Bs + r * 512), 16, 0, 0);
        }
        __syncthreads();
        #pragma unroll
        for (int ks = 0; ks < 4; ++ks) {
            short8 af[4], bfr[4];
            const int ch = (ks * 4 + l4) ^ l16;
            #pragma unroll
            for (int i = 0; i < 4; ++i) {
                af[i]  = *(const short8*)(As + (wm + i * 16 + l16) * 128 + ch * 8);
                bfr[i] = *(const short8*)(Bs + (wn + i * 16 + l16) * 128 + ch * 8);
            }
            #pragma unroll
            for (int i = 0; i < 4; ++i)
                #pragma unroll
                for (int j = 0; j < 4; ++j)
                    acc[i][j] = __builtin_amdgcn_mfma_f32_16x16x32_bf16(af[i], bfr[j], acc[i][j], 0, 0, 0);
        }
    }

    float bsv[4];
    #pragma unroll
    for (int j = 0; j < 4; ++j) bsv[j] = bias[n0 + wn + j * 16 + l16];
    #pragma unroll
    for (int i = 0; i < 4; ++i)
        #pragma unroll
        for (int r = 0; r < 4; ++r) {
            const int m = m0 + wm + i * 16 + l4 * 4 + r;
            #pragma unroll
            for (int j = 0; j < 4; ++j) {
                const int n = n0 + wn + j * 16 + l16;
                float v = acc[i][j][r] + bsv[j];
                if (RELU) v = fmaxf(v, 0.0f);
                if constexpr (sizeof(OutT) == 2) ((short*)C)[(size_t)m * N + n] = (short)f2bf(v);
                else                             ((float*)C)[(size_t)m * N + n] = v;
            }
        }
}

// ---------------------------------------------------------------------------
__global__ void __launch_bounds__(256) transpose_cast(const float* __restrict__ A,
                                                      short* __restrict__ At,
                                                      int R, int C) {
    __shared__ float tile[64][65];
    const int bx = blockIdx.x * 64, by = blockIdx.y * 64;
    const int t = threadIdx.x, tc = t & 63, tg = t >> 6;
    #pragma unroll
    for (int i = 0; i < 16; i++) {
        const int r = tg * 16 + i;
        tile[r][tc] = A[(size_t)(by + r) * C + bx + tc];
    }
    __syncthreads();
    #pragma unroll
    for (int i = 0; i < 16; i++) {
        const int r = tg * 16 + i;
        At[(size_t)(bx + r) * R + by + tc] = (short)f2bf(tile[tc][r]);
    }
}

__global__ void normalize_cast(const float* __restrict__ z, short* __restrict__ zb) {
    const int row = blockIdx.x, t = threadIdx.x;
    const float v = z[(size_t)row * PROJ_D_ + t];
    float ss = v * v;
    #pragma unroll
    for (int o = 32; o > 0; o >>= 1) ss += __shfl_down(ss, o);
    __shared__ float s2[2];
    if ((t & 63) == 0) s2[t >> 6] = ss;
    __syncthreads();
    zb[(size_t)row * PROJ_D_ + t] = (short)f2bf(v / sqrtf(s2[0] + s2[1]));
}

__global__ void cast_bf16_vec(const float* __restrict__ src, short* __restrict__ dst, int n4) {
    const int i = blockIdx.x * blockDim.x + threadIdx.x;
    if (i < n4) {
        const float4 f = ((const float4*)src)[i];
        short4v o = {(short)f2bf(f.x), (short)f2bf(f.y), (short)f2bf(f.z), (short)f2bf(f.w)};
        ((short4v*)dst)[i] = o;
    }
}

// queue-label census: qcnt[0]=#{==0}, qcnt[1]=#{==1}, qcnt[2]=#{>=0}
__global__ void count_qlab(const int* __restrict__ qlab, int* __restrict__ qcnt) {
    const int i = blockIdx.x * 256 + threadIdx.x;
    int c0 = 0, c1 = 0, cv = 0;
    for (int j = i; j < QUEUE_N; j += 8192) {
        const int q = qlab[j];
        c0 += (q == 0); c1 += (q == 1); cv += (q >= 0);
    }
    #pragma unroll
    for (int o = 32; o > 0; o >>= 1) {
        c0 += __shfl_xor(c0, o); c1 += __shfl_xor(c1, o); cv += __shfl_xor(cv, o);
    }
    if ((threadIdx.x & 63) == 0) {
        atomicAdd(&qcnt[0], c0); atomicAdd(&qcnt[1], c1); atomicAdd(&qcnt[2], cv);
    }
}

// ---------------------------------------------------------------------------
// Histogram crossing search (verified r1-r8; used by fallback)
// ---------------------------------------------------------------------------
__device__ __forceinline__ void find_crossing(int* hist, int* grp, int target,
                                              int* s_bin, int* s_chi) {
    const int t = threadIdx.x;
    const int b0 = hist[4*t], b1 = hist[4*t+1], b2 = hist[4*t+2], b3 = hist[4*t+3];
    grp[t] = b0 + b1 + b2 + b3;
    __syncthreads();
    for (int off = 1; off < 256; off <<= 1) {
        int add = (t + off < 256) ? grp[t + off] : 0;
        __syncthreads();
        grp[t] += add;
        __syncthreads();
    }
    int cab = (t < 255) ? grp[t + 1] : 0;
    const int hb[4] = {b0, b1, b2, b3};
    #pragma unroll
    for (int i = 3; i >= 0; i--) {
        const int h = hb[i];
        if (cab < target && cab + h >= target) { *s_bin = 4*t + i; *s_chi = cab; }
        cab += h;
    }
    __syncthreads();
}

// ---------------------------------------------------------------------------
// Merge 16 chunk-partial histograms -> lse_queue. One WAVE per row: 64 lanes
// = 64 bins, shfl suffix-scan, crossing, r5-verified composition.
// ---------------------------------------------------------------------------
__global__ void __launch_bounds__(256) queue_lse_reduce(const int* __restrict__ ghist,
                                                        const float* __restrict__ gfexp,
                                                        const int* __restrict__ qcnt,
                                                        const int* __restrict__ labels,
                                                        float* __restrict__ lseq,
                                                        int* __restrict__ flag) {
    const int t = threadIdx.x;
    const int wv = t >> 6, lane = t & 63;
    const int row = blockIdx.x * 4 + wv;

    int cnt = 0; float fx = 0.0f;
    #pragma unroll
    for (int c = 0; c < NCHUNK; c++) {
        const size_t off = ((size_t)c * BATCH_N + row) * NBIN + lane;
        cnt += ghist[off];
        fx  += gfexp[off];
    }
    // inclusive suffix sums across 64 lanes (lane b: sum over bins >= b)
    int sc = cnt; float sx = fx;
    #pragma unroll
    for (int o = 1; o < 64; o <<= 1) {
        const int   gc = __shfl_down(sc, o);
        const float gx = __shfl_down(sx, o);
        if (lane + o < 64) { sc += gc; sx += gx; }
    }
    const int total = __shfl(sc, 0);
    const int opp   = opp_of(labels[row], qcnt);
    if (total < HARD_K_ || opp < HARD_K_) {
        if (lane == 0) flag[row] = 0;
        return;
    }
    const int cab = sc - cnt;                    // count strictly above this bin
    if (cab < HARD_K_ && sc >= HARD_K_) {        // exactly one lane: crossing bin
        const float above = sx - fx;
        const int   take  = HARD_K_ - cab;
        const float sadj  = above + fx * ((float)take / (float)cnt);
        lseq[row] = INV_T + __logf(sadj);
        flag[row] = 1;
    }
}

// iterate all 128 packed-half2 values
#define FOR_ALL_VALS(BODY)                                                   \
    _Pragma("unroll")                                                        \
    for (int _k = 0; _k < 64; _k++) {                                        \
        const float2 _f = __half22float2(*(const __half2*)&dv[_k]);          \
        { const float v = _f.x; BODY }                                       \
        { const float v = _f.y; BODY }                                       \
    }

// ---------------------------------------------------------------------------
// Exact fallback (verified r5-r8; normally zero rows). Recomputes from zb/qb.
// ---------------------------------------------------------------------------
__global__ void __launch_bounds__(256) topk_lse_fallback(const short* __restrict__ zb,
                                                         const short* __restrict__ qb,
                                                         const int* __restrict__ labels,
                                                         const int* __restrict__ qlab,
                                                         const int* __restrict__ qcnt,
                                                         const int* __restrict__ flag,
                                                         float* __restrict__ lseq) {
    const int row = blockIdx.x, t = threadIdx.x;
    if (flag[row]) return;
    const int opp = opp_of(labels[row], qcnt);

    __shared__ float zrow[128];
    __shared__ int hist[1024];
    __shared__ int grp[256];
    __shared__ int s_bin, s_chi, s_bin2, s_chi2;
    __shared__ float scf[4]; __shared__ int sci[4];
    if (t < 128) zrow[t] = bf2f(zb[(size_t)row * 128 + t]);
    __syncthreads();

    const int mylab = labels[row];
    unsigned dv[64];
    float rm = -1e30f, rs = 0.0f;
    for (int k = 0; k < 128; k++) {
        const int j = t + 256 * k;
        float d = 0.0f;
        #pragma unroll
        for (int c = 0; c < 16; ++c) {
            const short8 qv = *(const short8*)(qb + (size_t)j * 128 + c * 8);
            #pragma unroll
            for (int e = 0; e < 8; ++e) d += zrow[c * 8 + e] * bf2f(qv[e]);
        }
        if (j < HARD_K_) {
            const float sv = d * INV_T;
            if (sv > rm) { rs = rs * __expf(rm - sv) + 1.0f; rm = sv; }
            else         { rs += __expf(sv - rm); }
        }
        const int q = qlab[j];
        const float mv = (q != mylab && q >= 0) ? d : -65504.0f;
        const __half h = __float2half(mv);
        unsigned short* p = (unsigned short*)&dv[k >> 1];
        p[k & 1] = *(const unsigned short*)&h;
    }

    if (opp == 0) {
        #pragma unroll
        for (int o = 32; o > 0; o >>= 1) {
            const float om = __shfl_xor(rm, o), os = __shfl_xor(rs, o);
            const float nm = fmaxf(rm, om);
            rs = rs * __expf(rm - nm) + os * __expf(om - nm);
            rm = nm;
        }
        if ((t & 63) == 0) { scf[t >> 6] = rm; ((float*)sci)[t >> 6] = rs; }
        __syncthreads();
        if (t == 0) {
            float M = -1e30f, Sx = 0.0f;
            for (int w = 0; w < 4; w++) {
                const float nm = fmaxf(M, scf[w]);
                Sx = Sx * __expf(M - nm) + ((float*)sci)[w] * __expf(scf[w] - nm);
                M = nm;
            }
            lseq[row] = M + __logf(Sx);
        }
        return;
    }
    if (opp < HARD_K_) {
        float mm = -1e30f, ss = 0.0f;
        FOR_ALL_VALS(
            if (v > -60000.0f) {
                const float sv = v * INV_T;
                if (sv > mm) { ss = ss * __expf(mm - sv) + 1.0f; mm = sv; }
                else         { ss += __expf(sv - mm); }
            } )
        #pragma unroll
        for (int o = 32; o > 0; o >>= 1) {
            const float om = __shfl_xor(mm, o), os = __shfl_xor(ss, o);
            const float nm = fmaxf(mm, om);
            ss = ss * __expf(mm - nm) + os * __expf(om - nm);
            mm = nm;
        }
        if ((t & 63) == 0) { scf[t >> 6] = mm; ((float*)sci)[t >> 6] = ss; }
        __syncthreads();
        if (t == 0) {
            float M = -1e30f, Sx = 0.0f;
            for (int w = 0; w < 4; w++) {
                const float nm = fmaxf(M, scf[w]);
                Sx = Sx * __expf(M - nm) + ((float*)sci)[w] * __expf(scf[w] - nm);
                M = nm;
            }
            lseq[row] = M + __logf(Sx);
        }
        return;
    }

    float mloc = -1e30f;
    FOR_ALL_VALS( mloc = fmaxf(mloc, v); )
    #pragma unroll
    for (int o = 32; o > 0; o >>= 1) mloc = fmaxf(mloc, __shfl_xor(mloc, o));
    if ((t & 63) == 0) scf[t >> 6] = mloc;
    __syncthreads();
    const float m = fmaxf(fmaxf(scf[0], scf[1]), fmaxf(scf[2], scf[3]));

    int c1 = 0, c2 = 0;
    const float w1 = m - 0.25f, w2 = m - 1.0f;
    FOR_ALL_VALS( c1 += (v >= w1); c2 += (v >= w2); )
    #pragma unroll
    for (int o = 32; o > 0; o >>= 1) { c1 += __shfl_xor(c1, o); c2 += __shfl_xor(c2, o); }
    if ((t & 63) == 0) { sci[t >> 6] = c1; }
    __syncthreads();
    const int C1 = sci[0] + sci[1] + sci[2] + sci[3];
    __syncthreads();
    if ((t & 63) == 0) { sci[t >> 6] = c2; }
    __syncthreads();
    const int C2 = sci[0] + sci[1] + sci[2] + sci[3];

    float lo;
    if      (C1 >= HARD_K_) lo = w1;
    else if (C2 >= HARD_K_) lo = w2;
    else                    lo = -1.01f;
    const float range = m - lo;
    const float scale = 1024.0f / range;

    for (int k = t; k < 1024; k += 256) hist[k] = 0;
    __syncthreads();
    FOR_ALL_VALS(
        if (v >= lo) {
            const float bf = fminf((v - lo) * scale, 1023.0f);
            atomicAdd(&hist[(int)bf], 1);
        } )
    __syncthreads();
    find_crossing(hist, grp, HARD_K_, &s_bin, &s_chi);
    const int   bin1 = s_bin, chi1 = s_chi;
    const float binw = range * (1.0f / 1024.0f);
    const float lo1  = lo + bin1 * binw;
    const float ssc  = 1024.0f / binw;

    for (int k = t; k < 1024; k += 256) hist[k] = 0;
    __syncthreads();
    FOR_ALL_VALS(
        if (v >= lo) {
            const float bf = fminf((v - lo) * scale, 1023.0f);
            if ((int)bf == bin1) {
                const float sf = fminf(fmaxf((v - lo1) * ssc, 0.0f), 1023.0f);
                atomicAdd(&hist[(int)sf], 1);
            }
        } )
    __syncthreads();
    find_crossing(hist, grp, HARD_K_ - chi1, &s_bin2, &s_chi2);
    const float thr = lo1 + s_bin2 * (binw * (1.0f / 1024.0f));

    float sl = 0.0f; int cg = 0;
    FOR_ALL_VALS( if (v > thr) { cg++; sl += __expf((v - m) * INV_T); } )
    #pragma unroll
    for (int o = 32; o > 0; o >>= 1) { sl += __shfl_xor(sl, o); cg += __shfl_xor(cg, o); }
    if ((t & 63) == 0) { scf[t >> 6] = sl; sci[t >> 6] = cg; }
    __syncthreads();
    if (t == 0) {
        const float slt = scf[0] + scf[1] + scf[2] + scf[3];
        const int   cgt = sci[0] + sci[1] + sci[2] + sci[3];
        const float sadj = slt + ((float)HARD_K_ - (float)cgt) * __expf((thr - m) * INV_T);
        lseq[row] = m * INV_T + __logf(sadj);
    }
}

// ---------------------------------------------------------------------------
// Batch lse + positive-pair loss, one WAVE per row (verified r6-r8).
// ---------------------------------------------------------------------------
__global__ void __launch_bounds__(256) batch_row_loss(const float* __restrict__ S,
                                                      const int* __restrict__ labels,
                                                      const float* __restrict__ lse_queue,
                                                      float* __restrict__ part_out,
                                                      int* __restrict__ cnt_out) {
    const int t = threadIdx.x;
    const int wv = t >> 6, lane = t & 63;
    const int row = blockIdx.x * 4 + wv;
    __shared__ int lab[BATCH_N];
    for (int k = t; k < BATCH_N; k += 256) lab[k] = labels[k];
    __syncthreads();
    const int myLab = lab[row];
    const float4* rp4 = (const float4*)(S + (size_t)row * BATCH_N);
    const int4*   lb4 = (const int4*)lab;

    float v[32]; int lb[32];
    #pragma unroll
    for (int kk = 0; kk < 8; kk++) {
        const float4 f = rp4[lane + 64 * kk];
        const int4   l = lb4[lane + 64 * kk];
        v[4*kk+0] = f.x; v[4*kk+1] = f.y; v[4*kk+2] = f.z; v[4*kk+3] = f.w;
        lb[4*kk+0] = l.x; lb[4*kk+1] = l.y; lb[4*kk+2] = l.z; lb[4*kk+3] = l.w;
    }

    const float REF = INV_T;
    float sneg = 0.0f;
    #pragma unroll
    for (int k = 0; k < 32; k++) {
        const float ev = __expf(v[k] * INV_T - REF);
        sneg += (lb[k] != myLab) ? ev : 0.0f;
    }
    #pragma unroll
    for (int o = 32; o > 0; o >>= 1) sneg += __shfl_xor(sneg, o);
    const float lseb = (sneg > 0.0f) ? REF + __logf(sneg) : -1e30f;
    const float Lq = lse_queue[row];
    const float mx0 = fmaxf(lseb, Lq), mn0 = fminf(lseb, Lq);
    const float L = mx0 + __logf(1.0f + __expf(mn0 - mx0));

    float part = 0.0f; int cnt = 0;
    #pragma unroll
    for (int k = 0; k < 32; k++) {
        const int j = (lane + 64 * (k >> 2)) * 4 + (k & 3);
        if (lb[k] == myLab && j != row) {
            const float sv = v[k] * INV_T;
            const float mx = fmaxf(sv, L), mn = fminf(sv, L);
            part += (mx - sv) + __logf(1.0f + __expf(mn - mx));
            cnt++;
        }
    }
    #pragma unroll
    for (int o = 32; o > 0; o >>= 1) { part += __shfl_xor(part, o); cnt += __shfl_xor(cnt, o); }
    if (lane == 0) { part_out[row] = part; cnt_out[row] = cnt; }
}

// reduce 2048 per-row partials -> scalar loss. One block.
__global__ void __launch_bounds__(256) finalize_loss(const float* __restrict__ part,
                                                     const int* __restrict__ cnt,
                                                     float* __restrict__ out) {
    const int t = threadIdx.x;
    float s = 0.0f; int c = 0;
    #pragma unroll
    for (int k = 0; k < 8; k++) { s += part[t + 256 * k]; c += cnt[t + 256 * k]; }
    #pragma unroll
    for (int o = 32; o > 0; o >>= 1) { s += __shfl_xor(s, o); c += __shfl_xor(c, o); }
    __shared__ float sf[4]; __shared__ int sc[4];
    if ((t & 63) == 0) { sf[t >> 6] = s; sc[t >> 6] = c; }
    __syncthreads();
    if (t == 0) {
        const float st = sf[0] + sf[1] + sf[2] + sf[3];
        const int   ct = sc[0] + sc[1] + sc[2] + sc[3];
        out[0] = (ct > 0) ? (st / (float)ct) : 0.0f;
    }
}

// ---------------------------------------------------------------------------
extern "C" void kernel_launch(void* const* d_in, const int* in_sizes, int n_in,
                              void* d_out, int out_size, void* d_ws, size_t ws_size,
                              hipStream_t stream) {
    const float* emb    = (const float*)d_in[0];
    const int*   labels = (const int*)  d_in[1];
    const float* W1     = (const float*)d_in[2];
    const float* b1     = (const float*)d_in[3];
    const float* W2     = (const float*)d_in[4];
    const float* b2     = (const float*)d_in[5];
    const float* queue  = (const float*)d_in[6];
    const int*   qlab   = (const int*)  d_in[7];

    char* ws = (char*)d_ws;
    float* Sbuf  = (float*)(ws);                         // 16777216
    int*   ghist = (int*)  (ws + 16777216);              // 16*2048*64*4 = 8388608
    float* gfexp = (float*)(ws + 25165824);              // 8388608
    short* embb  = (short*)(ws + 33554432);              // 3145728
    short* hbf   = (short*)(ws + 36700160);              // 3145728
    float* z     = (float*)(ws + 39845888);              // 1048576
    short* zb    = (short*)(ws + 40894464);              // 524288
    short* qb    = (short*)(ws + 41418752);              // 8388608
    short* w1t   = (short*)(ws + 49807360);              // 1179648
    short* w2t   = (short*)(ws + 50987008);              // 196608
    float* lseq  = (float*)(ws + 51183616);              // 8192
    int*   flag  = (int*)  (ws + 51191808);              // 8192
    int*   qcnt  = (int*)  (ws + 51200000);              // 64
    float* partb = (float*)(ws + 51200064);              // 8192
    int*   cntb  = (int*)  (ws + 51208256);              // 8192

    hipMemsetAsync(ws + 51191808, 0, 8192 + 64, stream); // flag + qcnt only

    dim3 blk(256);
    cast_bf16_vec<<<dim3(BATCH_N * EMB_D_ / 4 / 256), blk, 0, stream>>>(emb, embb, BATCH_N * EMB_D_ / 4);
    cast_bf16_vec<<<dim3(QUEUE_N * PROJ_D_ / 4 / 256), blk, 0, stream>>>(queue, qb, QUEUE_N * PROJ_D_ / 4);
    transpose_cast<<<dim3(EMB_D_ / 64, EMB_D_ / 64), blk, 0, stream>>>(W1, w1t, EMB_D_, EMB_D_);
    transpose_cast<<<dim3(PROJ_D_ / 64, EMB_D_ / 64), blk, 0, stream>>>(W2, w2t, EMB_D_, PROJ_D_);
    count_qlab<<<dim3(32), blk, 0, stream>>>(qlab, qcnt);
    mfma_nt_k<short, true ><<<dim3(EMB_D_ / 128, BATCH_N / 128), blk, 0, stream>>>(embb, w1t, b1, hbf, EMB_D_, EMB_D_);
    mfma_nt_k<float, false><<<dim3(PROJ_D_ / 128, BATCH_N / 128), blk, 0, stream>>>(hbf, w2t, b2, z, PROJ_D_, EMB_D_);
    normalize_cast<<<BATCH_N, PROJ_D_, 0, stream>>>(z, zb);
    // fused queue GEMM + LDS-aggregated per-row histograms (no sims buffer)
    mfma_qhist<<<dim3(NCHUNK, BATCH_N / 128), blk, 0, stream>>>(zb, qb, ghist, gfexp, labels, qlab);
    queue_lse_reduce<<<BATCH_N / 4, blk, 0, stream>>>(ghist, gfexp, qcnt, labels, lseq, flag);
    topk_lse_fallback<<<BATCH_N, 256, 0, stream>>>(zb, qb, labels, qlab, qcnt, flag, lseq);
    mfma_nt_plain<<<dim3(BATCH_N / 128, BATCH_N / 128), blk, 0, stream>>>(zb, zb, Sbuf, BATCH_N);
    batch_row_loss<<<BATCH_N / 4, 256, 0, stream>>>(Sbuf, labels, lseq, partb, cntb);
    finalize_loss<<<1, 256, 0, stream>>>(partb, cntb, (float*)d_out);
}

// Round 10
// 215.811 us; speedup vs baseline: 2.0890x; 1.1987x over previous
//
#include <hip/hip_runtime.h>
#include <hip/hip_fp16.h>

#define BATCH_N   2048
#define EMB_D_    768
#define PROJ_D_   128
#define QUEUE_N   32768
#define HARD_K_   512
static constexpr float INV_T  = 1.0f / 0.07f;
static constexpr float WLO    = 0.12f;              // code-0 boundary (512th opp val ~0.164)
static constexpr float S8ENC  = 255.0f / 0.88f;     // encode scale
static constexpr float BINW   = 0.88f / 255.0f;     // code bin width

typedef __attribute__((ext_vector_type(8))) short short8;
typedef __attribute__((ext_vector_type(4))) short short4v;
typedef __attribute__((ext_vector_type(4))) float f32x4;

__device__ __forceinline__ unsigned short f2bf(float f) {
    unsigned u = __float_as_uint(f);
    unsigned r = u + 0x7fffu + ((u >> 16) & 1u);   // RNE
    return (unsigned short)(r >> 16);
}
__device__ __forceinline__ float bf2f(short s) {
    return __uint_as_float(((unsigned)(unsigned short)s) << 16);
}
__device__ __forceinline__ int opp_of(int mylab, const int* __restrict__ qcnt) {
    const int same = (mylab == 0) ? qcnt[0] : ((mylab == 1) ? qcnt[1] : 0);
    return qcnt[2] - same;
}

// ---------------------------------------------------------------------------
// bf16 MFMA NT GEMM, K=128 in LDS, plain fp32 store (S matrix). Verified r2-r9.
// ---------------------------------------------------------------------------
__global__ void __launch_bounds__(256) mfma_nt_plain(const short* __restrict__ Ab,
                                                     const short* __restrict__ Bb,
                                                     float* __restrict__ C, int N) {
    __shared__ __align__(16) short As[128 * 128];
    __shared__ __align__(16) short Bs[128 * 128];
    const int t = threadIdx.x;
    const int lane = t & 63, wv = t >> 6;
    const int l16 = lane & 15, l4 = lane >> 4;
    const int m0 = blockIdx.y * 128, n0 = blockIdx.x * 128;

    #pragma unroll
    for (int it = 0; it < 8; ++it) {
        const int r = it * 4 + wv, row = r * 4 + l4, cg = l16 ^ (row & 15);
        __builtin_amdgcn_global_load_lds(
            (const __attribute__((address_space(1))) void*)(Ab + (size_t)(m0 + row) * 128 + cg * 8),
            (__attribute__((address_space(3))) void*)(As + r * 512), 16, 0, 0);
    }
    #pragma unroll
    for (int it = 0; it < 8; ++it) {
        const int r = it * 4 + wv, row = r * 4 + l4, cg = l16 ^ (row & 15);
        __builtin_amdgcn_global_load_lds(
            (const __attribute__((address_space(1))) void*)(Bb + (size_t)(n0 + row) * 128 + cg * 8),
            (__attribute__((address_space(3))) void*)(Bs + r * 512), 16, 0, 0);
    }
    __syncthreads();

    const int wm = (wv & 1) * 64, wn = (wv >> 1) * 64;
    f32x4 acc[4][4];
    #pragma unroll
    for (int i = 0; i < 4; ++i)
        #pragma unroll
        for (int j = 0; j < 4; ++j) acc[i][j] = f32x4{0.f, 0.f, 0.f, 0.f};

    #pragma unroll
    for (int ks = 0; ks < 4; ++ks) {
        short8 af[4], bfr[4];
        const int ch = (ks * 4 + l4) ^ l16;
        #pragma unroll
        for (int i = 0; i < 4; ++i) {
            af[i]  = *(const short8*)(As + (wm + i * 16 + l16) * 128 + ch * 8);
            bfr[i] = *(const short8*)(Bs + (wn + i * 16 + l16) * 128 + ch * 8);
        }
        #pragma unroll
        for (int i = 0; i < 4; ++i)
            #pragma unroll
            for (int j = 0; j < 4; ++j)
                acc[i][j] = __builtin_amdgcn_mfma_f32_16x16x32_bf16(af[i], bfr[j], acc[i][j], 0, 0, 0);
    }
    #pragma unroll
    for (int i = 0; i < 4; ++i)
        #pragma unroll
        for (int r = 0; r < 4; ++r) {
            const int m = m0 + wm + i * 16 + l4 * 4 + r;
            #pragma unroll
            for (int j = 0; j < 4; ++j)
                C[(size_t)m * N + n0 + wn + j * 16 + l16] = acc[i][j][r];
        }
}

// ---------------------------------------------------------------------------
// Masked queue GEMM -> u8 linear codes. code 0 = masked / v < WLO;
// code c in 1..255 covers v in [WLO+(c-1)*BINW, WLO+c*BINW). Same verified
// GEMM body as r7's mfma_nt; epilogue stores 1 byte/element (half of fp16).
// ---------------------------------------------------------------------------
__global__ void __launch_bounds__(256) mfma_mask8(const short* __restrict__ Ab,
                                                  const short* __restrict__ Bb,
                                                  unsigned char* __restrict__ codes,
                                                  const int* __restrict__ labA,
                                                  const int* __restrict__ labB) {
    __shared__ __align__(16) short As[128 * 128];
    __shared__ __align__(16) short Bs[128 * 128];
    const int t = threadIdx.x;
    const int lane = t & 63, wv = t >> 6;
    const int l16 = lane & 15, l4 = lane >> 4;
    const int m0 = blockIdx.y * 128, n0 = blockIdx.x * 128;

    #pragma unroll
    for (int it = 0; it < 8; ++it) {
        const int r = it * 4 + wv, row = r * 4 + l4, cg = l16 ^ (row & 15);
        __builtin_amdgcn_global_load_lds(
            (const __attribute__((address_space(1))) void*)(Ab + (size_t)(m0 + row) * 128 + cg * 8),
            (__attribute__((address_space(3))) void*)(As + r * 512), 16, 0, 0);
    }
    #pragma unroll
    for (int it = 0; it < 8; ++it) {
        const int r = it * 4 + wv, row = r * 4 + l4, cg = l16 ^ (row & 15);
        __builtin_amdgcn_global_load_lds(
            (const __attribute__((address_space(1))) void*)(Bb + (size_t)(n0 + row) * 128 + cg * 8),
            (__attribute__((address_space(3))) void*)(Bs + r * 512), 16, 0, 0);
    }
    __syncthreads();

    const int wm = (wv & 1) * 64, wn = (wv >> 1) * 64;
    f32x4 acc[4][4];
    #pragma unroll
    for (int i = 0; i < 4; ++i)
        #pragma unroll
        for (int j = 0; j < 4; ++j) acc[i][j] = f32x4{0.f, 0.f, 0.f, 0.f};

    #pragma unroll
    for (int ks = 0; ks < 4; ++ks) {
        short8 af[4], bfr[4];
        const int ch = (ks * 4 + l4) ^ l16;
        #pragma unroll
        for (int i = 0; i < 4; ++i) {
            af[i]  = *(const short8*)(As + (wm + i * 16 + l16) * 128 + ch * 8);
            bfr[i] = *(const short8*)(Bs + (wn + i * 16 + l16) * 128 + ch * 8);
        }
        #pragma unroll
        for (int i = 0; i < 4; ++i)
            #pragma unroll
            for (int j = 0; j < 4; ++j)
                acc[i][j] = __builtin_amdgcn_mfma_f32_16x16x32_bf16(af[i], bfr[j], acc[i][j], 0, 0, 0);
    }

    int qn[4];
    #pragma unroll
    for (int j = 0; j < 4; ++j) qn[j] = labB[n0 + wn + j * 16 + l16];
    #pragma unroll
    for (int i = 0; i < 4; ++i) {
        #pragma unroll
        for (int r = 0; r < 4; ++r) {
            const int m  = m0 + wm + i * 16 + l4 * 4 + r;
            const int lm = labA[m];
            #pragma unroll
            for (int j = 0; j < 4; ++j) {
                const int n = n0 + wn + j * 16 + l16;
                const float v = acc[i][j][r];
                unsigned char code = 0;
                if (qn[j] != lm && qn[j] >= 0 && v >= WLO)
                    code = (unsigned char)(1 + min((int)((v - WLO) * S8ENC), 254));
                codes[(size_t)m * QUEUE_N + n] = code;
            }
        }
    }
}

// ---------------------------------------------------------------------------
// bf16 MFMA NT GEMM with K-loop, fused bias(+ReLU). Verified r3-r9 (MLP).
// ---------------------------------------------------------------------------
template<typename OutT, bool RELU>
__global__ void __launch_bounds__(256) mfma_nt_k(const short* __restrict__ Ab,
                                                 const short* __restrict__ Bb,
                                                 const float* __restrict__ bias,
                                                 OutT* __restrict__ C,
                                                 int N, int K) {
    __shared__ __align__(16) short As[128 * 128];
    __shared__ __align__(16) short Bs[128 * 128];
    const int t = threadIdx.x;
    const int lane = t & 63, wv = t >> 6;
    const int l16 = lane & 15, l4 = lane >> 4;
    const int m0 = blockIdx.y * 128, n0 = blockIdx.x * 128;
    const int wm = (wv & 1) * 64, wn = (wv >> 1) * 64;

    f32x4 acc[4][4];
    #pragma unroll
    for (int i = 0; i < 4; ++i)
        #pragma unroll
        for (int j = 0; j < 4; ++j) acc[i][j] = f32x4{0.f, 0.f, 0.f, 0.f};

    for (int kb = 0; kb < K; kb += 128) {
        __syncthreads();
        #pragma unroll
        for (int it = 0; it < 8; ++it) {
            const int r = it * 4 + wv, row = r * 4 + l4, cg = l16 ^ (row & 15);
            __builtin_amdgcn_global_load_lds(
                (const __attribute__((address_space(1))) void*)(Ab + (size_t)(m0 + row) * K + kb + cg * 8),
                (__attribute__((address_space(3))) void*)(As + r * 512), 16, 0, 0);
        }
        #pragma unroll
        for (int it = 0; it < 8; ++it) {
            const int r = it * 4 + wv, row = r * 4 + l4, cg = l16 ^ (row & 15);
            __builtin_amdgcn_global_load_lds(
                (const __attribute__((address_space(1))) void*)(Bb + (size_t)(n0 + row) * K + kb + cg * 8),
                (__attribute__((address_space(3))) void*)(Bs + r * 512), 16, 0, 0);
        }
        __syncthreads();
        #pragma unroll
        for (int ks = 0; ks < 4; ++ks) {
            short8 af[4], bfr[4];
            const int ch = (ks * 4 + l4) ^ l16;
            #pragma unroll
            for (int i = 0; i < 4; ++i) {
                af[i]  = *(const short8*)(As + (wm + i * 16 + l16) * 128 + ch * 8);
                bfr[i] = *(const short8*)(Bs + (wn + i * 16 + l16) * 128 + ch * 8);
            }
            #pragma unroll
            for (int i = 0; i < 4; ++i)
                #pragma unroll
                for (int j = 0; j < 4; ++j)
                    acc[i][j] = __builtin_amdgcn_mfma_f32_16x16x32_bf16(af[i], bfr[j], acc[i][j], 0, 0, 0);
        }
    }

    float bsv[4];
    #pragma unroll
    for (int j = 0; j < 4; ++j) bsv[j] = bias[n0 + wn + j * 16 + l16];
    #pragma unroll
    for (int i = 0; i < 4; ++i)
        #pragma unroll
        for (int r = 0; r < 4; ++r) {
            const int m = m0 + wm + i * 16 + l4 * 4 + r;
            #pragma unroll
            for (int j = 0; j < 4; ++j) {
                const int n = n0 + wn + j * 16 + l16;
                float v = acc[i][j][r] + bsv[j];
                if (RELU) v = fmaxf(v, 0.0f);
                if constexpr (sizeof(OutT) == 2) ((short*)C)[(size_t)m * N + n] = (short)f2bf(v);
                else                             ((float*)C)[(size_t)m * N + n] = v;
            }
        }
}

// ---------------------------------------------------------------------------
// z-GEMM with FUSED bias + row-L2-normalize + bf16 cast. N=128 so each block
// owns complete rows: per-row sumsq via 16-lane shfl + LDS atomics, rsqrt,
// store bf16 zb directly (no fp32 z buffer, no normalize kernel).
// ---------------------------------------------------------------------------
__global__ void __launch_bounds__(256) mfma_z_norm(const short* __restrict__ Ab,
                                                   const short* __restrict__ Bb,
                                                   const float* __restrict__ bias,
                                                   short* __restrict__ zb) {
    __shared__ __align__(16) short As[128 * 128];
    __shared__ __align__(16) short Bs[128 * 128];
    __shared__ float ssq[128];
    const int t = threadIdx.x;
    const int lane = t & 63, wv = t >> 6;
    const int l16 = lane & 15, l4 = lane >> 4;
    const int m0 = blockIdx.x * 128;
    const int wm = (wv & 1) * 64, wn = (wv >> 1) * 64;
    const int K = EMB_D_;

    if (t < 128) ssq[t] = 0.0f;   // K-loop barriers order this before epilogue use

    f32x4 acc[4][4];
    #pragma unroll
    for (int i = 0; i < 4; ++i)
        #pragma unroll
        for (int j = 0; j < 4; ++j) acc[i][j] = f32x4{0.f, 0.f, 0.f, 0.f};

    for (int kb = 0; kb < K; kb += 128) {
        __syncthreads();
        #pragma unroll
        for (int it = 0; it < 8; ++it) {
            const int r = it * 4 + wv, row = r * 4 + l4, cg = l16 ^ (row & 15);
            __builtin_amdgcn_global_load_lds(
                (const __attribute__((address_space(1))) void*)(Ab + (size_t)(m0 + row) * K + kb + cg * 8),
                (__attribute__((address_space(3))) void*)(As + r * 512), 16, 0, 0);
        }
        #pragma unroll
        for (int it = 0; it < 8; ++it) {
            const int r = it * 4 + wv, row = r * 4 + l4, cg = l16 ^ (row & 15);
            __builtin_amdgcn_global_load_lds(
                (const __attribute__((address_space(1))) void*)(Bb + (size_t)(row) * K + kb + cg * 8),
                (__attribute__((address_space(3))) void*)(Bs + r * 512), 16, 0, 0);
        }
        __syncthreads();
        #pragma unroll
        for (int ks = 0; ks < 4; ++ks) {
            short8 af[4], bfr[4];
            const int ch = (ks * 4 + l4) ^ l16;
            #pragma unroll
            for (int i = 0; i < 4; ++i) {
                af[i]  = *(const short8*)(As + (wm + i * 16 + l16) * 128 + ch * 8);
                bfr[i] = *(const short8*)(Bs + (wn + i * 16 + l16) * 128 + ch * 8);
            }
            #pragma unroll
            for (int i = 0; i < 4; ++i)
                #pragma unroll
                for (int j = 0; j < 4; ++j)
                    acc[i][j] = __builtin_amdgcn_mfma_f32_16x16x32_bf16(af[i], bfr[j], acc[i][j], 0, 0, 0);
        }
    }

    float bsv[4];
    #pragma unroll
    for (int j = 0; j < 4; ++j) bsv[j] = bias[wn + j * 16 + l16];
    #pragma unroll
    for (int i = 0; i < 4; ++i)
        #pragma unroll
        for (int r = 0; r < 4; ++r) {
            float p = 0.0f;
            #pragma unroll
            for (int j = 0; j < 4; ++j) {
                acc[i][j][r] += bsv[j];
                p += acc[i][j][r] * acc[i][j][r];
            }
            // reduce across the 16 lanes (same l4 group) holding this row's cols
            #pragma unroll
            for (int o = 8; o > 0; o >>= 1) p += __shfl_xor(p, o);
            if (l16 == 0) atomicAdd(&ssq[wm + i * 16 + l4 * 4 + r], p);
        }
    __syncthreads();
    #pragma unroll
    for (int i = 0; i < 4; ++i)
        #pragma unroll
        for (int r = 0; r < 4; ++r) {
            const int lrow = wm + i * 16 + l4 * 4 + r;
            const float inv = rsqrtf(ssq[lrow]);
            #pragma unroll
            for (int j = 0; j < 4; ++j)
                zb[(size_t)(m0 + lrow) * PROJ_D_ + wn + j * 16 + l16] =
                    (short)f2bf(acc[i][j][r] * inv);
        }
}

// ---------------------------------------------------------------------------
// Merged prep: emb cast (blocks 0..1535) + queue cast (1536..5631) +
// queue-label census (5632..5663). One launch.
// ---------------------------------------------------------------------------
__global__ void __launch_bounds__(256) prep(const float* __restrict__ emb, short* __restrict__ embb,
                                            const float* __restrict__ queue, short* __restrict__ qb,
                                            const int* __restrict__ qlab, int* __restrict__ qcnt) {
    const int b = blockIdx.x, t = threadIdx.x;
    if (b < 1536) {
        const int i = b * 256 + t;
        const float4 f = ((const float4*)emb)[i];
        short4v o = {(short)f2bf(f.x), (short)f2bf(f.y), (short)f2bf(f.z), (short)f2bf(f.w)};
        ((short4v*)embb)[i] = o;
    } else if (b < 5632) {
        const int i = (b - 1536) * 256 + t;
        const float4 f = ((const float4*)queue)[i];
        short4v o = {(short)f2bf(f.x), (short)f2bf(f.y), (short)f2bf(f.z), (short)f2bf(f.w)};
        ((short4v*)qb)[i] = o;
    } else {
        const int i = (b - 5632) * 256 + t;
        int c0 = 0, c1 = 0, cv = 0;
        for (int j = i; j < QUEUE_N; j += 8192) {
            const int q = qlab[j];
            c0 += (q == 0); c1 += (q == 1); cv += (q >= 0);
        }
        #pragma unroll
        for (int o = 32; o > 0; o >>= 1) {
            c0 += __shfl_xor(c0, o); c1 += __shfl_xor(c1, o); cv += __shfl_xor(cv, o);
        }
        if ((t & 63) == 0) {
            atomicAdd(&qcnt[0], c0); atomicAdd(&qcnt[1], c1); atomicAdd(&qcnt[2], cv);
        }
    }
}

// ---------------------------------------------------------------------------
// Merged W1/W2 transpose+cast: blocks 0..143 -> W1 (768x768), 144..167 -> W2.
// ---------------------------------------------------------------------------
__global__ void __launch_bounds__(256) transpose_cast2(const float* __restrict__ W1, short* __restrict__ w1t,
                                                       const float* __restrict__ W2, short* __restrict__ w2t) {
    __shared__ float tile[64][65];
    const int bid = blockIdx.x;
    const float* A; short* At; int R, C, bx, by;
    if (bid < 144) { A = W1; At = w1t; R = EMB_D_; C = EMB_D_;  bx = (bid % 12) * 64; by = (bid / 12) * 64; }
    else { const int b2 = bid - 144; A = W2; At = w2t; R = EMB_D_; C = PROJ_D_; bx = (b2 & 1) * 64; by = (b2 >> 1) * 64; }
    const int t = threadIdx.x, tc = t & 63, tg = t >> 6;
    #pragma unroll
    for (int i = 0; i < 16; i++) {
        const int r = tg * 16 + i;
        tile[r][tc] = A[(size_t)(by + r) * C + bx + tc];
    }
    __syncthreads();
    #pragma unroll
    for (int i = 0; i < 16; i++) {
        const int r = tg * 16 + i;
        At[(size_t)(bx + r) * R + by + tc] = (short)f2bf(tile[tc][r]);
    }
}

// ---------------------------------------------------------------------------
// u8-code top-512 lse. One block per row: 256-bin byte histogram (skip 0),
// suffix-scan 1 bin/thread, crossing, lse from exact per-code counts x
// bin-center exp. Composition math verified r5-r9; bin width 0.0035.
// ---------------------------------------------------------------------------
__global__ void __launch_bounds__(256) topk_lse_u8(const unsigned char* __restrict__ codes,
                                                   const int* __restrict__ qcnt,
                                                   const int* __restrict__ labels,
                                                   float* __restrict__ lseq,
                                                   int* __restrict__ flag) {
    const int row = blockIdx.x, t = threadIdx.x;
    __shared__ int hist[256];
    __shared__ int suf[256];
    __shared__ int s_bin;
    __shared__ float scf[4];
    hist[t] = 0;
    __syncthreads();

    const uint4* rowp = (const uint4*)(codes + (size_t)row * QUEUE_N);
    #pragma unroll
    for (int k = 0; k < 8; k++) {
        const uint4 u = rowp[k * 256 + t];
        const unsigned w[4] = {u.x, u.y, u.z, u.w};
        #pragma unroll
        for (int q = 0; q < 4; q++)
            #pragma unroll
            for (int s = 0; s < 4; s++) {
                const int c = (w[q] >> (8 * s)) & 0xFF;
                if (c) atomicAdd(&hist[c], 1);
            }
    }
    __syncthreads();

    suf[t] = hist[t];
    __syncthreads();
    for (int off = 1; off < 256; off <<= 1) {
        int add = (t + off < 256) ? suf[t + off] : 0;
        __syncthreads();
        suf[t] += add;
        __syncthreads();
    }
    const int total = suf[1];
    const int opp   = opp_of(labels[row], qcnt);
    if (total < HARD_K_ || opp < HARD_K_) {
        if (t == 0) flag[row] = 0;
        return;
    }
    {
        const int above = (t < 255) ? suf[t + 1] : 0;
        if (suf[t] >= HARD_K_ && above < HARD_K_) s_bin = t;
    }
    __syncthreads();
    const int b = s_bin;

    float e = 0.0f;
    if (t > b && hist[t]) e = (float)hist[t] * __expf((WLO + ((float)t - 0.5f) * BINW - 1.0f) * INV_T);
    #pragma unroll
    for (int o = 32; o > 0; o >>= 1) e += __shfl_xor(e, o);
    if ((t & 63) == 0) scf[t >> 6] = e;
    __syncthreads();
    if (t == 0) {
        const float Eab  = scf[0] + scf[1] + scf[2] + scf[3];
        const int   cab  = (b < 255) ? suf[b + 1] : 0;
        const float ebin = __expf((WLO + ((float)b - 0.5f) * BINW - 1.0f) * INV_T);
        const float sadj = Eab + (float)(HARD_K_ - cab) * ebin;
        lseq[row] = INV_T + __logf(sadj);
        flag[row] = 1;
    }
}

// ---------------------------------------------------------------------------
// Histogram crossing search (verified r1-r9; used by fallback)
// ---------------------------------------------------------------------------
__device__ __forceinline__ void find_crossing(int* hist, int* grp, int target,
                                              int* s_bin, int* s_chi) {
    const int t = threadIdx.x;
    const int b0 = hist[4*t], b1 = hist[4*t+1], b2 = hist[4*t+2], b3 = hist[4*t+3];
    grp[t] = b0 + b1 + b2 + b3;
    __syncthreads();
    for (int off = 1; off < 256; off <<= 1) {
        int add = (t + off < 256) ? grp[t + off] : 0;
        __syncthreads();
        grp[t] += add;
        __syncthreads();
    }
    int cab = (t < 255) ? grp[t + 1] : 0;
    const int hb[4] = {b0, b1, b2, b3};
    #pragma unroll
    for (int i = 3; i >= 0; i--) {
        const int h = hb[i];
        if (cab < target && cab + h >= target) { *s_bin = 4*t + i; *s_chi = cab; }
        cab += h;
    }
    __syncthreads();
}

// iterate all 128 packed-half2 values
#define FOR_ALL_VALS(BODY)                                                   \
    _Pragma("unroll")                                                        \
    for (int _k = 0; _k < 64; _k++) {                                        \
        const float2 _f = __half22float2(*(const __half2*)&dv[_k]);          \
        { const float v = _f.x; BODY }                                       \
        { const float v = _f.y; BODY }                                       \
    }

// ---------------------------------------------------------------------------
// Exact fallback (verified r5-r9; normally zero rows). Recomputes from zb/qb.
// ---------------------------------------------------------------------------
__global__ void __launch_bounds__(256) topk_lse_fallback(const short* __restrict__ zb,
                                                         const short* __restrict__ qb,
                                                         const int* __restrict__ labels,
                                                         const int* __restrict__ qlab,
                                                         const int* __restrict__ qcnt,
                                                         const int* __restrict__ flag,
                                                         float* __restrict__ lseq) {
    const int row = blockIdx.x, t = threadIdx.x;
    if (flag[row]) return;
    const int opp = opp_of(labels[row], qcnt);

    __shared__ float zrow[128];
    __shared__ int hist[1024];
    __shared__ int grp[256];
    __shared__ int s_bin, s_chi, s_bin2, s_chi2;
    __shared__ float scf[4]; __shared__ int sci[4];
    if (t < 128) zrow[t] = bf2f(zb[(size_t)row * 128 + t]);
    __syncthreads();

    const int mylab = labels[row];
    unsigned dv[64];
    float rm = -1e30f, rs = 0.0f;
    for (int k = 0; k < 128; k++) {
        const int j = t + 256 * k;
        float d = 0.0f;
        #pragma unroll
        for (int c = 0; c < 16; ++c) {
            const short8 qv = *(const short8*)(qb + (size_t)j * 128 + c * 8);
            #pragma unroll
            for (int e = 0; e < 8; ++e) d += zrow[c * 8 + e] * bf2f(qv[e]);
        }
        if (j < HARD_K_) {
            const float sv = d * INV_T;
            if (sv > rm) { rs = rs * __expf(rm - sv) + 1.0f; rm = sv; }
            else         { rs += __expf(sv - rm); }
        }
        const int q = qlab[j];
        const float mv = (q != mylab && q >= 0) ? d : -65504.0f;
        const __half h = __float2half(mv);
        unsigned short* p = (unsigned short*)&dv[k >> 1];
        p[k & 1] = *(const unsigned short*)&h;
    }

    if (opp == 0) {
        #pragma unroll
        for (int o = 32; o > 0; o >>= 1) {
            const float om = __shfl_xor(rm, o), os = __shfl_xor(rs, o);
            const float nm = fmaxf(rm, om);
            rs = rs * __expf(rm - nm) + os * __expf(om - nm);
            rm = nm;
        }
        if ((t & 63) == 0) { scf[t >> 6] = rm; ((float*)sci)[t >> 6] = rs; }
        __syncthreads();
        if (t == 0) {
            float M = -1e30f, Sx = 0.0f;
            for (int w = 0; w < 4; w++) {
                const float nm = fmaxf(M, scf[w]);
                Sx = Sx * __expf(M - nm) + ((float*)sci)[w] * __expf(scf[w] - nm);
                M = nm;
            }
            lseq[row] = M + __logf(Sx);
        }
        return;
    }
    if (opp < HARD_K_) {
        float mm = -1e30f, ss = 0.0f;
        FOR_ALL_VALS(
            if (v > -60000.0f) {
                const float sv = v * INV_T;
                if (sv > mm) { ss = ss * __expf(mm - sv) + 1.0f; mm = sv; }
                else         { ss += __expf(sv - mm); }
            } )
        #pragma unroll
        for (int o = 32; o > 0; o >>= 1) {
            const float om = __shfl_xor(mm, o), os = __shfl_xor(ss, o);
            const float nm = fmaxf(mm, om);
            ss = ss * __expf(mm - nm) + os * __expf(om - nm);
            mm = nm;
        }
        if ((t & 63) == 0) { scf[t >> 6] = mm; ((float*)sci)[t >> 6] = ss; }
        __syncthreads();
        if (t == 0) {
            float M = -1e30f, Sx = 0.0f;
            for (int w = 0; w < 4; w++) {
                const float nm = fmaxf(M, scf[w]);
                Sx = Sx * __expf(M - nm) + ((float*)sci)[w] * __expf(scf[w] - nm);
                M = nm;
            }
            lseq[row] = M + __logf(Sx);
        }
        return;
    }

    float mloc = -1e30f;
    FOR_ALL_VALS( mloc = fmaxf(mloc, v); )
    #pragma unroll
    for (int o = 32; o > 0; o >>= 1) mloc = fmaxf(mloc, __shfl_xor(mloc, o));
    if ((t & 63) == 0) scf[t >> 6] = mloc;
    __syncthreads();
    const float m = fmaxf(fmaxf(scf[0], scf[1]), fmaxf(scf[2], scf[3]));

    int c1 = 0, c2 = 0;
    const float w1 = m - 0.25f, w2 = m - 1.0f;
    FOR_ALL_VALS( c1 += (v >= w1); c2 += (v >= w2); )
    #pragma unroll
    for (int o = 32; o > 0; o >>= 1) { c1 += __shfl_xor(c1, o); c2 += __shfl_xor(c2, o); }
    if ((t & 63) == 0) { sci[t >> 6] = c1; }
    __syncthreads();
    const int C1 = sci[0] + sci[1] + sci[2] + sci[3];
    __syncthreads();
    if ((t & 63) == 0) { sci[t >> 6] = c2; }
    __syncthreads();
    const int C2 = sci[0] + sci[1] + sci[2] + sci[3];

    float lo;
    if      (C1 >= HARD_K_) lo = w1;
    else if (C2 >= HARD_K_) lo = w2;
    else                    lo = -1.01f;
    const float range = m - lo;
    const float scale = 1024.0f / range;

    for (int k = t; k < 1024; k += 256) hist[k] = 0;
    __syncthreads();
    FOR_ALL_VALS(
        if (v >= lo) {
            const float bf = fminf((v - lo) * scale, 1023.0f);
            atomicAdd(&hist[(int)bf], 1);
        } )
    __syncthreads();
    find_crossing(hist, grp, HARD_K_, &s_bin, &s_chi);
    const int   bin1 = s_bin, chi1 = s_chi;
    const float binw = range * (1.0f / 1024.0f);
    const float lo1  = lo + bin1 * binw;
    const float ssc  = 1024.0f / binw;

    for (int k = t; k < 1024; k += 256) hist[k] = 0;
    __syncthreads();
    FOR_ALL_VALS(
        if (v >= lo) {
            const float bf = fminf((v - lo) * scale, 1023.0f);
            if ((int)bf == bin1) {
                const float sf = fminf(fmaxf((v - lo1) * ssc, 0.0f), 1023.0f);
                atomicAdd(&hist[(int)sf], 1);
            }
        } )
    __syncthreads();
    find_crossing(hist, grp, HARD_K_ - chi1, &s_bin2, &s_chi2);
    const float thr = lo1 + s_bin2 * (binw * (1.0f / 1024.0f));

    float sl = 0.0f; int cg = 0;
    FOR_ALL_VALS( if (v > thr) { cg++; sl += __expf((v - m) * INV_T); } )
    #pragma unroll
    for (int o = 32; o > 0; o >>= 1) { sl += __shfl_xor(sl, o); cg += __shfl_xor(cg, o); }
    if ((t & 63) == 0) { scf[t >> 6] = sl; sci[t >> 6] = cg; }
    __syncthreads();
    if (t == 0) {
        const float slt = scf[0] + scf[1] + scf[2] + scf[3];
        const int   cgt = sci[0] + sci[1] + sci[2] + sci[3];
        const float sadj = slt + ((float)HARD_K_ - (float)cgt) * __expf((thr - m) * INV_T);
        lseq[row] = m * INV_T + __logf(sadj);
    }
}

// ---------------------------------------------------------------------------
// Batch lse + positive-pair loss, one WAVE per row (verified r6-r9).
// ---------------------------------------------------------------------------
__global__ void __launch_bounds__(256) batch_row_loss(const float* __restrict__ S,
                                                      const int* __restrict__ labels,
                                                      const float* __restrict__ lse_queue,
                                                      float* __restrict__ part_out,
                                                      int* __restrict__ cnt_out) {
    const int t = threadIdx.x;
    const int wv = t >> 6, lane = t & 63;
    const int row = blockIdx.x * 4 + wv;
    __shared__ int lab[BATCH_N];
    for (int k = t; k < BATCH_N; k += 256) lab[k] = labels[k];
    __syncthreads();
    const int myLab = lab[row];
    const float4* rp4 = (const float4*)(S + (size_t)row * BATCH_N);
    const int4*   lb4 = (const int4*)lab;

    float v[32]; int lb[32];
    #pragma unroll
    for (int kk = 0; kk < 8; kk++) {
        const float4 f = rp4[lane + 64 * kk];
        const int4   l = lb4[lane + 64 * kk];
        v[4*kk+0] = f.x; v[4*kk+1] = f.y; v[4*kk+2] = f.z; v[4*kk+3] = f.w;
        lb[4*kk+0] = l.x; lb[4*kk+1] = l.y; lb[4*kk+2] = l.z; lb[4*kk+3] = l.w;
    }

    const float REF = INV_T;
    float sneg = 0.0f;
    #pragma unroll
    for (int k = 0; k < 32; k++) {
        const float ev = __expf(v[k] * INV_T - REF);
        sneg += (lb[k] != myLab) ? ev : 0.0f;
    }
    #pragma unroll
    for (int o = 32; o > 0; o >>= 1) sneg += __shfl_xor(sneg, o);
    const float lseb = (sneg > 0.0f) ? REF + __logf(sneg) : -1e30f;
    const float Lq = lse_queue[row];
    const float mx0 = fmaxf(lseb, Lq), mn0 = fminf(lseb, Lq);
    const float L = mx0 + __logf(1.0f + __expf(mn0 - mx0));

    float part = 0.0f; int cnt = 0;
    #pragma unroll
    for (int k = 0; k < 32; k++) {
        const int j = (lane + 64 * (k >> 2)) * 4 + (k & 3);
        if (lb[k] == myLab && j != row) {
            const float sv = v[k] * INV_T;
            const float mx = fmaxf(sv, L), mn = fminf(sv, L);
            part += (mx - sv) + __logf(1.0f + __expf(mn - mx));
            cnt++;
        }
    }
    #pragma unroll
    for (int o = 32; o > 0; o >>= 1) { part += __shfl_xor(part, o); cnt += __shfl_xor(cnt, o); }
    if (lane == 0) { part_out[row] = part; cnt_out[row] = cnt; }
}

// reduce 2048 per-row partials -> scalar loss. One block.
__global__ void __launch_bounds__(256) finalize_loss(const float* __restrict__ part,
                                                     const int* __restrict__ cnt,
                                                     float* __restrict__ out) {
    const int t = threadIdx.x;
    float s = 0.0f; int c = 0;
    #pragma unroll
    for (int k = 0; k < 8; k++) { s += part[t + 256 * k]; c += cnt[t + 256 * k]; }
    #pragma unroll
    for (int o = 32; o > 0; o >>= 1) { s += __shfl_xor(s, o); c += __shfl_xor(c, o); }
    __shared__ float sf[4]; __shared__ int sc[4];
    if ((t & 63) == 0) { sf[t >> 6] = s; sc[t >> 6] = c; }
    __syncthreads();
    if (t == 0) {
        const float st = sf[0] + sf[1] + sf[2] + sf[3];
        const int   ct = sc[0] + sc[1] + sc[2] + sc[3];
        out[0] = (ct > 0) ? (st / (float)ct) : 0.0f;
    }
}

// ---------------------------------------------------------------------------
extern "C" void kernel_launch(void* const* d_in, const int* in_sizes, int n_in,
                              void* d_out, int out_size, void* d_ws, size_t ws_size,
                              hipStream_t stream) {
    const float* emb    = (const float*)d_in[0];
    const int*   labels = (const int*)  d_in[1];
    const float* W1     = (const float*)d_in[2];
    const float* b1     = (const float*)d_in[3];
    const float* W2     = (const float*)d_in[4];
    const float* b2     = (const float*)d_in[5];
    const float* queue  = (const float*)d_in[6];
    const int*   qlab   = (const int*)  d_in[7];

    char* ws = (char*)d_ws;
    float*         Sbuf  = (float*)        (ws);              // 16777216
    unsigned char* codes = (unsigned char*)(ws + 16777216);   // 67108864
    short*         embb  = (short*)        (ws + 83886080);   // 3145728
    short*         hbf   = (short*)        (ws + 87031808);   // 3145728
    short*         zb    = (short*)        (ws + 90177536);   // 524288
    short*         qb    = (short*)        (ws + 90701824);   // 8388608
    short*         w1t   = (short*)        (ws + 99090432);   // 1179648
    short*         w2t   = (short*)        (ws + 100270080);  // 196608
    float*         lseq  = (float*)        (ws + 100466688);  // 8192
    int*           flag  = (int*)          (ws + 100474880);  // 8192
    int*           qcnt  = (int*)          (ws + 100483072);  // 64
    float*         partb = (float*)        (ws + 100483136);  // 8192
    int*           cntb  = (int*)          (ws + 100491328);  // 8192

    hipMemsetAsync(ws + 100474880, 0, 8192 + 64, stream);     // flag + qcnt

    dim3 blk(256);
    prep<<<dim3(5664), blk, 0, stream>>>(emb, embb, queue, qb, qlab, qcnt);
    transpose_cast2<<<dim3(168), blk, 0, stream>>>(W1, w1t, W2, w2t);
    mfma_nt_k<short, true><<<dim3(EMB_D_ / 128, BATCH_N / 128), blk, 0, stream>>>(embb, w1t, b1, hbf, EMB_D_, EMB_D_);
    mfma_z_norm<<<dim3(BATCH_N / 128), blk, 0, stream>>>(hbf, w2t, b2, zb);
    mfma_mask8<<<dim3(QUEUE_N / 128, BATCH_N / 128), blk, 0, stream>>>(zb, qb, codes, labels, qlab);
    topk_lse_u8<<<BATCH_N, blk, 0, stream>>>(codes, qcnt, labels, lseq, flag);
    topk_lse_fallback<<<BATCH_N, blk, 0, stream>>>(zb, qb, labels, qlab, qcnt, flag, lseq);
    mfma_nt_plain<<<dim3(BATCH_N / 128, BATCH_N / 128), blk, 0, stream>>>(zb, zb, Sbuf, BATCH_N);
    batch_row_loss<<<BATCH_N / 4, blk, 0, stream>>>(Sbuf, labels, lseq, partb, cntb);
    finalize_loss<<<1, blk, 0, stream>>>(partb, cntb, (float*)d_out);
}

// Round 11
// 181.357 us; speedup vs baseline: 2.4858x; 1.1900x over previous
//
#include <hip/hip_runtime.h>
#include <hip/hip_fp16.h>

#define BATCH_N   2048
#define EMB_D_    768
#define PROJ_D_   128
#define QUEUE_N   32768
#define HARD_K_   512
static constexpr float INV_T  = 1.0f / 0.07f;
static constexpr float WLO    = 0.12f;              // code-0 boundary (512th opp val ~0.164)
static constexpr float S8ENC  = 255.0f / 0.88f;     // encode scale
static constexpr float BINW   = 0.88f / 255.0f;     // code bin width

typedef __attribute__((ext_vector_type(8))) short short8;
typedef __attribute__((ext_vector_type(4))) short short4v;
typedef __attribute__((ext_vector_type(4))) float f32x4;

__device__ __forceinline__ unsigned short f2bf(float f) {
    unsigned u = __float_as_uint(f);
    unsigned r = u + 0x7fffu + ((u >> 16) & 1u);   // RNE
    return (unsigned short)(r >> 16);
}
__device__ __forceinline__ float bf2f(short s) {
    return __uint_as_float(((unsigned)(unsigned short)s) << 16);
}
__device__ __forceinline__ int opp_of(int mylab, const int* __restrict__ qcnt) {
    const int same = (mylab == 0) ? qcnt[0] : ((mylab == 1) ? qcnt[1] : 0);
    return qcnt[2] - same;
}

// ---------------------------------------------------------------------------
// bf16 MFMA NT GEMM, K=128 in LDS, plain fp32 store (S matrix). Verified r2-r10.
// ---------------------------------------------------------------------------
__global__ void __launch_bounds__(256) mfma_nt_plain(const short* __restrict__ Ab,
                                                     const short* __restrict__ Bb,
                                                     float* __restrict__ C, int N) {
    __shared__ __align__(16) short As[128 * 128];
    __shared__ __align__(16) short Bs[128 * 128];
    const int t = threadIdx.x;
    const int lane = t & 63, wv = t >> 6;
    const int l16 = lane & 15, l4 = lane >> 4;
    const int m0 = blockIdx.y * 128, n0 = blockIdx.x * 128;

    #pragma unroll
    for (int it = 0; it < 8; ++it) {
        const int r = it * 4 + wv, row = r * 4 + l4, cg = l16 ^ (row & 15);
        __builtin_amdgcn_global_load_lds(
            (const __attribute__((address_space(1))) void*)(Ab + (size_t)(m0 + row) * 128 + cg * 8),
            (__attribute__((address_space(3))) void*)(As + r * 512), 16, 0, 0);
    }
    #pragma unroll
    for (int it = 0; it < 8; ++it) {
        const int r = it * 4 + wv, row = r * 4 + l4, cg = l16 ^ (row & 15);
        __builtin_amdgcn_global_load_lds(
            (const __attribute__((address_space(1))) void*)(Bb + (size_t)(n0 + row) * 128 + cg * 8),
            (__attribute__((address_space(3))) void*)(Bs + r * 512), 16, 0, 0);
    }
    __syncthreads();

    const int wm = (wv & 1) * 64, wn = (wv >> 1) * 64;
    f32x4 acc[4][4];
    #pragma unroll
    for (int i = 0; i < 4; ++i)
        #pragma unroll
        for (int j = 0; j < 4; ++j) acc[i][j] = f32x4{0.f, 0.f, 0.f, 0.f};

    #pragma unroll
    for (int ks = 0; ks < 4; ++ks) {
        short8 af[4], bfr[4];
        const int ch = (ks * 4 + l4) ^ l16;
        #pragma unroll
        for (int i = 0; i < 4; ++i) {
            af[i]  = *(const short8*)(As + (wm + i * 16 + l16) * 128 + ch * 8);
            bfr[i] = *(const short8*)(Bs + (wn + i * 16 + l16) * 128 + ch * 8);
        }
        #pragma unroll
        for (int i = 0; i < 4; ++i)
            #pragma unroll
            for (int j = 0; j < 4; ++j)
                acc[i][j] = __builtin_amdgcn_mfma_f32_16x16x32_bf16(af[i], bfr[j], acc[i][j], 0, 0, 0);
    }
    #pragma unroll
    for (int i = 0; i < 4; ++i)
        #pragma unroll
        for (int r = 0; r < 4; ++r) {
            const int m = m0 + wm + i * 16 + l4 * 4 + r;
            #pragma unroll
            for (int j = 0; j < 4; ++j)
                C[(size_t)m * N + n0 + wn + j * 16 + l16] = acc[i][j][r];
        }
}

// ---------------------------------------------------------------------------
// Masked queue GEMM -> u8 codes, PACKED dword stores in a column-permuted
// layout (histogram consumer is order-invariant within a row). Per thread:
// pack j=0..3 (cols wn+j*16+l16) into one dword at m*QUEUE_N+n0+wn+l16*4.
// Encode: f = fma(v, S8ENC, addend[row-label][j]); hardware-saturating
// v_cvt_pk_u8_f32 -> byte. addend = -1e9 for masked -> code 0.
// (r10 lesson: epilogue was instruction-bound: 64 encodes + 64 byte stores.)
// NOTE: relies on labels in {0,1} (NUM_CLASSES=2), as do opp_of/fallback.
// ---------------------------------------------------------------------------
__global__ void __launch_bounds__(256) mfma_mask8(const short* __restrict__ Ab,
                                                  const short* __restrict__ Bb,
                                                  unsigned char* __restrict__ codes,
                                                  const int* __restrict__ labA,
                                                  const int* __restrict__ labB) {
    __shared__ __align__(16) short As[128 * 128];
    __shared__ __align__(16) short Bs[128 * 128];
    const int t = threadIdx.x;
    const int lane = t & 63, wv = t >> 6;
    const int l16 = lane & 15, l4 = lane >> 4;
    const int m0 = blockIdx.y * 128, n0 = blockIdx.x * 128;

    #pragma unroll
    for (int it = 0; it < 8; ++it) {
        const int r = it * 4 + wv, row = r * 4 + l4, cg = l16 ^ (row & 15);
        __builtin_amdgcn_global_load_lds(
            (const __attribute__((address_space(1))) void*)(Ab + (size_t)(m0 + row) * 128 + cg * 8),
            (__attribute__((address_space(3))) void*)(As + r * 512), 16, 0, 0);
    }
    #pragma unroll
    for (int it = 0; it < 8; ++it) {
        const int r = it * 4 + wv, row = r * 4 + l4, cg = l16 ^ (row & 15);
        __builtin_amdgcn_global_load_lds(
            (const __attribute__((address_space(1))) void*)(Bb + (size_t)(n0 + row) * 128 + cg * 8),
            (__attribute__((address_space(3))) void*)(Bs + r * 512), 16, 0, 0);
    }
    __syncthreads();

    const int wm = (wv & 1) * 64, wn = (wv >> 1) * 64;
    f32x4 acc[4][4];
    #pragma unroll
    for (int i = 0; i < 4; ++i)
        #pragma unroll
        for (int j = 0; j < 4; ++j) acc[i][j] = f32x4{0.f, 0.f, 0.f, 0.f};

    #pragma unroll
    for (int ks = 0; ks < 4; ++ks) {
        short8 af[4], bfr[4];
        const int ch = (ks * 4 + l4) ^ l16;
        #pragma unroll
        for (int i = 0; i < 4; ++i) {
            af[i]  = *(const short8*)(As + (wm + i * 16 + l16) * 128 + ch * 8);
            bfr[i] = *(const short8*)(Bs + (wn + i * 16 + l16) * 128 + ch * 8);
        }
        #pragma unroll
        for (int i = 0; i < 4; ++i)
            #pragma unroll
            for (int j = 0; j < 4; ++j)
                acc[i][j] = __builtin_amdgcn_mfma_f32_16x16x32_bf16(af[i], bfr[j], acc[i][j], 0, 0, 0);
    }

    // --- packed epilogue ---
    const float C0 = 1.0f - WLO * S8ENC;           // valid-value code offset
    float a0[4], a1[4];                            // addend if row-label==0 / ==1
    #pragma unroll
    for (int j = 0; j < 4; ++j) {
        const int q = labB[n0 + wn + j * 16 + l16];
        a0[j] = (q >= 0 && q != 0) ? C0 : -1e9f;
        a1[j] = (q >= 0 && q != 1) ? C0 : -1e9f;
    }
    int la[16];
    #pragma unroll
    for (int i = 0; i < 4; ++i)
        #pragma unroll
        for (int r = 0; r < 4; ++r)
            la[i * 4 + r] = labA[m0 + wm + i * 16 + l4 * 4 + r];

    #pragma unroll
    for (int i = 0; i < 4; ++i) {
        #pragma unroll
        for (int r = 0; r < 4; ++r) {
            const int m  = m0 + wm + i * 16 + l4 * 4 + r;
            const bool z = (la[i * 4 + r] == 0);
            unsigned pk = 0;
            #pragma unroll
            for (int j = 0; j < 4; ++j) {
                const float add = z ? a0[j] : a1[j];
                const float f = fmaf(acc[i][j][r], S8ENC, add);
#if __has_builtin(__builtin_amdgcn_cvt_pk_u8_f32)
                pk = __builtin_amdgcn_cvt_pk_u8_f32(f, j, pk);
#else
                const unsigned c = (unsigned)fminf(fmaxf(f, 0.0f), 255.0f);
                pk |= c << (8 * j);
#endif
            }
            *(unsigned*)(codes + (size_t)m * QUEUE_N + n0 + wn + l16 * 4) = pk;
        }
    }
}

// ---------------------------------------------------------------------------
// bf16 MFMA NT GEMM with K-loop, fused bias(+ReLU). Verified r3-r10 (MLP).
// ---------------------------------------------------------------------------
template<typename OutT, bool RELU>
__global__ void __launch_bounds__(256) mfma_nt_k(const short* __restrict__ Ab,
                                                 const short* __restrict__ Bb,
                                                 const float* __restrict__ bias,
                                                 OutT* __restrict__ C,
                                                 int N, int K) {
    __shared__ __align__(16) short As[128 * 128];
    __shared__ __align__(16) short Bs[128 * 128];
    const int t = threadIdx.x;
    const int lane = t & 63, wv = t >> 6;
    const int l16 = lane & 15, l4 = lane >> 4;
    const int m0 = blockIdx.y * 128, n0 = blockIdx.x * 128;
    const int wm = (wv & 1) * 64, wn = (wv >> 1) * 64;

    f32x4 acc[4][4];
    #pragma unroll
    for (int i = 0; i < 4; ++i)
        #pragma unroll
        for (int j = 0; j < 4; ++j) acc[i][j] = f32x4{0.f, 0.f, 0.f, 0.f};

    for (int kb = 0; kb < K; kb += 128) {
        __syncthreads();
        #pragma unroll
        for (int it = 0; it < 8; ++it) {
            const int r = it * 4 + wv, row = r * 4 + l4, cg = l16 ^ (row & 15);
            __builtin_amdgcn_global_load_lds(
                (const __attribute__((address_space(1))) void*)(Ab + (size_t)(m0 + row) * K + kb + cg * 8),
                (__attribute__((address_space(3))) void*)(As + r * 512), 16, 0, 0);
        }
        #pragma unroll
        for (int it = 0; it < 8; ++it) {
            const int r = it * 4 + wv, row = r * 4 + l4, cg = l16 ^ (row & 15);
            __builtin_amdgcn_global_load_lds(
                (const __attribute__((address_space(1))) void*)(Bb + (size_t)(n0 + row) * K + kb + cg * 8),
                (__attribute__((address_space(3))) void*)(Bs + r * 512), 16, 0, 0);
        }
        __syncthreads();
        #pragma unroll
        for (int ks = 0; ks < 4; ++ks) {
            short8 af[4], bfr[4];
            const int ch = (ks * 4 + l4) ^ l16;
            #pragma unroll
            for (int i = 0; i < 4; ++i) {
                af[i]  = *(const short8*)(As + (wm + i * 16 + l16) * 128 + ch * 8);
                bfr[i] = *(const short8*)(Bs + (wn + i * 16 + l16) * 128 + ch * 8);
            }
            #pragma unroll
            for (int i = 0; i < 4; ++i)
                #pragma unroll
                for (int j = 0; j < 4; ++j)
                    acc[i][j] = __builtin_amdgcn_mfma_f32_16x16x32_bf16(af[i], bfr[j], acc[i][j], 0, 0, 0);
        }
    }

    float bsv[4];
    #pragma unroll
    for (int j = 0; j < 4; ++j) bsv[j] = bias[n0 + wn + j * 16 + l16];
    #pragma unroll
    for (int i = 0; i < 4; ++i)
        #pragma unroll
        for (int r = 0; r < 4; ++r) {
            const int m = m0 + wm + i * 16 + l4 * 4 + r;
            #pragma unroll
            for (int j = 0; j < 4; ++j) {
                const int n = n0 + wn + j * 16 + l16;
                float v = acc[i][j][r] + bsv[j];
                if (RELU) v = fmaxf(v, 0.0f);
                if constexpr (sizeof(OutT) == 2) ((short*)C)[(size_t)m * N + n] = (short)f2bf(v);
                else                             ((float*)C)[(size_t)m * N + n] = v;
            }
        }
}

// ---------------------------------------------------------------------------
// z-GEMM with FUSED bias + row-L2-normalize + bf16 cast (verified r10).
// ---------------------------------------------------------------------------
__global__ void __launch_bounds__(256) mfma_z_norm(const short* __restrict__ Ab,
                                                   const short* __restrict__ Bb,
                                                   const float* __restrict__ bias,
                                                   short* __restrict__ zb) {
    __shared__ __align__(16) short As[128 * 128];
    __shared__ __align__(16) short Bs[128 * 128];
    __shared__ float ssq[128];
    const int t = threadIdx.x;
    const int lane = t & 63, wv = t >> 6;
    const int l16 = lane & 15, l4 = lane >> 4;
    const int m0 = blockIdx.x * 128;
    const int wm = (wv & 1) * 64, wn = (wv >> 1) * 64;
    const int K = EMB_D_;

    if (t < 128) ssq[t] = 0.0f;

    f32x4 acc[4][4];
    #pragma unroll
    for (int i = 0; i < 4; ++i)
        #pragma unroll
        for (int j = 0; j < 4; ++j) acc[i][j] = f32x4{0.f, 0.f, 0.f, 0.f};

    for (int kb = 0; kb < K; kb += 128) {
        __syncthreads();
        #pragma unroll
        for (int it = 0; it < 8; ++it) {
            const int r = it * 4 + wv, row = r * 4 + l4, cg = l16 ^ (row & 15);
            __builtin_amdgcn_global_load_lds(
                (const __attribute__((address_space(1))) void*)(Ab + (size_t)(m0 + row) * K + kb + cg * 8),
                (__attribute__((address_space(3))) void*)(As + r * 512), 16, 0, 0);
        }
        #pragma unroll
        for (int it = 0; it < 8; ++it) {
            const int r = it * 4 + wv, row = r * 4 + l4, cg = l16 ^ (row & 15);
            __builtin_amdgcn_global_load_lds(
                (const __attribute__((address_space(1))) void*)(Bb + (size_t)(row) * K + kb + cg * 8),
                (__attribute__((address_space(3))) void*)(Bs + r * 512), 16, 0, 0);
        }
        __syncthreads();
        #pragma unroll
        for (int ks = 0; ks < 4; ++ks) {
            short8 af[4], bfr[4];
            const int ch = (ks * 4 + l4) ^ l16;
            #pragma unroll
            for (int i = 0; i < 4; ++i) {
                af[i]  = *(const short8*)(As + (wm + i * 16 + l16) * 128 + ch * 8);
                bfr[i] = *(const short8*)(Bs + (wn + i * 16 + l16) * 128 + ch * 8);
            }
            #pragma unroll
            for (int i = 0; i < 4; ++i)
                #pragma unroll
                for (int j = 0; j < 4; ++j)
                    acc[i][j] = __builtin_amdgcn_mfma_f32_16x16x32_bf16(af[i], bfr[j], acc[i][j], 0, 0, 0);
        }
    }

    float bsv[4];
    #pragma unroll
    for (int j = 0; j < 4; ++j) bsv[j] = bias[wn + j * 16 + l16];
    #pragma unroll
    for (int i = 0; i < 4; ++i)
        #pragma unroll
        for (int r = 0; r < 4; ++r) {
            float p = 0.0f;
            #pragma unroll
            for (int j = 0; j < 4; ++j) {
                acc[i][j][r] += bsv[j];
                p += acc[i][j][r] * acc[i][j][r];
            }
            #pragma unroll
            for (int o = 8; o > 0; o >>= 1) p += __shfl_xor(p, o);
            if (l16 == 0) atomicAdd(&ssq[wm + i * 16 + l4 * 4 + r], p);
        }
    __syncthreads();
    #pragma unroll
    for (int i = 0; i < 4; ++i)
        #pragma unroll
        for (int r = 0; r < 4; ++r) {
            const int lrow = wm + i * 16 + l4 * 4 + r;
            const float inv = rsqrtf(ssq[lrow]);
            #pragma unroll
            for (int j = 0; j < 4; ++j)
                zb[(size_t)(m0 + lrow) * PROJ_D_ + wn + j * 16 + l16] =
                    (short)f2bf(acc[i][j][r] * inv);
        }
}

// ---------------------------------------------------------------------------
// Merged prep: emb cast (0..1535) + queue cast (1536..5631) + qlab census
// (5632..5663) + W1 transpose (5664..5807) + W2 transpose (5808..5831).
// ---------------------------------------------------------------------------
__global__ void __launch_bounds__(256) prep(const float* __restrict__ emb, short* __restrict__ embb,
                                            const float* __restrict__ queue, short* __restrict__ qb,
                                            const int* __restrict__ qlab, int* __restrict__ qcnt,
                                            const float* __restrict__ W1, short* __restrict__ w1t,
                                            const float* __restrict__ W2, short* __restrict__ w2t) {
    __shared__ float tile[64][65];
    const int b = blockIdx.x, t = threadIdx.x;
    if (b < 1536) {
        const int i = b * 256 + t;
        const float4 f = ((const float4*)emb)[i];
        short4v o = {(short)f2bf(f.x), (short)f2bf(f.y), (short)f2bf(f.z), (short)f2bf(f.w)};
        ((short4v*)embb)[i] = o;
    } else if (b < 5632) {
        const int i = (b - 1536) * 256 + t;
        const float4 f = ((const float4*)queue)[i];
        short4v o = {(short)f2bf(f.x), (short)f2bf(f.y), (short)f2bf(f.z), (short)f2bf(f.w)};
        ((short4v*)qb)[i] = o;
    } else if (b < 5664) {
        const int i = (b - 5632) * 256 + t;
        int c0 = 0, c1 = 0, cv = 0;
        for (int j = i; j < QUEUE_N; j += 8192) {
            const int q = qlab[j];
            c0 += (q == 0); c1 += (q == 1); cv += (q >= 0);
        }
        #pragma unroll
        for (int o = 32; o > 0; o >>= 1) {
            c0 += __shfl_xor(c0, o); c1 += __shfl_xor(c1, o); cv += __shfl_xor(cv, o);
        }
        if ((t & 63) == 0) {
            atomicAdd(&qcnt[0], c0); atomicAdd(&qcnt[1], c1); atomicAdd(&qcnt[2], cv);
        }
    } else {
        const int bid = b - 5664;
        const float* A; short* At; int R, C, bx, by;
        if (bid < 144) { A = W1; At = w1t; R = EMB_D_; C = EMB_D_;  bx = (bid % 12) * 64; by = (bid / 12) * 64; }
        else { const int b2 = bid - 144; A = W2; At = w2t; R = EMB_D_; C = PROJ_D_; bx = (b2 & 1) * 64; by = (b2 >> 1) * 64; }
        const int tc = t & 63, tg = t >> 6;
        #pragma unroll
        for (int i = 0; i < 16; i++) {
            const int r = tg * 16 + i;
            tile[r][tc] = A[(size_t)(by + r) * C + bx + tc];
        }
        __syncthreads();
        #pragma unroll
        for (int i = 0; i < 16; i++) {
            const int r = tg * 16 + i;
            At[(size_t)(bx + r) * R + by + tc] = (short)f2bf(tile[tc][r]);
        }
    }
}

// ---------------------------------------------------------------------------
// u8-code top-512 lse (verified r10). One block per row: 256-bin byte
// histogram (skip 0), suffix-scan, crossing, lse from counts x bin-center.
// ---------------------------------------------------------------------------
__global__ void __launch_bounds__(256) topk_lse_u8(const unsigned char* __restrict__ codes,
                                                   const int* __restrict__ qcnt,
                                                   const int* __restrict__ labels,
                                                   float* __restrict__ lseq,
                                                   int* __restrict__ flag) {
    const int row = blockIdx.x, t = threadIdx.x;
    __shared__ int hist[256];
    __shared__ int suf[256];
    __shared__ int s_bin;
    __shared__ float scf[4];
    hist[t] = 0;
    __syncthreads();

    const uint4* rowp = (const uint4*)(codes + (size_t)row * QUEUE_N);
    #pragma unroll
    for (int k = 0; k < 8; k++) {
        const uint4 u = rowp[k * 256 + t];
        const unsigned w[4] = {u.x, u.y, u.z, u.w};
        #pragma unroll
        for (int q = 0; q < 4; q++)
            #pragma unroll
            for (int s = 0; s < 4; s++) {
                const int c = (w[q] >> (8 * s)) & 0xFF;
                if (c) atomicAdd(&hist[c], 1);
            }
    }
    __syncthreads();

    suf[t] = hist[t];
    __syncthreads();
    for (int off = 1; off < 256; off <<= 1) {
        int add = (t + off < 256) ? suf[t + off] : 0;
        __syncthreads();
        suf[t] += add;
        __syncthreads();
    }
    const int total = suf[1];
    const int opp   = opp_of(labels[row], qcnt);
    if (total < HARD_K_ || opp < HARD_K_) {
        if (t == 0) flag[row] = 0;
        return;
    }
    {
        const int above = (t < 255) ? suf[t + 1] : 0;
        if (suf[t] >= HARD_K_ && above < HARD_K_) s_bin = t;
    }
    __syncthreads();
    const int b = s_bin;

    float e = 0.0f;
    if (t > b && hist[t]) e = (float)hist[t] * __expf((WLO + ((float)t - 0.5f) * BINW - 1.0f) * INV_T);
    #pragma unroll
    for (int o = 32; o > 0; o >>= 1) e += __shfl_xor(e, o);
    if ((t & 63) == 0) scf[t >> 6] = e;
    __syncthreads();
    if (t == 0) {
        const float Eab  = scf[0] + scf[1] + scf[2] + scf[3];
        const int   cab  = (b < 255) ? suf[b + 1] : 0;
        const float ebin = __expf((WLO + ((float)b - 0.5f) * BINW - 1.0f) * INV_T);
        const float sadj = Eab + (float)(HARD_K_ - cab) * ebin;
        lseq[row] = INV_T + __logf(sadj);
        flag[row] = 1;
    }
}

// ---------------------------------------------------------------------------
// Histogram crossing search (verified r1-r10; used by fallback)
// ---------------------------------------------------------------------------
__device__ __forceinline__ void find_crossing(int* hist, int* grp, int target,
                                              int* s_bin, int* s_chi) {
    const int t = threadIdx.x;
    const int b0 = hist[4*t], b1 = hist[4*t+1], b2 = hist[4*t+2], b3 = hist[4*t+3];
    grp[t] = b0 + b1 + b2 + b3;
    __syncthreads();
    for (int off = 1; off < 256; off <<= 1) {
        int add = (t + off < 256) ? grp[t + off] : 0;
        __syncthreads();
        grp[t] += add;
        __syncthreads();
    }
    int cab = (t < 255) ? grp[t + 1] : 0;
    const int hb[4] = {b0, b1, b2, b3};
    #pragma unroll
    for (int i = 3; i >= 0; i--) {
        const int h = hb[i];
        if (cab < target && cab + h >= target) { *s_bin = 4*t + i; *s_chi = cab; }
        cab += h;
    }
    __syncthreads();
}

// iterate all 128 packed-half2 values
#define FOR_ALL_VALS(BODY)                                                   \
    _Pragma("unroll")                                                        \
    for (int _k = 0; _k < 64; _k++) {                                        \
        const float2 _f = __half22float2(*(const __half2*)&dv[_k]);          \
        { const float v = _f.x; BODY }                                       \
        { const float v = _f.y; BODY }                                       \
    }

// ---------------------------------------------------------------------------
// Exact fallback (verified r5-r10; normally zero rows). Recomputes from zb/qb.
// ---------------------------------------------------------------------------
__global__ void __launch_bounds__(256) topk_lse_fallback(const short* __restrict__ zb,
                                                         const short* __restrict__ qb,
                                                         const int* __restrict__ labels,
                                                         const int* __restrict__ qlab,
                                                         const int* __restrict__ qcnt,
                                                         const int* __restrict__ flag,
                                                         float* __restrict__ lseq) {
    const int row = blockIdx.x, t = threadIdx.x;
    if (flag[row]) return;
    const int opp = opp_of(labels[row], qcnt);

    __shared__ float zrow[128];
    __shared__ int hist[1024];
    __shared__ int grp[256];
    __shared__ int s_bin, s_chi, s_bin2, s_chi2;
    __shared__ float scf[4]; __shared__ int sci[4];
    if (t < 128) zrow[t] = bf2f(zb[(size_t)row * 128 + t]);
    __syncthreads();

    const int mylab = labels[row];
    unsigned dv[64];
    float rm = -1e30f, rs = 0.0f;
    for (int k = 0; k < 128; k++) {
        const int j = t + 256 * k;
        float d = 0.0f;
        #pragma unroll
        for (int c = 0; c < 16; ++c) {
            const short8 qv = *(const short8*)(qb + (size_t)j * 128 + c * 8);
            #pragma unroll
            for (int e = 0; e < 8; ++e) d += zrow[c * 8 + e] * bf2f(qv[e]);
        }
        if (j < HARD_K_) {
            const float sv = d * INV_T;
            if (sv > rm) { rs = rs * __expf(rm - sv) + 1.0f; rm = sv; }
            else         { rs += __expf(sv - rm); }
        }
        const int q = qlab[j];
        const float mv = (q != mylab && q >= 0) ? d : -65504.0f;
        const __half h = __float2half(mv);
        unsigned short* p = (unsigned short*)&dv[k >> 1];
        p[k & 1] = *(const unsigned short*)&h;
    }

    if (opp == 0) {
        #pragma unroll
        for (int o = 32; o > 0; o >>= 1) {
            const float om = __shfl_xor(rm, o), os = __shfl_xor(rs, o);
            const float nm = fmaxf(rm, om);
            rs = rs * __expf(rm - nm) + os * __expf(om - nm);
            rm = nm;
        }
        if ((t & 63) == 0) { scf[t >> 6] = rm; ((float*)sci)[t >> 6] = rs; }
        __syncthreads();
        if (t == 0) {
            float M = -1e30f, Sx = 0.0f;
            for (int w = 0; w < 4; w++) {
                const float nm = fmaxf(M, scf[w]);
                Sx = Sx * __expf(M - nm) + ((float*)sci)[w] * __expf(scf[w] - nm);
                M = nm;
            }
            lseq[row] = M + __logf(Sx);
        }
        return;
    }
    if (opp < HARD_K_) {
        float mm = -1e30f, ss = 0.0f;
        FOR_ALL_VALS(
            if (v > -60000.0f) {
                const float sv = v * INV_T;
                if (sv > mm) { ss = ss * __expf(mm - sv) + 1.0f; mm = sv; }
                else         { ss += __expf(sv - mm); }
            } )
        #pragma unroll
        for (int o = 32; o > 0; o >>= 1) {
            const float om = __shfl_xor(mm, o), os = __shfl_xor(ss, o);
            const float nm = fmaxf(mm, om);
            ss = ss * __expf(mm - nm) + os * __expf(om - nm);
            mm = nm;
        }
        if ((t & 63) == 0) { scf[t >> 6] = mm; ((float*)sci)[t >> 6] = ss; }
        __syncthreads();
        if (t == 0) {
            float M = -1e30f, Sx = 0.0f;
            for (int w = 0; w < 4; w++) {
                const float nm = fmaxf(M, scf[w]);
                Sx = Sx * __expf(M - nm) + ((float*)sci)[w] * __expf(scf[w] - nm);
                M = nm;
            }
            lseq[row] = M + __logf(Sx);
        }
        return;
    }

    float mloc = -1e30f;
    FOR_ALL_VALS( mloc = fmaxf(mloc, v); )
    #pragma unroll
    for (int o = 32; o > 0; o >>= 1) mloc = fmaxf(mloc, __shfl_xor(mloc, o));
    if ((t & 63) == 0) scf[t >> 6] = mloc;
    __syncthreads();
    const float m = fmaxf(fmaxf(scf[0], scf[1]), fmaxf(scf[2], scf[3]));

    int c1 = 0, c2 = 0;
    const float w1 = m - 0.25f, w2 = m - 1.0f;
    FOR_ALL_VALS( c1 += (v >= w1); c2 += (v >= w2); )
    #pragma unroll
    for (int o = 32; o > 0; o >>= 1) { c1 += __shfl_xor(c1, o); c2 += __shfl_xor(c2, o); }
    if ((t & 63) == 0) { sci[t >> 6] = c1; }
    __syncthreads();
    const int C1 = sci[0] + sci[1] + sci[2] + sci[3];
    __syncthreads();
    if ((t & 63) == 0) { sci[t >> 6] = c2; }
    __syncthreads();
    const int C2 = sci[0] + sci[1] + sci[2] + sci[3];

    float lo;
    if      (C1 >= HARD_K_) lo = w1;
    else if (C2 >= HARD_K_) lo = w2;
    else                    lo = -1.01f;
    const float range = m - lo;
    const float scale = 1024.0f / range;

    for (int k = t; k < 1024; k += 256) hist[k] = 0;
    __syncthreads();
    FOR_ALL_VALS(
        if (v >= lo) {
            const float bf = fminf((v - lo) * scale, 1023.0f);
            atomicAdd(&hist[(int)bf], 1);
        } )
    __syncthreads();
    find_crossing(hist, grp, HARD_K_, &s_bin, &s_chi);
    const int   bin1 = s_bin, chi1 = s_chi;
    const float binw = range * (1.0f / 1024.0f);
    const float lo1  = lo + bin1 * binw;
    const float ssc  = 1024.0f / binw;

    for (int k = t; k < 1024; k += 256) hist[k] = 0;
    __syncthreads();
    FOR_ALL_VALS(
        if (v >= lo) {
            const float bf = fminf((v - lo) * scale, 1023.0f);
            if ((int)bf == bin1) {
                const float sf = fminf(fmaxf((v - lo1) * ssc, 0.0f), 1023.0f);
                atomicAdd(&hist[(int)sf], 1);
            }
        } )
    __syncthreads();
    find_crossing(hist, grp, HARD_K_ - chi1, &s_bin2, &s_chi2);
    const float thr = lo1 + s_bin2 * (binw * (1.0f / 1024.0f));

    float sl = 0.0f; int cg = 0;
    FOR_ALL_VALS( if (v > thr) { cg++; sl += __expf((v - m) * INV_T); } )
    #pragma unroll
    for (int o = 32; o > 0; o >>= 1) { sl += __shfl_xor(sl, o); cg += __shfl_xor(cg, o); }
    if ((t & 63) == 0) { scf[t >> 6] = sl; sci[t >> 6] = cg; }
    __syncthreads();
    if (t == 0) {
        const float slt = scf[0] + scf[1] + scf[2] + scf[3];
        const int   cgt = sci[0] + sci[1] + sci[2] + sci[3];
        const float sadj = slt + ((float)HARD_K_ - (float)cgt) * __expf((thr - m) * INV_T);
        lseq[row] = m * INV_T + __logf(sadj);
    }
}

// ---------------------------------------------------------------------------
// Batch lse + positive-pair loss, one WAVE per row (verified r6-r10).
// ---------------------------------------------------------------------------
__global__ void __launch_bounds__(256) batch_row_loss(const float* __restrict__ S,
                                                      const int* __restrict__ labels,
                                                      const float* __restrict__ lse_queue,
                                                      float* __restrict__ part_out,
                                                      int* __restrict__ cnt_out) {
    const int t = threadIdx.x;
    const int wv = t >> 6, lane = t & 63;
    const int row = blockIdx.x * 4 + wv;
    __shared__ int lab[BATCH_N];
    for (int k = t; k < BATCH_N; k += 256) lab[k] = labels[k];
    __syncthreads();
    const int myLab = lab[row];
    const float4* rp4 = (const float4*)(S + (size_t)row * BATCH_N);
    const int4*   lb4 = (const int4*)lab;

    float v[32]; int lb[32];
    #pragma unroll
    for (int kk = 0; kk < 8; kk++) {
        const float4 f = rp4[lane + 64 * kk];
        const int4   l = lb4[lane + 64 * kk];
        v[4*kk+0] = f.x; v[4*kk+1] = f.y; v[4*kk+2] = f.z; v[4*kk+3] = f.w;
        lb[4*kk+0] = l.x; lb[4*kk+1] = l.y; lb[4*kk+2] = l.z; lb[4*kk+3] = l.w;
    }

    const float REF = INV_T;
    float sneg = 0.0f;
    #pragma unroll
    for (int k = 0; k < 32; k++) {
        const float ev = __expf(v[k] * INV_T - REF);
        sneg += (lb[k] != myLab) ? ev : 0.0f;
    }
    #pragma unroll
    for (int o = 32; o > 0; o >>= 1) sneg += __shfl_xor(sneg, o);
    const float lseb = (sneg > 0.0f) ? REF + __logf(sneg) : -1e30f;
    const float Lq = lse_queue[row];
    const float mx0 = fmaxf(lseb, Lq), mn0 = fminf(lseb, Lq);
    const float L = mx0 + __logf(1.0f + __expf(mn0 - mx0));

    float part = 0.0f; int cnt = 0;
    #pragma unroll
    for (int k = 0; k < 32; k++) {
        const int j = (lane + 64 * (k >> 2)) * 4 + (k & 3);
        if (lb[k] == myLab && j != row) {
            const float sv = v[k] * INV_T;
            const float mx = fmaxf(sv, L), mn = fminf(sv, L);
            part += (mx - sv) + __logf(1.0f + __expf(mn - mx));
            cnt++;
        }
    }
    #pragma unroll
    for (int o = 32; o > 0; o >>= 1) { part += __shfl_xor(part, o); cnt += __shfl_xor(cnt, o); }
    if (lane == 0) { part_out[row] = part; cnt_out[row] = cnt; }
}

// reduce 2048 per-row partials -> scalar loss. One block.
__global__ void __launch_bounds__(256) finalize_loss(const float* __restrict__ part,
                                                     const int* __restrict__ cnt,
                                                     float* __restrict__ out) {
    const int t = threadIdx.x;
    float s = 0.0f; int c = 0;
    #pragma unroll
    for (int k = 0; k < 8; k++) { s += part[t + 256 * k]; c += cnt[t + 256 * k]; }
    #pragma unroll
    for (int o = 32; o > 0; o >>= 1) { s += __shfl_xor(s, o); c += __shfl_xor(c, o); }
    __shared__ float sf[4]; __shared__ int sc[4];
    if ((t & 63) == 0) { sf[t >> 6] = s; sc[t >> 6] = c; }
    __syncthreads();
    if (t == 0) {
        const float st = sf[0] + sf[1] + sf[2] + sf[3];
        const int   ct = sc[0] + sc[1] + sc[2] + sc[3];
        out[0] = (ct > 0) ? (st / (float)ct) : 0.0f;
    }
}

// ---------------------------------------------------------------------------
extern "C" void kernel_launch(void* const* d_in, const int* in_sizes, int n_in,
                              void* d_out, int out_size, void* d_ws, size_t ws_size,
                              hipStream_t stream) {
    const float* emb    = (const float*)d_in[0];
    const int*   labels = (const int*)  d_in[1];
    const float* W1     = (const float*)d_in[2];
    const float* b1     = (const float*)d_in[3];
    const float* W2     = (const float*)d_in[4];
    const float* b2     = (const float*)d_in[5];
    const float* queue  = (const float*)d_in[6];
    const int*   qlab   = (const int*)  d_in[7];

    char* ws = (char*)d_ws;
    float*         Sbuf  = (float*)        (ws);              // 16777216
    unsigned char* codes = (unsigned char*)(ws + 16777216);   // 67108864
    short*         embb  = (short*)        (ws + 83886080);   // 3145728
    short*         hbf   = (short*)        (ws + 87031808);   // 3145728
    short*         zb    = (short*)        (ws + 90177536);   // 524288
    short*         qb    = (short*)        (ws + 90701824);   // 8388608
    short*         w1t   = (short*)        (ws + 99090432);   // 1179648
    short*         w2t   = (short*)        (ws + 100270080);  // 196608
    float*         lseq  = (float*)        (ws + 100466688);  // 8192
    int*           flag  = (int*)          (ws + 100474880);  // 8192
    int*           qcnt  = (int*)          (ws + 100483072);  // 64
    float*         partb = (float*)        (ws + 100483136);  // 8192
    int*           cntb  = (int*)          (ws + 100491328);  // 8192

    hipMemsetAsync(ws + 100474880, 0, 8192 + 64, stream);     // flag + qcnt

    dim3 blk(256);
    prep<<<dim3(5832), blk, 0, stream>>>(emb, embb, queue, qb, qlab, qcnt, W1, w1t, W2, w2t);
    mfma_nt_k<short, true><<<dim3(EMB_D_ / 128, BATCH_N / 128), blk, 0, stream>>>(embb, w1t, b1, hbf, EMB_D_, EMB_D_);
    mfma_z_norm<<<dim3(BATCH_N / 128), blk, 0, stream>>>(hbf, w2t, b2, zb);
    mfma_mask8<<<dim3(QUEUE_N / 128, BATCH_N / 128), blk, 0, stream>>>(zb, qb, codes, labels, qlab);
    topk_lse_u8<<<BATCH_N, blk, 0, stream>>>(codes, qcnt, labels, lseq, flag);
    topk_lse_fallback<<<BATCH_N, blk, 0, stream>>>(zb, qb, labels, qlab, qcnt, flag, lseq);
    mfma_nt_plain<<<dim3(BATCH_N / 128, BATCH_N / 128), blk, 0, stream>>>(zb, zb, Sbuf, BATCH_N);
    batch_row_loss<<<BATCH_N / 4, blk, 0, stream>>>(Sbuf, labels, lseq, partb, cntb);
    finalize_loss<<<1, blk, 0, stream>>>(partb, cntb, (float*)d_out);
}

// Round 12
// 176.950 us; speedup vs baseline: 2.5478x; 1.0249x over previous
//
#include <hip/hip_runtime.h>
#include <hip/hip_fp16.h>

#define BATCH_N   2048
#define EMB_D_    768
#define PROJ_D_   128
#define QUEUE_N   32768
#define HARD_K_   512
static constexpr float INV_T  = 1.0f / 0.07f;
static constexpr float WLO    = 0.12f;              // code-0 boundary (512th opp val ~0.164)
static constexpr float S8ENC  = 255.0f / 0.88f;     // encode scale
static constexpr float BINW   = 0.88f / 255.0f;     // code bin width

typedef __attribute__((ext_vector_type(8))) short short8;
typedef __attribute__((ext_vector_type(4))) short short4v;
typedef __attribute__((ext_vector_type(4))) float f32x4;

__device__ __forceinline__ unsigned short f2bf(float f) {
    unsigned u = __float_as_uint(f);
    unsigned r = u + 0x7fffu + ((u >> 16) & 1u);   // RNE
    return (unsigned short)(r >> 16);
}
__device__ __forceinline__ float bf2f(short s) {
    return __uint_as_float(((unsigned)(unsigned short)s) << 16);
}
__device__ __forceinline__ int opp_of(int mylab, const int* __restrict__ qcnt) {
    const int same = (mylab == 0) ? qcnt[0] : ((mylab == 1) ? qcnt[1] : 0);
    return qcnt[2] - same;
}

// ---------------------------------------------------------------------------
// S GEMM: bf16 MFMA NT, K=128, output packed bf16 in the mask8 column
// permutation (within each 64-col group, packed pos p = l16*4+j holds logical
// col j*16+l16). Halves S traffic; consumer un-permutes via LDS label table.
// GEMM body verified r2-r11.
// ---------------------------------------------------------------------------
__global__ void __launch_bounds__(256) mfma_s_pack(const short* __restrict__ Ab,
                                                   const short* __restrict__ Bb,
                                                   short* __restrict__ C, int N) {
    __shared__ __align__(16) short As[128 * 128];
    __shared__ __align__(16) short Bs[128 * 128];
    const int t = threadIdx.x;
    const int lane = t & 63, wv = t >> 6;
    const int l16 = lane & 15, l4 = lane >> 4;
    const int m0 = blockIdx.y * 128, n0 = blockIdx.x * 128;

    #pragma unroll
    for (int it = 0; it < 8; ++it) {
        const int r = it * 4 + wv, row = r * 4 + l4, cg = l16 ^ (row & 15);
        __builtin_amdgcn_global_load_lds(
            (const __attribute__((address_space(1))) void*)(Ab + (size_t)(m0 + row) * 128 + cg * 8),
            (__attribute__((address_space(3))) void*)(As + r * 512), 16, 0, 0);
    }
    #pragma unroll
    for (int it = 0; it < 8; ++it) {
        const int r = it * 4 + wv, row = r * 4 + l4, cg = l16 ^ (row & 15);
        __builtin_amdgcn_global_load_lds(
            (const __attribute__((address_space(1))) void*)(Bb + (size_t)(n0 + row) * 128 + cg * 8),
            (__attribute__((address_space(3))) void*)(Bs + r * 512), 16, 0, 0);
    }
    __syncthreads();

    const int wm = (wv & 1) * 64, wn = (wv >> 1) * 64;
    f32x4 acc[4][4];
    #pragma unroll
    for (int i = 0; i < 4; ++i)
        #pragma unroll
        for (int j = 0; j < 4; ++j) acc[i][j] = f32x4{0.f, 0.f, 0.f, 0.f};

    #pragma unroll
    for (int ks = 0; ks < 4; ++ks) {
        short8 af[4], bfr[4];
        const int ch = (ks * 4 + l4) ^ l16;
        #pragma unroll
        for (int i = 0; i < 4; ++i) {
            af[i]  = *(const short8*)(As + (wm + i * 16 + l16) * 128 + ch * 8);
            bfr[i] = *(const short8*)(Bs + (wn + i * 16 + l16) * 128 + ch * 8);
        }
        #pragma unroll
        for (int i = 0; i < 4; ++i)
            #pragma unroll
            for (int j = 0; j < 4; ++j)
                acc[i][j] = __builtin_amdgcn_mfma_f32_16x16x32_bf16(af[i], bfr[j], acc[i][j], 0, 0, 0);
    }
    #pragma unroll
    for (int i = 0; i < 4; ++i)
        #pragma unroll
        for (int r = 0; r < 4; ++r) {
            const int m = m0 + wm + i * 16 + l4 * 4 + r;
            union { unsigned short u[4]; uint2 d; } pk;
            #pragma unroll
            for (int j = 0; j < 4; ++j) pk.u[j] = f2bf(acc[i][j][r]);
            *(uint2*)(C + (size_t)m * N + n0 + wn + l16 * 4) = pk.d;
        }
}

// ---------------------------------------------------------------------------
// Masked queue GEMM -> u8 codes, packed dword stores, column-permuted
// (verified r11). TWO N-tiles per block: A-tile + row labels staged once,
// B restaged between tiles; t0 epilogue overlaps t1 B-staging.
// ---------------------------------------------------------------------------
__global__ void __launch_bounds__(256) mfma_mask8(const short* __restrict__ Ab,
                                                  const short* __restrict__ Bb,
                                                  unsigned char* __restrict__ codes,
                                                  const int* __restrict__ labA,
                                                  const int* __restrict__ labB) {
    __shared__ __align__(16) short As[128 * 128];
    __shared__ __align__(16) short Bs[128 * 128];
    const int t = threadIdx.x;
    const int lane = t & 63, wv = t >> 6;
    const int l16 = lane & 15, l4 = lane >> 4;
    const int m0 = blockIdx.y * 128;
    const int wm = (wv & 1) * 64, wn = (wv >> 1) * 64;

    #pragma unroll
    for (int it = 0; it < 8; ++it) {
        const int r = it * 4 + wv, row = r * 4 + l4, cg = l16 ^ (row & 15);
        __builtin_amdgcn_global_load_lds(
            (const __attribute__((address_space(1))) void*)(Ab + (size_t)(m0 + row) * 128 + cg * 8),
            (__attribute__((address_space(3))) void*)(As + r * 512), 16, 0, 0);
    }
    {
        const int n0 = (blockIdx.x * 2) * 128;
        #pragma unroll
        for (int it = 0; it < 8; ++it) {
            const int r = it * 4 + wv, row = r * 4 + l4, cg = l16 ^ (row & 15);
            __builtin_amdgcn_global_load_lds(
                (const __attribute__((address_space(1))) void*)(Bb + (size_t)(n0 + row) * 128 + cg * 8),
                (__attribute__((address_space(3))) void*)(Bs + r * 512), 16, 0, 0);
        }
    }

    int la[16];
    #pragma unroll
    for (int i = 0; i < 4; ++i)
        #pragma unroll
        for (int r = 0; r < 4; ++r)
            la[i * 4 + r] = labA[m0 + wm + i * 16 + l4 * 4 + r];
    const float C0 = 1.0f - WLO * S8ENC;
    __syncthreads();

    #pragma unroll
    for (int tt = 0; tt < 2; ++tt) {
        const int n0 = (blockIdx.x * 2 + tt) * 128;

        f32x4 acc[4][4];
        #pragma unroll
        for (int i = 0; i < 4; ++i)
            #pragma unroll
            for (int j = 0; j < 4; ++j) acc[i][j] = f32x4{0.f, 0.f, 0.f, 0.f};

        #pragma unroll
        for (int ks = 0; ks < 4; ++ks) {
            short8 af[4], bfr[4];
            const int ch = (ks * 4 + l4) ^ l16;
            #pragma unroll
            for (int i = 0; i < 4; ++i) {
                af[i]  = *(const short8*)(As + (wm + i * 16 + l16) * 128 + ch * 8);
                bfr[i] = *(const short8*)(Bs + (wn + i * 16 + l16) * 128 + ch * 8);
            }
            #pragma unroll
            for (int i = 0; i < 4; ++i)
                #pragma unroll
                for (int j = 0; j < 4; ++j)
                    acc[i][j] = __builtin_amdgcn_mfma_f32_16x16x32_bf16(af[i], bfr[j], acc[i][j], 0, 0, 0);
        }

        if (tt == 0) {
            __syncthreads();          // all waves done reading Bs tile 0
            const int n1 = (blockIdx.x * 2 + 1) * 128;
            #pragma unroll
            for (int it = 0; it < 8; ++it) {
                const int r = it * 4 + wv, row = r * 4 + l4, cg = l16 ^ (row & 15);
                __builtin_amdgcn_global_load_lds(
                    (const __attribute__((address_space(1))) void*)(Bb + (size_t)(n1 + row) * 128 + cg * 8),
                    (__attribute__((address_space(3))) void*)(Bs + r * 512), 16, 0, 0);
            }
        }

        // epilogue for this tile (overlaps tile-1 staging when tt==0)
        float a0[4], a1[4];
        #pragma unroll
        for (int j = 0; j < 4; ++j) {
            const int q = labB[n0 + wn + j * 16 + l16];
            a0[j] = (q >= 0 && q != 0) ? C0 : -1e9f;
            a1[j] = (q >= 0 && q != 1) ? C0 : -1e9f;
        }
        #pragma unroll
        for (int i = 0; i < 4; ++i) {
            #pragma unroll
            for (int r = 0; r < 4; ++r) {
                const int m  = m0 + wm + i * 16 + l4 * 4 + r;
                const bool z = (la[i * 4 + r] == 0);
                unsigned pk = 0;
                #pragma unroll
                for (int j = 0; j < 4; ++j) {
                    const float add = z ? a0[j] : a1[j];
                    const float f = fmaf(acc[i][j][r], S8ENC, add);
#if __has_builtin(__builtin_amdgcn_cvt_pk_u8_f32)
                    pk = __builtin_amdgcn_cvt_pk_u8_f32(f, j, pk);
#else
                    const unsigned c = (unsigned)fminf(fmaxf(f, 0.0f), 255.0f);
                    pk |= c << (8 * j);
#endif
                }
                *(unsigned*)(codes + (size_t)m * QUEUE_N + n0 + wn + l16 * 4) = pk;
            }
        }
        if (tt == 0) __syncthreads();  // tile-1 B staged (barrier drains vmcnt)
    }
}

// ---------------------------------------------------------------------------
// bf16 MFMA NT GEMM with K-loop, fused bias(+ReLU). Verified r3-r11 (MLP).
// ---------------------------------------------------------------------------
template<typename OutT, bool RELU>
__global__ void __launch_bounds__(256) mfma_nt_k(const short* __restrict__ Ab,
                                                 const short* __restrict__ Bb,
                                                 const float* __restrict__ bias,
                                                 OutT* __restrict__ C,
                                                 int N, int K) {
    __shared__ __align__(16) short As[128 * 128];
    __shared__ __align__(16) short Bs[128 * 128];
    const int t = threadIdx.x;
    const int lane = t & 63, wv = t >> 6;
    const int l16 = lane & 15, l4 = lane >> 4;
    const int m0 = blockIdx.y * 128, n0 = blockIdx.x * 128;
    const int wm = (wv & 1) * 64, wn = (wv >> 1) * 64;

    f32x4 acc[4][4];
    #pragma unroll
    for (int i = 0; i < 4; ++i)
        #pragma unroll
        for (int j = 0; j < 4; ++j) acc[i][j] = f32x4{0.f, 0.f, 0.f, 0.f};

    for (int kb = 0; kb < K; kb += 128) {
        __syncthreads();
        #pragma unroll
        for (int it = 0; it < 8; ++it) {
            const int r = it * 4 + wv, row = r * 4 + l4, cg = l16 ^ (row & 15);
            __builtin_amdgcn_global_load_lds(
                (const __attribute__((address_space(1))) void*)(Ab + (size_t)(m0 + row) * K + kb + cg * 8),
                (__attribute__((address_space(3))) void*)(As + r * 512), 16, 0, 0);
        }
        #pragma unroll
        for (int it = 0; it < 8; ++it) {
            const int r = it * 4 + wv, row = r * 4 + l4, cg = l16 ^ (row & 15);
            __builtin_amdgcn_global_load_lds(
                (const __attribute__((address_space(1))) void*)(Bb + (size_t)(n0 + row) * K + kb + cg * 8),
                (__attribute__((address_space(3))) void*)(Bs + r * 512), 16, 0, 0);
        }
        __syncthreads();
        #pragma unroll
        for (int ks = 0; ks < 4; ++ks) {
            short8 af[4], bfr[4];
            const int ch = (ks * 4 + l4) ^ l16;
            #pragma unroll
            for (int i = 0; i < 4; ++i) {
                af[i]  = *(const short8*)(As + (wm + i * 16 + l16) * 128 + ch * 8);
                bfr[i] = *(const short8*)(Bs + (wn + i * 16 + l16) * 128 + ch * 8);
            }
            #pragma unroll
            for (int i = 0; i < 4; ++i)
                #pragma unroll
                for (int j = 0; j < 4; ++j)
                    acc[i][j] = __builtin_amdgcn_mfma_f32_16x16x32_bf16(af[i], bfr[j], acc[i][j], 0, 0, 0);
        }
    }

    float bsv[4];
    #pragma unroll
    for (int j = 0; j < 4; ++j) bsv[j] = bias[n0 + wn + j * 16 + l16];
    #pragma unroll
    for (int i = 0; i < 4; ++i)
        #pragma unroll
        for (int r = 0; r < 4; ++r) {
            const int m = m0 + wm + i * 16 + l4 * 4 + r;
            #pragma unroll
            for (int j = 0; j < 4; ++j) {
                const int n = n0 + wn + j * 16 + l16;
                float v = acc[i][j][r] + bsv[j];
                if (RELU) v = fmaxf(v, 0.0f);
                if constexpr (sizeof(OutT) == 2) ((short*)C)[(size_t)m * N + n] = (short)f2bf(v);
                else                             ((float*)C)[(size_t)m * N + n] = v;
            }
        }
}

// ---------------------------------------------------------------------------
// z-GEMM with FUSED bias + row-L2-normalize + bf16 cast (verified r10/r11).
// ---------------------------------------------------------------------------
__global__ void __launch_bounds__(256) mfma_z_norm(const short* __restrict__ Ab,
                                                   const short* __restrict__ Bb,
                                                   const float* __restrict__ bias,
                                                   short* __restrict__ zb) {
    __shared__ __align__(16) short As[128 * 128];
    __shared__ __align__(16) short Bs[128 * 128];
    __shared__ float ssq[128];
    const int t = threadIdx.x;
    const int lane = t & 63, wv = t >> 6;
    const int l16 = lane & 15, l4 = lane >> 4;
    const int m0 = blockIdx.x * 128;
    const int wm = (wv & 1) * 64, wn = (wv >> 1) * 64;
    const int K = EMB_D_;

    if (t < 128) ssq[t] = 0.0f;

    f32x4 acc[4][4];
    #pragma unroll
    for (int i = 0; i < 4; ++i)
        #pragma unroll
        for (int j = 0; j < 4; ++j) acc[i][j] = f32x4{0.f, 0.f, 0.f, 0.f};

    for (int kb = 0; kb < K; kb += 128) {
        __syncthreads();
        #pragma unroll
        for (int it = 0; it < 8; ++it) {
            const int r = it * 4 + wv, row = r * 4 + l4, cg = l16 ^ (row & 15);
            __builtin_amdgcn_global_load_lds(
                (const __attribute__((address_space(1))) void*)(Ab + (size_t)(m0 + row) * K + kb + cg * 8),
                (__attribute__((address_space(3))) void*)(As + r * 512), 16, 0, 0);
        }
        #pragma unroll
        for (int it = 0; it < 8; ++it) {
            const int r = it * 4 + wv, row = r * 4 + l4, cg = l16 ^ (row & 15);
            __builtin_amdgcn_global_load_lds(
                (const __attribute__((address_space(1))) void*)(Bb + (size_t)(row) * K + kb + cg * 8),
                (__attribute__((address_space(3))) void*)(Bs + r * 512), 16, 0, 0);
        }
        __syncthreads();
        #pragma unroll
        for (int ks = 0; ks < 4; ++ks) {
            short8 af[4], bfr[4];
            const int ch = (ks * 4 + l4) ^ l16;
            #pragma unroll
            for (int i = 0; i < 4; ++i) {
                af[i]  = *(const short8*)(As + (wm + i * 16 + l16) * 128 + ch * 8);
                bfr[i] = *(const short8*)(Bs + (wn + i * 16 + l16) * 128 + ch * 8);
            }
            #pragma unroll
            for (int i = 0; i < 4; ++i)
                #pragma unroll
                for (int j = 0; j < 4; ++j)
                    acc[i][j] = __builtin_amdgcn_mfma_f32_16x16x32_bf16(af[i], bfr[j], acc[i][j], 0, 0, 0);
        }
    }

    float bsv[4];
    #pragma unroll
    for (int j = 0; j < 4; ++j) bsv[j] = bias[wn + j * 16 + l16];
    #pragma unroll
    for (int i = 0; i < 4; ++i)
        #pragma unroll
        for (int r = 0; r < 4; ++r) {
            float p = 0.0f;
            #pragma unroll
            for (int j = 0; j < 4; ++j) {
                acc[i][j][r] += bsv[j];
                p += acc[i][j][r] * acc[i][j][r];
            }
            #pragma unroll
            for (int o = 8; o > 0; o >>= 1) p += __shfl_xor(p, o);
            if (l16 == 0) atomicAdd(&ssq[wm + i * 16 + l4 * 4 + r], p);
        }
    __syncthreads();
    #pragma unroll
    for (int i = 0; i < 4; ++i)
        #pragma unroll
        for (int r = 0; r < 4; ++r) {
            const int lrow = wm + i * 16 + l4 * 4 + r;
            const float inv = rsqrtf(ssq[lrow]);
            #pragma unroll
            for (int j = 0; j < 4; ++j)
                zb[(size_t)(m0 + lrow) * PROJ_D_ + wn + j * 16 + l16] =
                    (short)f2bf(acc[i][j][r] * inv);
        }
}

// ---------------------------------------------------------------------------
// Merged prep (verified r11): emb cast + queue cast + qlab census + W1/W2
// transpose.
// ---------------------------------------------------------------------------
__global__ void __launch_bounds__(256) prep(const float* __restrict__ emb, short* __restrict__ embb,
                                            const float* __restrict__ queue, short* __restrict__ qb,
                                            const int* __restrict__ qlab, int* __restrict__ qcnt,
                                            const float* __restrict__ W1, short* __restrict__ w1t,
                                            const float* __restrict__ W2, short* __restrict__ w2t) {
    __shared__ float tile[64][65];
    const int b = blockIdx.x, t = threadIdx.x;
    if (b < 1536) {
        const int i = b * 256 + t;
        const float4 f = ((const float4*)emb)[i];
        short4v o = {(short)f2bf(f.x), (short)f2bf(f.y), (short)f2bf(f.z), (short)f2bf(f.w)};
        ((short4v*)embb)[i] = o;
    } else if (b < 5632) {
        const int i = (b - 1536) * 256 + t;
        const float4 f = ((const float4*)queue)[i];
        short4v o = {(short)f2bf(f.x), (short)f2bf(f.y), (short)f2bf(f.z), (short)f2bf(f.w)};
        ((short4v*)qb)[i] = o;
    } else if (b < 5664) {
        const int i = (b - 5632) * 256 + t;
        int c0 = 0, c1 = 0, cv = 0;
        for (int j = i; j < QUEUE_N; j += 8192) {
            const int q = qlab[j];
            c0 += (q == 0); c1 += (q == 1); cv += (q >= 0);
        }
        #pragma unroll
        for (int o = 32; o > 0; o >>= 1) {
            c0 += __shfl_xor(c0, o); c1 += __shfl_xor(c1, o); cv += __shfl_xor(cv, o);
        }
        if ((t & 63) == 0) {
            atomicAdd(&qcnt[0], c0); atomicAdd(&qcnt[1], c1); atomicAdd(&qcnt[2], cv);
        }
    } else {
        const int bid = b - 5664;
        const float* A; short* At; int R, C, bx, by;
        if (bid < 144) { A = W1; At = w1t; R = EMB_D_; C = EMB_D_;  bx = (bid % 12) * 64; by = (bid / 12) * 64; }
        else { const int b2 = bid - 144; A = W2; At = w2t; R = EMB_D_; C = PROJ_D_; bx = (b2 & 1) * 64; by = (b2 >> 1) * 64; }
        const int tc = t & 63, tg = t >> 6;
        #pragma unroll
        for (int i = 0; i < 16; i++) {
            const int r = tg * 16 + i;
            tile[r][tc] = A[(size_t)(by + r) * C + bx + tc];
        }
        __syncthreads();
        #pragma unroll
        for (int i = 0; i < 16; i++) {
            const int r = tg * 16 + i;
            At[(size_t)(bx + r) * R + by + tc] = (short)f2bf(tile[tc][r]);
        }
    }
}

// ---------------------------------------------------------------------------
// u8-code top-512 lse (verified r10/r11).
// ---------------------------------------------------------------------------
__global__ void __launch_bounds__(256) topk_lse_u8(const unsigned char* __restrict__ codes,
                                                   const int* __restrict__ qcnt,
                                                   const int* __restrict__ labels,
                                                   float* __restrict__ lseq,
                                                   int* __restrict__ flag) {
    const int row = blockIdx.x, t = threadIdx.x;
    __shared__ int hist[256];
    __shared__ int suf[256];
    __shared__ int s_bin;
    __shared__ float scf[4];
    hist[t] = 0;
    __syncthreads();

    const uint4* rowp = (const uint4*)(codes + (size_t)row * QUEUE_N);
    #pragma unroll
    for (int k = 0; k < 8; k++) {
        const uint4 u = rowp[k * 256 + t];
        const unsigned w[4] = {u.x, u.y, u.z, u.w};
        #pragma unroll
        for (int q = 0; q < 4; q++)
            #pragma unroll
            for (int s = 0; s < 4; s++) {
                const int c = (w[q] >> (8 * s)) & 0xFF;
                if (c) atomicAdd(&hist[c], 1);
            }
    }
    __syncthreads();

    suf[t] = hist[t];
    __syncthreads();
    for (int off = 1; off < 256; off <<= 1) {
        int add = (t + off < 256) ? suf[t + off] : 0;
        __syncthreads();
        suf[t] += add;
        __syncthreads();
    }
    const int total = suf[1];
    const int opp   = opp_of(labels[row], qcnt);
    if (total < HARD_K_ || opp < HARD_K_) {
        if (t == 0) flag[row] = 0;
        return;
    }
    {
        const int above = (t < 255) ? suf[t + 1] : 0;
        if (suf[t] >= HARD_K_ && above < HARD_K_) s_bin = t;
    }
    __syncthreads();
    const int b = s_bin;

    float e = 0.0f;
    if (t > b && hist[t]) e = (float)hist[t] * __expf((WLO + ((float)t - 0.5f) * BINW - 1.0f) * INV_T);
    #pragma unroll
    for (int o = 32; o > 0; o >>= 1) e += __shfl_xor(e, o);
    if ((t & 63) == 0) scf[t >> 6] = e;
    __syncthreads();
    if (t == 0) {
        const float Eab  = scf[0] + scf[1] + scf[2] + scf[3];
        const int   cab  = (b < 255) ? suf[b + 1] : 0;
        const float ebin = __expf((WLO + ((float)b - 0.5f) * BINW - 1.0f) * INV_T);
        const float sadj = Eab + (float)(HARD_K_ - cab) * ebin;
        lseq[row] = INV_T + __logf(sadj);
        flag[row] = 1;
    }
}

// ---------------------------------------------------------------------------
// Histogram crossing search (verified r1-r11; used by fallback)
// ---------------------------------------------------------------------------
__device__ __forceinline__ void find_crossing(int* hist, int* grp, int target,
                                              int* s_bin, int* s_chi) {
    const int t = threadIdx.x;
    const int b0 = hist[4*t], b1 = hist[4*t+1], b2 = hist[4*t+2], b3 = hist[4*t+3];
    grp[t] = b0 + b1 + b2 + b3;
    __syncthreads();
    for (int off = 1; off < 256; off <<= 1) {
        int add = (t + off < 256) ? grp[t + off] : 0;
        __syncthreads();
        grp[t] += add;
        __syncthreads();
    }
    int cab = (t < 255) ? grp[t + 1] : 0;
    const int hb[4] = {b0, b1, b2, b3};
    #pragma unroll
    for (int i = 3; i >= 0; i--) {
        const int h = hb[i];
        if (cab < target && cab + h >= target) { *s_bin = 4*t + i; *s_chi = cab; }
        cab += h;
    }
    __syncthreads();
}

// iterate all 128 packed-half2 values
#define FOR_ALL_VALS(BODY)                                                   \
    _Pragma("unroll")                                                        \
    for (int _k = 0; _k < 64; _k++) {                                        \
        const float2 _f = __half22float2(*(const __half2*)&dv[_k]);          \
        { const float v = _f.x; BODY }                                       \
        { const float v = _f.y; BODY }                                       \
    }

// ---------------------------------------------------------------------------
// Exact fallback (verified r5-r11; normally zero rows). Recomputes from zb/qb.
// ---------------------------------------------------------------------------
__global__ void __launch_bounds__(256) topk_lse_fallback(const short* __restrict__ zb,
                                                         const short* __restrict__ qb,
                                                         const int* __restrict__ labels,
                                                         const int* __restrict__ qlab,
                                                         const int* __restrict__ qcnt,
                                                         const int* __restrict__ flag,
                                                         float* __restrict__ lseq) {
    const int row = blockIdx.x, t = threadIdx.x;
    if (flag[row]) return;
    const int opp = opp_of(labels[row], qcnt);

    __shared__ float zrow[128];
    __shared__ int hist[1024];
    __shared__ int grp[256];
    __shared__ int s_bin, s_chi, s_bin2, s_chi2;
    __shared__ float scf[4]; __shared__ int sci[4];
    if (t < 128) zrow[t] = bf2f(zb[(size_t)row * 128 + t]);
    __syncthreads();

    const int mylab = labels[row];
    unsigned dv[64];
    float rm = -1e30f, rs = 0.0f;
    for (int k = 0; k < 128; k++) {
        const int j = t + 256 * k;
        float d = 0.0f;
        #pragma unroll
        for (int c = 0; c < 16; ++c) {
            const short8 qv = *(const short8*)(qb + (size_t)j * 128 + c * 8);
            #pragma unroll
            for (int e = 0; e < 8; ++e) d += zrow[c * 8 + e] * bf2f(qv[e]);
        }
        if (j < HARD_K_) {
            const float sv = d * INV_T;
            if (sv > rm) { rs = rs * __expf(rm - sv) + 1.0f; rm = sv; }
            else         { rs += __expf(sv - rm); }
        }
        const int q = qlab[j];
        const float mv = (q != mylab && q >= 0) ? d : -65504.0f;
        const __half h = __float2half(mv);
        unsigned short* p = (unsigned short*)&dv[k >> 1];
        p[k & 1] = *(const unsigned short*)&h;
    }

    if (opp == 0) {
        #pragma unroll
        for (int o = 32; o > 0; o >>= 1) {
            const float om = __shfl_xor(rm, o), os = __shfl_xor(rs, o);
            const float nm = fmaxf(rm, om);
            rs = rs * __expf(rm - nm) + os * __expf(om - nm);
            rm = nm;
        }
        if ((t & 63) == 0) { scf[t >> 6] = rm; ((float*)sci)[t >> 6] = rs; }
        __syncthreads();
        if (t == 0) {
            float M = -1e30f, Sx = 0.0f;
            for (int w = 0; w < 4; w++) {
                const float nm = fmaxf(M, scf[w]);
                Sx = Sx * __expf(M - nm) + ((float*)sci)[w] * __expf(scf[w] - nm);
                M = nm;
            }
            lseq[row] = M + __logf(Sx);
        }
        return;
    }
    if (opp < HARD_K_) {
        float mm = -1e30f, ss = 0.0f;
        FOR_ALL_VALS(
            if (v > -60000.0f) {
                const float sv = v * INV_T;
                if (sv > mm) { ss = ss * __expf(mm - sv) + 1.0f; mm = sv; }
                else         { ss += __expf(sv - mm); }
            } )
        #pragma unroll
        for (int o = 32; o > 0; o >>= 1) {
            const float om = __shfl_xor(mm, o), os = __shfl_xor(ss, o);
            const float nm = fmaxf(mm, om);
            ss = ss * __expf(mm - nm) + os * __expf(om - nm);
            mm = nm;
        }
        if ((t & 63) == 0) { scf[t >> 6] = mm; ((float*)sci)[t >> 6] = ss; }
        __syncthreads();
        if (t == 0) {
            float M = -1e30f, Sx = 0.0f;
            for (int w = 0; w < 4; w++) {
                const float nm = fmaxf(M, scf[w]);
                Sx = Sx * __expf(M - nm) + ((float*)sci)[w] * __expf(scf[w] - nm);
                M = nm;
            }
            lseq[row] = M + __logf(Sx);
        }
        return;
    }

    float mloc = -1e30f;
    FOR_ALL_VALS( mloc = fmaxf(mloc, v); )
    #pragma unroll
    for (int o = 32; o > 0; o >>= 1) mloc = fmaxf(mloc, __shfl_xor(mloc, o));
    if ((t & 63) == 0) scf[t >> 6] = mloc;
    __syncthreads();
    const float m = fmaxf(fmaxf(scf[0], scf[1]), fmaxf(scf[2], scf[3]));

    int c1 = 0, c2 = 0;
    const float w1 = m - 0.25f, w2 = m - 1.0f;
    FOR_ALL_VALS( c1 += (v >= w1); c2 += (v >= w2); )
    #pragma unroll
    for (int o = 32; o > 0; o >>= 1) { c1 += __shfl_xor(c1, o); c2 += __shfl_xor(c2, o); }
    if ((t & 63) == 0) { sci[t >> 6] = c1; }
    __syncthreads();
    const int C1 = sci[0] + sci[1] + sci[2] + sci[3];
    __syncthreads();
    if ((t & 63) == 0) { sci[t >> 6] = c2; }
    __syncthreads();
    const int C2 = sci[0] + sci[1] + sci[2] + sci[3];

    float lo;
    if      (C1 >= HARD_K_) lo = w1;
    else if (C2 >= HARD_K_) lo = w2;
    else                    lo = -1.01f;
    const float range = m - lo;
    const float scale = 1024.0f / range;

    for (int k = t; k < 1024; k += 256) hist[k] = 0;
    __syncthreads();
    FOR_ALL_VALS(
        if (v >= lo) {
            const float bf = fminf((v - lo) * scale, 1023.0f);
            atomicAdd(&hist[(int)bf], 1);
        } )
    __syncthreads();
    find_crossing(hist, grp, HARD_K_, &s_bin, &s_chi);
    const int   bin1 = s_bin, chi1 = s_chi;
    const float binw = range * (1.0f / 1024.0f);
    const float lo1  = lo + bin1 * binw;
    const float ssc  = 1024.0f / binw;

    for (int k = t; k < 1024; k += 256) hist[k] = 0;
    __syncthreads();
    FOR_ALL_VALS(
        if (v >= lo) {
            const float bf = fminf((v - lo) * scale, 1023.0f);
            if ((int)bf == bin1) {
                const float sf = fminf(fmaxf((v - lo1) * ssc, 0.0f), 1023.0f);
                atomicAdd(&hist[(int)sf], 1);
            }
        } )
    __syncthreads();
    find_crossing(hist, grp, HARD_K_ - chi1, &s_bin2, &s_chi2);
    const float thr = lo1 + s_bin2 * (binw * (1.0f / 1024.0f));

    float sl = 0.0f; int cg = 0;
    FOR_ALL_VALS( if (v > thr) { cg++; sl += __expf((v - m) * INV_T); } )
    #pragma unroll
    for (int o = 32; o > 0; o >>= 1) { sl += __shfl_xor(sl, o); cg += __shfl_xor(cg, o); }
    if ((t & 63) == 0) { scf[t >> 6] = sl; sci[t >> 6] = cg; }
    __syncthreads();
    if (t == 0) {
        const float slt = scf[0] + scf[1] + scf[2] + scf[3];
        const int   cgt = sci[0] + sci[1] + sci[2] + sci[3];
        const float sadj = slt + ((float)HARD_K_ - (float)cgt) * __expf((thr - m) * INV_T);
        lseq[row] = m * INV_T + __logf(sadj);
    }
}

// ---------------------------------------------------------------------------
// Batch lse + positive-pair loss over packed bf16 S. One WAVE per row.
// Permuted-label LDS table (linear reads); logical col recomputed for the
// diagonal check: col(idx) = (idx & ~63) + (idx&3)*16 + ((idx>>2)&15).
// Math verified r6-r11 (fixed-ref lse).
// ---------------------------------------------------------------------------
__global__ void __launch_bounds__(256) batch_row_loss(const short* __restrict__ S,
                                                      const int* __restrict__ labels,
                                                      const float* __restrict__ lse_queue,
                                                      float* __restrict__ part_out,
                                                      int* __restrict__ cnt_out) {
    const int t = threadIdx.x;
    const int wv = t >> 6, lane = t & 63;
    const int row = blockIdx.x * 4 + wv;
    __shared__ int plab[BATCH_N];      // labels in packed order
    for (int idx = t; idx < BATCH_N; idx += 256) {
        const int col = (idx & ~63) + ((idx & 3) << 4) + ((idx >> 2) & 15);
        plab[idx] = labels[col];
    }
    __syncthreads();
    const int myLab = labels[row];
    const uint4* rp = (const uint4*)(S + (size_t)row * BATCH_N);  // 8 bf16 per uint4

    float v[32]; int lb[32];
    #pragma unroll
    for (int kk = 0; kk < 4; kk++) {
        const uint4 u = rp[lane + 64 * kk];
        const unsigned w[4] = {u.x, u.y, u.z, u.w};
        const int base = (lane + 64 * kk) * 8;
        #pragma unroll
        for (int q = 0; q < 4; q++) {
            v[kk * 8 + 2 * q]     = __uint_as_float(w[q] << 16);
            v[kk * 8 + 2 * q + 1] = __uint_as_float(w[q] & 0xFFFF0000u);
            lb[kk * 8 + 2 * q]     = plab[base + 2 * q];
            lb[kk * 8 + 2 * q + 1] = plab[base + 2 * q + 1];
        }
    }

    // pass A: negatives exp-sum at fixed reference REF = 1/T
    const float REF = INV_T;
    float sneg = 0.0f;
    #pragma unroll
    for (int k = 0; k < 32; k++) {
        const float ev = __expf(v[k] * INV_T - REF);
        sneg += (lb[k] != myLab) ? ev : 0.0f;
    }
    #pragma unroll
    for (int o = 32; o > 0; o >>= 1) sneg += __shfl_xor(sneg, o);
    const float lseb = (sneg > 0.0f) ? REF + __logf(sneg) : -1e30f;
    const float Lq = lse_queue[row];
    const float mx0 = fmaxf(lseb, Lq), mn0 = fminf(lseb, Lq);
    const float L = mx0 + __logf(1.0f + __expf(mn0 - mx0));

    // pass B: positive-pair terms logaddexp(sv, L) - sv
    float part = 0.0f; int cnt = 0;
    #pragma unroll
    for (int k = 0; k < 32; k++) {
        const int idx = ((lane + 64 * (k >> 3)) * 8) + (k & 7);
        const int col = (idx & ~63) + ((idx & 3) << 4) + ((idx >> 2) & 15);
        if (lb[k] == myLab && col != row) {
            const float sv = v[k] * INV_T;
            const float mx = fmaxf(sv, L), mn = fminf(sv, L);
            part += (mx - sv) + __logf(1.0f + __expf(mn - mx));
            cnt++;
        }
    }
    #pragma unroll
    for (int o = 32; o > 0; o >>= 1) { part += __shfl_xor(part, o); cnt += __shfl_xor(cnt, o); }
    if (lane == 0) { part_out[row] = part; cnt_out[row] = cnt; }
}

// reduce 2048 per-row partials -> scalar loss. One block.
__global__ void __launch_bounds__(256) finalize_loss(const float* __restrict__ part,
                                                     const int* __restrict__ cnt,
                                                     float* __restrict__ out) {
    const int t = threadIdx.x;
    float s = 0.0f; int c = 0;
    #pragma unroll
    for (int k = 0; k < 8; k++) { s += part[t + 256 * k]; c += cnt[t + 256 * k]; }
    #pragma unroll
    for (int o = 32; o > 0; o >>= 1) { s += __shfl_xor(s, o); c += __shfl_xor(c, o); }
    __shared__ float sf[4]; __shared__ int sc[4];
    if ((t & 63) == 0) { sf[t >> 6] = s; sc[t >> 6] = c; }
    __syncthreads();
    if (t == 0) {
        const float st = sf[0] + sf[1] + sf[2] + sf[3];
        const int   ct = sc[0] + sc[1] + sc[2] + sc[3];
        out[0] = (ct > 0) ? (st / (float)ct) : 0.0f;
    }
}

// ---------------------------------------------------------------------------
extern "C" void kernel_launch(void* const* d_in, const int* in_sizes, int n_in,
                              void* d_out, int out_size, void* d_ws, size_t ws_size,
                              hipStream_t stream) {
    const float* emb    = (const float*)d_in[0];
    const int*   labels = (const int*)  d_in[1];
    const float* W1     = (const float*)d_in[2];
    const float* b1     = (const float*)d_in[3];
    const float* W2     = (const float*)d_in[4];
    const float* b2     = (const float*)d_in[5];
    const float* queue  = (const float*)d_in[6];
    const int*   qlab   = (const int*)  d_in[7];

    char* ws = (char*)d_ws;
    short*         Sbuf  = (short*)        (ws);              // 8388608 used (region 16 MB kept)
    unsigned char* codes = (unsigned char*)(ws + 16777216);   // 67108864
    short*         embb  = (short*)        (ws + 83886080);   // 3145728
    short*         hbf   = (short*)        (ws + 87031808);   // 3145728
    short*         zb    = (short*)        (ws + 90177536);   // 524288
    short*         qb    = (short*)        (ws + 90701824);   // 8388608
    short*         w1t   = (short*)        (ws + 99090432);   // 1179648
    short*         w2t   = (short*)        (ws + 100270080);  // 196608
    float*         lseq  = (float*)        (ws + 100466688);  // 8192
    int*           flag  = (int*)          (ws + 100474880);  // 8192
    int*           qcnt  = (int*)          (ws + 100483072);  // 64
    float*         partb = (float*)        (ws + 100483136);  // 8192
    int*           cntb  = (int*)          (ws + 100491328);  // 8192

    hipMemsetAsync(ws + 100474880, 0, 8192 + 64, stream);     // flag + qcnt

    dim3 blk(256);
    prep<<<dim3(5832), blk, 0, stream>>>(emb, embb, queue, qb, qlab, qcnt, W1, w1t, W2, w2t);
    mfma_nt_k<short, true><<<dim3(EMB_D_ / 128, BATCH_N / 128), blk, 0, stream>>>(embb, w1t, b1, hbf, EMB_D_, EMB_D_);
    mfma_z_norm<<<dim3(BATCH_N / 128), blk, 0, stream>>>(hbf, w2t, b2, zb);
    mfma_mask8<<<dim3(QUEUE_N / 256, BATCH_N / 128), blk, 0, stream>>>(zb, qb, codes, labels, qlab);
    topk_lse_u8<<<BATCH_N, blk, 0, stream>>>(codes, qcnt, labels, lseq, flag);
    topk_lse_fallback<<<BATCH_N, blk, 0, stream>>>(zb, qb, labels, qlab, qcnt, flag, lseq);
    mfma_s_pack<<<dim3(BATCH_N / 128, BATCH_N / 128), blk, 0, stream>>>(zb, zb, Sbuf, BATCH_N);
    batch_row_loss<<<BATCH_N / 4, blk, 0, stream>>>(Sbuf, labels, lseq, partb, cntb);
    finalize_loss<<<1, blk, 0, stream>>>(partb, cntb, (float*)d_out);
}

// Round 13
// 167.052 us; speedup vs baseline: 2.6987x; 1.0593x over previous
//
#include <hip/hip_runtime.h>
#include <hip/hip_fp16.h>

#define BATCH_N   2048
#define EMB_D_    768
#define PROJ_D_   128
#define QUEUE_N   32768
#define HARD_K_   512
static constexpr float INV_T  = 1.0f / 0.07f;
static constexpr float WLO    = 0.12f;              // code-0 boundary (512th opp val ~0.164)
static constexpr float S8ENC  = 255.0f / 0.88f;     // encode scale
static constexpr float BINW   = 0.88f / 255.0f;     // code bin width

typedef __attribute__((ext_vector_type(8))) short short8;
typedef __attribute__((ext_vector_type(4))) short short4v;
typedef __attribute__((ext_vector_type(4))) float f32x4;

__device__ __forceinline__ unsigned short f2bf(float f) {
    unsigned u = __float_as_uint(f);
    unsigned r = u + 0x7fffu + ((u >> 16) & 1u);   // RNE
    return (unsigned short)(r >> 16);
}
__device__ __forceinline__ float bf2f(short s) {
    return __uint_as_float(((unsigned)(unsigned short)s) << 16);
}
__device__ __forceinline__ int opp_of(int mylab, const int* __restrict__ qcnt) {
    const int same = (mylab == 0) ? qcnt[0] : ((mylab == 1) ? qcnt[1] : 0);
    return qcnt[2] - same;
}

// ---------------------------------------------------------------------------
// S GEMM: bf16 MFMA NT, K=128, packed bf16 output (verified r12).
// ---------------------------------------------------------------------------
__global__ void __launch_bounds__(256) mfma_s_pack(const short* __restrict__ Ab,
                                                   const short* __restrict__ Bb,
                                                   short* __restrict__ C, int N) {
    __shared__ __align__(16) short As[128 * 128];
    __shared__ __align__(16) short Bs[128 * 128];
    const int t = threadIdx.x;
    const int lane = t & 63, wv = t >> 6;
    const int l16 = lane & 15, l4 = lane >> 4;
    const int m0 = blockIdx.y * 128, n0 = blockIdx.x * 128;

    #pragma unroll
    for (int it = 0; it < 8; ++it) {
        const int r = it * 4 + wv, row = r * 4 + l4, cg = l16 ^ (row & 15);
        __builtin_amdgcn_global_load_lds(
            (const __attribute__((address_space(1))) void*)(Ab + (size_t)(m0 + row) * 128 + cg * 8),
            (__attribute__((address_space(3))) void*)(As + r * 512), 16, 0, 0);
    }
    #pragma unroll
    for (int it = 0; it < 8; ++it) {
        const int r = it * 4 + wv, row = r * 4 + l4, cg = l16 ^ (row & 15);
        __builtin_amdgcn_global_load_lds(
            (const __attribute__((address_space(1))) void*)(Bb + (size_t)(n0 + row) * 128 + cg * 8),
            (__attribute__((address_space(3))) void*)(Bs + r * 512), 16, 0, 0);
    }
    __syncthreads();

    const int wm = (wv & 1) * 64, wn = (wv >> 1) * 64;
    f32x4 acc[4][4];
    #pragma unroll
    for (int i = 0; i < 4; ++i)
        #pragma unroll
        for (int j = 0; j < 4; ++j) acc[i][j] = f32x4{0.f, 0.f, 0.f, 0.f};

    #pragma unroll
    for (int ks = 0; ks < 4; ++ks) {
        short8 af[4], bfr[4];
        const int ch = (ks * 4 + l4) ^ l16;
        #pragma unroll
        for (int i = 0; i < 4; ++i) {
            af[i]  = *(const short8*)(As + (wm + i * 16 + l16) * 128 + ch * 8);
            bfr[i] = *(const short8*)(Bs + (wn + i * 16 + l16) * 128 + ch * 8);
        }
        #pragma unroll
        for (int i = 0; i < 4; ++i)
            #pragma unroll
            for (int j = 0; j < 4; ++j)
                acc[i][j] = __builtin_amdgcn_mfma_f32_16x16x32_bf16(af[i], bfr[j], acc[i][j], 0, 0, 0);
    }
    #pragma unroll
    for (int i = 0; i < 4; ++i)
        #pragma unroll
        for (int r = 0; r < 4; ++r) {
            const int m = m0 + wm + i * 16 + l4 * 4 + r;
            union { unsigned short u[4]; uint2 d; } pk;
            #pragma unroll
            for (int j = 0; j < 4; ++j) pk.u[j] = f2bf(acc[i][j][r]);
            *(uint2*)(C + (size_t)m * N + n0 + wn + l16 * 4) = pk.d;
        }
}

// ---------------------------------------------------------------------------
// Masked queue GEMM -> u8 codes, packed dword stores (verified r11/r12).
// FOUR N-tiles per block: A-tile + row labels staged once; each tile's
// epilogue overlaps the next tile's B-staging (r12 barrier pattern, looped).
// ---------------------------------------------------------------------------
__global__ void __launch_bounds__(256) mfma_mask8(const short* __restrict__ Ab,
                                                  const short* __restrict__ Bb,
                                                  unsigned char* __restrict__ codes,
                                                  const int* __restrict__ labA,
                                                  const int* __restrict__ labB) {
    __shared__ __align__(16) short As[128 * 128];
    __shared__ __align__(16) short Bs[128 * 128];
    const int t = threadIdx.x;
    const int lane = t & 63, wv = t >> 6;
    const int l16 = lane & 15, l4 = lane >> 4;
    const int m0 = blockIdx.y * 128;
    const int wm = (wv & 1) * 64, wn = (wv >> 1) * 64;

    #pragma unroll
    for (int it = 0; it < 8; ++it) {
        const int r = it * 4 + wv, row = r * 4 + l4, cg = l16 ^ (row & 15);
        __builtin_amdgcn_global_load_lds(
            (const __attribute__((address_space(1))) void*)(Ab + (size_t)(m0 + row) * 128 + cg * 8),
            (__attribute__((address_space(3))) void*)(As + r * 512), 16, 0, 0);
    }
    {
        const int n0 = (blockIdx.x * 4) * 128;
        #pragma unroll
        for (int it = 0; it < 8; ++it) {
            const int r = it * 4 + wv, row = r * 4 + l4, cg = l16 ^ (row & 15);
            __builtin_amdgcn_global_load_lds(
                (const __attribute__((address_space(1))) void*)(Bb + (size_t)(n0 + row) * 128 + cg * 8),
                (__attribute__((address_space(3))) void*)(Bs + r * 512), 16, 0, 0);
        }
    }

    int la[16];
    #pragma unroll
    for (int i = 0; i < 4; ++i)
        #pragma unroll
        for (int r = 0; r < 4; ++r)
            la[i * 4 + r] = labA[m0 + wm + i * 16 + l4 * 4 + r];
    const float C0 = 1.0f - WLO * S8ENC;
    __syncthreads();

    #pragma unroll
    for (int tt = 0; tt < 4; ++tt) {
        const int n0 = (blockIdx.x * 4 + tt) * 128;

        f32x4 acc[4][4];
        #pragma unroll
        for (int i = 0; i < 4; ++i)
            #pragma unroll
            for (int j = 0; j < 4; ++j) acc[i][j] = f32x4{0.f, 0.f, 0.f, 0.f};

        #pragma unroll
        for (int ks = 0; ks < 4; ++ks) {
            short8 af[4], bfr[4];
            const int ch = (ks * 4 + l4) ^ l16;
            #pragma unroll
            for (int i = 0; i < 4; ++i) {
                af[i]  = *(const short8*)(As + (wm + i * 16 + l16) * 128 + ch * 8);
                bfr[i] = *(const short8*)(Bs + (wn + i * 16 + l16) * 128 + ch * 8);
            }
            #pragma unroll
            for (int i = 0; i < 4; ++i)
                #pragma unroll
                for (int j = 0; j < 4; ++j)
                    acc[i][j] = __builtin_amdgcn_mfma_f32_16x16x32_bf16(af[i], bfr[j], acc[i][j], 0, 0, 0);
        }

        if (tt < 3) {
            __syncthreads();          // all waves done reading Bs tile tt
            const int n1 = (blockIdx.x * 4 + tt + 1) * 128;
            #pragma unroll
            for (int it = 0; it < 8; ++it) {
                const int r = it * 4 + wv, row = r * 4 + l4, cg = l16 ^ (row & 15);
                __builtin_amdgcn_global_load_lds(
                    (const __attribute__((address_space(1))) void*)(Bb + (size_t)(n1 + row) * 128 + cg * 8),
                    (__attribute__((address_space(3))) void*)(Bs + r * 512), 16, 0, 0);
            }
        }

        // epilogue for this tile (overlaps next tile's B staging)
        float a0[4], a1[4];
        #pragma unroll
        for (int j = 0; j < 4; ++j) {
            const int q = labB[n0 + wn + j * 16 + l16];
            a0[j] = (q >= 0 && q != 0) ? C0 : -1e9f;
            a1[j] = (q >= 0 && q != 1) ? C0 : -1e9f;
        }
        #pragma unroll
        for (int i = 0; i < 4; ++i) {
            #pragma unroll
            for (int r = 0; r < 4; ++r) {
                const int m  = m0 + wm + i * 16 + l4 * 4 + r;
                const bool z = (la[i * 4 + r] == 0);
                unsigned pk = 0;
                #pragma unroll
                for (int j = 0; j < 4; ++j) {
                    const float add = z ? a0[j] : a1[j];
                    const float f = fmaf(acc[i][j][r], S8ENC, add);
#if __has_builtin(__builtin_amdgcn_cvt_pk_u8_f32)
                    pk = __builtin_amdgcn_cvt_pk_u8_f32(f, j, pk);
#else
                    const unsigned c = (unsigned)fminf(fmaxf(f, 0.0f), 255.0f);
                    pk |= c << (8 * j);
#endif
                }
                *(unsigned*)(codes + (size_t)m * QUEUE_N + n0 + wn + l16 * 4) = pk;
            }
        }
        if (tt < 3) __syncthreads();  // next tile's B staged (barrier drains vmcnt)
    }
}

// ---------------------------------------------------------------------------
// GEMM1: bf16 MFMA NT, 64x128 (MxN) tile, K-loop, fused bias+ReLU, bf16 out.
// 192-block grid (was 96 at 128x128 -> half the GPU idle). Wave wv: all 64
// rows x cols [wv*32, wv*32+32), acc[4][2]. Same XOR staging (row&15 = l16).
// ---------------------------------------------------------------------------
__global__ void __launch_bounds__(256) mfma_h64(const short* __restrict__ Ab,
                                                const short* __restrict__ Bb,
                                                const float* __restrict__ bias,
                                                short* __restrict__ C,
                                                int N, int K) {
    __shared__ __align__(16) short As[64 * 128];    // 16 KB
    __shared__ __align__(16) short Bs[128 * 128];   // 32 KB
    const int t = threadIdx.x;
    const int lane = t & 63, wv = t >> 6;
    const int l16 = lane & 15, l4 = lane >> 4;
    const int m0 = blockIdx.y * 64, n0 = blockIdx.x * 128;
    const int wn = wv * 32;

    f32x4 acc[4][2];
    #pragma unroll
    for (int i = 0; i < 4; ++i)
        #pragma unroll
        for (int j = 0; j < 2; ++j) acc[i][j] = f32x4{0.f, 0.f, 0.f, 0.f};

    for (int kb = 0; kb < K; kb += 128) {
        __syncthreads();
        #pragma unroll
        for (int it = 0; it < 4; ++it) {            // A: 16 units of 512 shorts
            const int r = it * 4 + wv, row = r * 4 + l4, cg = l16 ^ (row & 15);
            __builtin_amdgcn_global_load_lds(
                (const __attribute__((address_space(1))) void*)(Ab + (size_t)(m0 + row) * K + kb + cg * 8),
                (__attribute__((address_space(3))) void*)(As + r * 512), 16, 0, 0);
        }
        #pragma unroll
        for (int it = 0; it < 8; ++it) {            // B: 32 units
            const int r = it * 4 + wv, row = r * 4 + l4, cg = l16 ^ (row & 15);
            __builtin_amdgcn_global_load_lds(
                (const __attribute__((address_space(1))) void*)(Bb + (size_t)(n0 + row) * K + kb + cg * 8),
                (__attribute__((address_space(3))) void*)(Bs + r * 512), 16, 0, 0);
        }
        __syncthreads();
        #pragma unroll
        for (int ks = 0; ks < 4; ++ks) {
            short8 af[4], bfr[2];
            const int ch = (ks * 4 + l4) ^ l16;
            #pragma unroll
            for (int i = 0; i < 4; ++i)
                af[i] = *(const short8*)(As + (i * 16 + l16) * 128 + ch * 8);
            #pragma unroll
            for (int j = 0; j < 2; ++j)
                bfr[j] = *(const short8*)(Bs + (wn + j * 16 + l16) * 128 + ch * 8);
            #pragma unroll
            for (int i = 0; i < 4; ++i)
                #pragma unroll
                for (int j = 0; j < 2; ++j)
                    acc[i][j] = __builtin_amdgcn_mfma_f32_16x16x32_bf16(af[i], bfr[j], acc[i][j], 0, 0, 0);
        }
    }

    float bsv[2];
    #pragma unroll
    for (int j = 0; j < 2; ++j) bsv[j] = bias[n0 + wn + j * 16 + l16];
    #pragma unroll
    for (int i = 0; i < 4; ++i)
        #pragma unroll
        for (int r = 0; r < 4; ++r) {
            const int m = m0 + i * 16 + l4 * 4 + r;
            #pragma unroll
            for (int j = 0; j < 2; ++j) {
                const int n = n0 + wn + j * 16 + l16;
                const float v = fmaxf(acc[i][j][r] + bsv[j], 0.0f);
                C[(size_t)m * N + n] = (short)f2bf(v);
            }
        }
}

// ---------------------------------------------------------------------------
// z-GEMM, 64x128 M-tile (grid 32, was 16), fused bias + row-L2-normalize +
// bf16 cast. Row sumsq block-local in ssq[64]. Structure verified r10-r12.
// ---------------------------------------------------------------------------
__global__ void __launch_bounds__(256) mfma_z_norm64(const short* __restrict__ Ab,
                                                     const short* __restrict__ Bb,
                                                     const float* __restrict__ bias,
                                                     short* __restrict__ zb) {
    __shared__ __align__(16) short As[64 * 128];
    __shared__ __align__(16) short Bs[128 * 128];
    __shared__ float ssq[64];
    const int t = threadIdx.x;
    const int lane = t & 63, wv = t >> 6;
    const int l16 = lane & 15, l4 = lane >> 4;
    const int m0 = blockIdx.x * 64;
    const int wn = wv * 32;
    const int K = EMB_D_;

    if (t < 64) ssq[t] = 0.0f;    // ordered before epilogue by K-loop barriers

    f32x4 acc[4][2];
    #pragma unroll
    for (int i = 0; i < 4; ++i)
        #pragma unroll
        for (int j = 0; j < 2; ++j) acc[i][j] = f32x4{0.f, 0.f, 0.f, 0.f};

    for (int kb = 0; kb < K; kb += 128) {
        __syncthreads();
        #pragma unroll
        for (int it = 0; it < 4; ++it) {
            const int r = it * 4 + wv, row = r * 4 + l4, cg = l16 ^ (row & 15);
            __builtin_amdgcn_global_load_lds(
                (const __attribute__((address_space(1))) void*)(Ab + (size_t)(m0 + row) * K + kb + cg * 8),
                (__attribute__((address_space(3))) void*)(As + r * 512), 16, 0, 0);
        }
        #pragma unroll
        for (int it = 0; it < 8; ++it) {
            const int r = it * 4 + wv, row = r * 4 + l4, cg = l16 ^ (row & 15);
            __builtin_amdgcn_global_load_lds(
                (const __attribute__((address_space(1))) void*)(Bb + (size_t)(row) * K + kb + cg * 8),
                (__attribute__((address_space(3))) void*)(Bs + r * 512), 16, 0, 0);
        }
        __syncthreads();
        #pragma unroll
        for (int ks = 0; ks < 4; ++ks) {
            short8 af[4], bfr[2];
            const int ch = (ks * 4 + l4) ^ l16;
            #pragma unroll
            for (int i = 0; i < 4; ++i)
                af[i] = *(const short8*)(As + (i * 16 + l16) * 128 + ch * 8);
            #pragma unroll
            for (int j = 0; j < 2; ++j)
                bfr[j] = *(const short8*)(Bs + (wn + j * 16 + l16) * 128 + ch * 8);
            #pragma unroll
            for (int i = 0; i < 4; ++i)
                #pragma unroll
                for (int j = 0; j < 2; ++j)
                    acc[i][j] = __builtin_amdgcn_mfma_f32_16x16x32_bf16(af[i], bfr[j], acc[i][j], 0, 0, 0);
        }
    }

    float bsv[2];
    #pragma unroll
    for (int j = 0; j < 2; ++j) bsv[j] = bias[wn + j * 16 + l16];
    #pragma unroll
    for (int i = 0; i < 4; ++i)
        #pragma unroll
        for (int r = 0; r < 4; ++r) {
            float p = 0.0f;
            #pragma unroll
            for (int j = 0; j < 2; ++j) {
                acc[i][j][r] += bsv[j];
                p += acc[i][j][r] * acc[i][j][r];
            }
            #pragma unroll
            for (int o = 8; o > 0; o >>= 1) p += __shfl_xor(p, o);
            if (l16 == 0) atomicAdd(&ssq[i * 16 + l4 * 4 + r], p);
        }
    __syncthreads();
    #pragma unroll
    for (int i = 0; i < 4; ++i)
        #pragma unroll
        for (int r = 0; r < 4; ++r) {
            const int lrow = i * 16 + l4 * 4 + r;
            const float inv = rsqrtf(ssq[lrow]);
            #pragma unroll
            for (int j = 0; j < 2; ++j)
                zb[(size_t)(m0 + lrow) * PROJ_D_ + wn + j * 16 + l16] =
                    (short)f2bf(acc[i][j][r] * inv);
        }
}

// ---------------------------------------------------------------------------
// Merged prep (verified r11/r12): emb cast + queue cast + qlab census +
// W1/W2 transpose.
// ---------------------------------------------------------------------------
__global__ void __launch_bounds__(256) prep(const float* __restrict__ emb, short* __restrict__ embb,
                                            const float* __restrict__ queue, short* __restrict__ qb,
                                            const int* __restrict__ qlab, int* __restrict__ qcnt,
                                            const float* __restrict__ W1, short* __restrict__ w1t,
                                            const float* __restrict__ W2, short* __restrict__ w2t) {
    __shared__ float tile[64][65];
    const int b = blockIdx.x, t = threadIdx.x;
    if (b < 1536) {
        const int i = b * 256 + t;
        const float4 f = ((const float4*)emb)[i];
        short4v o = {(short)f2bf(f.x), (short)f2bf(f.y), (short)f2bf(f.z), (short)f2bf(f.w)};
        ((short4v*)embb)[i] = o;
    } else if (b < 5632) {
        const int i = (b - 1536) * 256 + t;
        const float4 f = ((const float4*)queue)[i];
        short4v o = {(short)f2bf(f.x), (short)f2bf(f.y), (short)f2bf(f.z), (short)f2bf(f.w)};
        ((short4v*)qb)[i] = o;
    } else if (b < 5664) {
        const int i = (b - 5632) * 256 + t;
        int c0 = 0, c1 = 0, cv = 0;
        for (int j = i; j < QUEUE_N; j += 8192) {
            const int q = qlab[j];
            c0 += (q == 0); c1 += (q == 1); cv += (q >= 0);
        }
        #pragma unroll
        for (int o = 32; o > 0; o >>= 1) {
            c0 += __shfl_xor(c0, o); c1 += __shfl_xor(c1, o); cv += __shfl_xor(cv, o);
        }
        if ((t & 63) == 0) {
            atomicAdd(&qcnt[0], c0); atomicAdd(&qcnt[1], c1); atomicAdd(&qcnt[2], cv);
        }
    } else {
        const int bid = b - 5664;
        const float* A; short* At; int R, C, bx, by;
        if (bid < 144) { A = W1; At = w1t; R = EMB_D_; C = EMB_D_;  bx = (bid % 12) * 64; by = (bid / 12) * 64; }
        else { const int b2 = bid - 144; A = W2; At = w2t; R = EMB_D_; C = PROJ_D_; bx = (b2 & 1) * 64; by = (b2 >> 1) * 64; }
        const int tc = t & 63, tg = t >> 6;
        #pragma unroll
        for (int i = 0; i < 16; i++) {
            const int r = tg * 16 + i;
            tile[r][tc] = A[(size_t)(by + r) * C + bx + tc];
        }
        __syncthreads();
        #pragma unroll
        for (int i = 0; i < 16; i++) {
            const int r = tg * 16 + i;
            At[(size_t)(bx + r) * R + by + tc] = (short)f2bf(tile[tc][r]);
        }
    }
}

// ---------------------------------------------------------------------------
// u8-code top-512 lse (verified r10-r12).
// ---------------------------------------------------------------------------
__global__ void __launch_bounds__(256) topk_lse_u8(const unsigned char* __restrict__ codes,
                                                   const int* __restrict__ qcnt,
                                                   const int* __restrict__ labels,
                                                   float* __restrict__ lseq,
                                                   int* __restrict__ flag) {
    const int row = blockIdx.x, t = threadIdx.x;
    __shared__ int hist[256];
    __shared__ int suf[256];
    __shared__ int s_bin;
    __shared__ float scf[4];
    hist[t] = 0;
    __syncthreads();

    const uint4* rowp = (const uint4*)(codes + (size_t)row * QUEUE_N);
    #pragma unroll
    for (int k = 0; k < 8; k++) {
        const uint4 u = rowp[k * 256 + t];
        const unsigned w[4] = {u.x, u.y, u.z, u.w};
        #pragma unroll
        for (int q = 0; q < 4; q++)
            #pragma unroll
            for (int s = 0; s < 4; s++) {
                const int c = (w[q] >> (8 * s)) & 0xFF;
                if (c) atomicAdd(&hist[c], 1);
            }
    }
    __syncthreads();

    suf[t] = hist[t];
    __syncthreads();
    for (int off = 1; off < 256; off <<= 1) {
        int add = (t + off < 256) ? suf[t + off] : 0;
        __syncthreads();
        suf[t] += add;
        __syncthreads();
    }
    const int total = suf[1];
    const int opp   = opp_of(labels[row], qcnt);
    if (total < HARD_K_ || opp < HARD_K_) {
        if (t == 0) flag[row] = 0;
        return;
    }
    {
        const int above = (t < 255) ? suf[t + 1] : 0;
        if (suf[t] >= HARD_K_ && above < HARD_K_) s_bin = t;
    }
    __syncthreads();
    const int b = s_bin;

    float e = 0.0f;
    if (t > b && hist[t]) e = (float)hist[t] * __expf((WLO + ((float)t - 0.5f) * BINW - 1.0f) * INV_T);
    #pragma unroll
    for (int o = 32; o > 0; o >>= 1) e += __shfl_xor(e, o);
    if ((t & 63) == 0) scf[t >> 6] = e;
    __syncthreads();
    if (t == 0) {
        const float Eab  = scf[0] + scf[1] + scf[2] + scf[3];
        const int   cab  = (b < 255) ? suf[b + 1] : 0;
        const float ebin = __expf((WLO + ((float)b - 0.5f) * BINW - 1.0f) * INV_T);
        const float sadj = Eab + (float)(HARD_K_ - cab) * ebin;
        lseq[row] = INV_T + __logf(sadj);
        flag[row] = 1;
    }
}

// ---------------------------------------------------------------------------
// Histogram crossing search (verified r1-r12; used by fallback)
// ---------------------------------------------------------------------------
__device__ __forceinline__ void find_crossing(int* hist, int* grp, int target,
                                              int* s_bin, int* s_chi) {
    const int t = threadIdx.x;
    const int b0 = hist[4*t], b1 = hist[4*t+1], b2 = hist[4*t+2], b3 = hist[4*t+3];
    grp[t] = b0 + b1 + b2 + b3;
    __syncthreads();
    for (int off = 1; off < 256; off <<= 1) {
        int add = (t + off < 256) ? grp[t + off] : 0;
        __syncthreads();
        grp[t] += add;
        __syncthreads();
    }
    int cab = (t < 255) ? grp[t + 1] : 0;
    const int hb[4] = {b0, b1, b2, b3};
    #pragma unroll
    for (int i = 3; i >= 0; i--) {
        const int h = hb[i];
        if (cab < target && cab + h >= target) { *s_bin = 4*t + i; *s_chi = cab; }
        cab += h;
    }
    __syncthreads();
}

// iterate all 128 packed-half2 values
#define FOR_ALL_VALS(BODY)                                                   \
    _Pragma("unroll")                                                        \
    for (int _k = 0; _k < 64; _k++) {                                        \
        const float2 _f = __half22float2(*(const __half2*)&dv[_k]);          \
        { const float v = _f.x; BODY }                                       \
        { const float v = _f.y; BODY }                                       \
    }

// ---------------------------------------------------------------------------
// Exact fallback (verified r5-r12; normally zero rows). Recomputes from zb/qb.
// ---------------------------------------------------------------------------
__global__ void __launch_bounds__(256) topk_lse_fallback(const short* __restrict__ zb,
                                                         const short* __restrict__ qb,
                                                         const int* __restrict__ labels,
                                                         const int* __restrict__ qlab,
                                                         const int* __restrict__ qcnt,
                                                         const int* __restrict__ flag,
                                                         float* __restrict__ lseq) {
    const int row = blockIdx.x, t = threadIdx.x;
    if (flag[row]) return;
    const int opp = opp_of(labels[row], qcnt);

    __shared__ float zrow[128];
    __shared__ int hist[1024];
    __shared__ int grp[256];
    __shared__ int s_bin, s_chi, s_bin2, s_chi2;
    __shared__ float scf[4]; __shared__ int sci[4];
    if (t < 128) zrow[t] = bf2f(zb[(size_t)row * 128 + t]);
    __syncthreads();

    const int mylab = labels[row];
    unsigned dv[64];
    float rm = -1e30f, rs = 0.0f;
    for (int k = 0; k < 128; k++) {
        const int j = t + 256 * k;
        float d = 0.0f;
        #pragma unroll
        for (int c = 0; c < 16; ++c) {
            const short8 qv = *(const short8*)(qb + (size_t)j * 128 + c * 8);
            #pragma unroll
            for (int e = 0; e < 8; ++e) d += zrow[c * 8 + e] * bf2f(qv[e]);
        }
        if (j < HARD_K_) {
            const float sv = d * INV_T;
            if (sv > rm) { rs = rs * __expf(rm - sv) + 1.0f; rm = sv; }
            else         { rs += __expf(sv - rm); }
        }
        const int q = qlab[j];
        const float mv = (q != mylab && q >= 0) ? d : -65504.0f;
        const __half h = __float2half(mv);
        unsigned short* p = (unsigned short*)&dv[k >> 1];
        p[k & 1] = *(const unsigned short*)&h;
    }

    if (opp == 0) {
        #pragma unroll
        for (int o = 32; o > 0; o >>= 1) {
            const float om = __shfl_xor(rm, o), os = __shfl_xor(rs, o);
            const float nm = fmaxf(rm, om);
            rs = rs * __expf(rm - nm) + os * __expf(om - nm);
            rm = nm;
        }
        if ((t & 63) == 0) { scf[t >> 6] = rm; ((float*)sci)[t >> 6] = rs; }
        __syncthreads();
        if (t == 0) {
            float M = -1e30f, Sx = 0.0f;
            for (int w = 0; w < 4; w++) {
                const float nm = fmaxf(M, scf[w]);
                Sx = Sx * __expf(M - nm) + ((float*)sci)[w] * __expf(scf[w] - nm);
                M = nm;
            }
            lseq[row] = M + __logf(Sx);
        }
        return;
    }
    if (opp < HARD_K_) {
        float mm = -1e30f, ss = 0.0f;
        FOR_ALL_VALS(
            if (v > -60000.0f) {
                const float sv = v * INV_T;
                if (sv > mm) { ss = ss * __expf(mm - sv) + 1.0f; mm = sv; }
                else         { ss += __expf(sv - mm); }
            } )
        #pragma unroll
        for (int o = 32; o > 0; o >>= 1) {
            const float om = __shfl_xor(mm, o), os = __shfl_xor(ss, o);
            const float nm = fmaxf(mm, om);
            ss = ss * __expf(mm - nm) + os * __expf(om - nm);
            mm = nm;
        }
        if ((t & 63) == 0) { scf[t >> 6] = mm; ((float*)sci)[t >> 6] = ss; }
        __syncthreads();
        if (t == 0) {
            float M = -1e30f, Sx = 0.0f;
            for (int w = 0; w < 4; w++) {
                const float nm = fmaxf(M, scf[w]);
                Sx = Sx * __expf(M - nm) + ((float*)sci)[w] * __expf(scf[w] - nm);
                M = nm;
            }
            lseq[row] = M + __logf(Sx);
        }
        return;
    }

    float mloc = -1e30f;
    FOR_ALL_VALS( mloc = fmaxf(mloc, v); )
    #pragma unroll
    for (int o = 32; o > 0; o >>= 1) mloc = fmaxf(mloc, __shfl_xor(mloc, o));
    if ((t & 63) == 0) scf[t >> 6] = mloc;
    __syncthreads();
    const float m = fmaxf(fmaxf(scf[0], scf[1]), fmaxf(scf[2], scf[3]));

    int c1 = 0, c2 = 0;
    const float w1 = m - 0.25f, w2 = m - 1.0f;
    FOR_ALL_VALS( c1 += (v >= w1); c2 += (v >= w2); )
    #pragma unroll
    for (int o = 32; o > 0; o >>= 1) { c1 += __shfl_xor(c1, o); c2 += __shfl_xor(c2, o); }
    if ((t & 63) == 0) { sci[t >> 6] = c1; }
    __syncthreads();
    const int C1 = sci[0] + sci[1] + sci[2] + sci[3];
    __syncthreads();
    if ((t & 63) == 0) { sci[t >> 6] = c2; }
    __syncthreads();
    const int C2 = sci[0] + sci[1] + sci[2] + sci[3];

    float lo;
    if      (C1 >= HARD_K_) lo = w1;
    else if (C2 >= HARD_K_) lo = w2;
    else                    lo = -1.01f;
    const float range = m - lo;
    const float scale = 1024.0f / range;

    for (int k = t; k < 1024; k += 256) hist[k] = 0;
    __syncthreads();
    FOR_ALL_VALS(
        if (v >= lo) {
            const float bf = fminf((v - lo) * scale, 1023.0f);
            atomicAdd(&hist[(int)bf], 1);
        } )
    __syncthreads();
    find_crossing(hist, grp, HARD_K_, &s_bin, &s_chi);
    const int   bin1 = s_bin, chi1 = s_chi;
    const float binw = range * (1.0f / 1024.0f);
    const float lo1  = lo + bin1 * binw;
    const float ssc  = 1024.0f / binw;

    for (int k = t; k < 1024; k += 256) hist[k] = 0;
    __syncthreads();
    FOR_ALL_VALS(
        if (v >= lo) {
            const float bf = fminf((v - lo) * scale, 1023.0f);
            if ((int)bf == bin1) {
                const float sf = fminf(fmaxf((v - lo1) * ssc, 0.0f), 1023.0f);
                atomicAdd(&hist[(int)sf], 1);
            }
        } )
    __syncthreads();
    find_crossing(hist, grp, HARD_K_ - chi1, &s_bin2, &s_chi2);
    const float thr = lo1 + s_bin2 * (binw * (1.0f / 1024.0f));

    float sl = 0.0f; int cg = 0;
    FOR_ALL_VALS( if (v > thr) { cg++; sl += __expf((v - m) * INV_T); } )
    #pragma unroll
    for (int o = 32; o > 0; o >>= 1) { sl += __shfl_xor(sl, o); cg += __shfl_xor(cg, o); }
    if ((t & 63) == 0) { scf[t >> 6] = sl; sci[t >> 6] = cg; }
    __syncthreads();
    if (t == 0) {
        const float slt = scf[0] + scf[1] + scf[2] + scf[3];
        const int   cgt = sci[0] + sci[1] + sci[2] + sci[3];
        const float sadj = slt + ((float)HARD_K_ - (float)cgt) * __expf((thr - m) * INV_T);
        lseq[row] = m * INV_T + __logf(sadj);
    }
}

// ---------------------------------------------------------------------------
// Batch lse + positive-pair loss over packed bf16 S (verified r12).
// ---------------------------------------------------------------------------
__global__ void __launch_bounds__(256) batch_row_loss(const short* __restrict__ S,
                                                      const int* __restrict__ labels,
                                                      const float* __restrict__ lse_queue,
                                                      float* __restrict__ part_out,
                                                      int* __restrict__ cnt_out) {
    const int t = threadIdx.x;
    const int wv = t >> 6, lane = t & 63;
    const int row = blockIdx.x * 4 + wv;
    __shared__ int plab[BATCH_N];      // labels in packed order
    for (int idx = t; idx < BATCH_N; idx += 256) {
        const int col = (idx & ~63) + ((idx & 3) << 4) + ((idx >> 2) & 15);
        plab[idx] = labels[col];
    }
    __syncthreads();
    const int myLab = labels[row];
    const uint4* rp = (const uint4*)(S + (size_t)row * BATCH_N);  // 8 bf16 per uint4

    float v[32]; int lb[32];
    #pragma unroll
    for (int kk = 0; kk < 4; kk++) {
        const uint4 u = rp[lane + 64 * kk];
        const unsigned w[4] = {u.x, u.y, u.z, u.w};
        const int base = (lane + 64 * kk) * 8;
        #pragma unroll
        for (int q = 0; q < 4; q++) {
            v[kk * 8 + 2 * q]     = __uint_as_float(w[q] << 16);
            v[kk * 8 + 2 * q + 1] = __uint_as_float(w[q] & 0xFFFF0000u);
            lb[kk * 8 + 2 * q]     = plab[base + 2 * q];
            lb[kk * 8 + 2 * q + 1] = plab[base + 2 * q + 1];
        }
    }

    const float REF = INV_T;
    float sneg = 0.0f;
    #pragma unroll
    for (int k = 0; k < 32; k++) {
        const float ev = __expf(v[k] * INV_T - REF);
        sneg += (lb[k] != myLab) ? ev : 0.0f;
    }
    #pragma unroll
    for (int o = 32; o > 0; o >>= 1) sneg += __shfl_xor(sneg, o);
    const float lseb = (sneg > 0.0f) ? REF + __logf(sneg) : -1e30f;
    const float Lq = lse_queue[row];
    const float mx0 = fmaxf(lseb, Lq), mn0 = fminf(lseb, Lq);
    const float L = mx0 + __logf(1.0f + __expf(mn0 - mx0));

    float part = 0.0f; int cnt = 0;
    #pragma unroll
    for (int k = 0; k < 32; k++) {
        const int idx = ((lane + 64 * (k >> 3)) * 8) + (k & 7);
        const int col = (idx & ~63) + ((idx & 3) << 4) + ((idx >> 2) & 15);
        if (lb[k] == myLab && col != row) {
            const float sv = v[k] * INV_T;
            const float mx = fmaxf(sv, L), mn = fminf(sv, L);
            part += (mx - sv) + __logf(1.0f + __expf(mn - mx));
            cnt++;
        }
    }
    #pragma unroll
    for (int o = 32; o > 0; o >>= 1) { part += __shfl_xor(part, o); cnt += __shfl_xor(cnt, o); }
    if (lane == 0) { part_out[row] = part; cnt_out[row] = cnt; }
}

// reduce 2048 per-row partials -> scalar loss. One block.
__global__ void __launch_bounds__(256) finalize_loss(const float* __restrict__ part,
                                                     const int* __restrict__ cnt,
                                                     float* __restrict__ out) {
    const int t = threadIdx.x;
    float s = 0.0f; int c = 0;
    #pragma unroll
    for (int k = 0; k < 8; k++) { s += part[t + 256 * k]; c += cnt[t + 256 * k]; }
    #pragma unroll
    for (int o = 32; o > 0; o >>= 1) { s += __shfl_xor(s, o); c += __shfl_xor(c, o); }
    __shared__ float sf[4]; __shared__ int sc[4];
    if ((t & 63) == 0) { sf[t >> 6] = s; sc[t >> 6] = c; }
    __syncthreads();
    if (t == 0) {
        const float st = sf[0] + sf[1] + sf[2] + sf[3];
        const int   ct = sc[0] + sc[1] + sc[2] + sc[3];
        out[0] = (ct > 0) ? (st / (float)ct) : 0.0f;
    }
}

// ---------------------------------------------------------------------------
extern "C" void kernel_launch(void* const* d_in, const int* in_sizes, int n_in,
                              void* d_out, int out_size, void* d_ws, size_t ws_size,
                              hipStream_t stream) {
    const float* emb    = (const float*)d_in[0];
    const int*   labels = (const int*)  d_in[1];
    const float* W1     = (const float*)d_in[2];
    const float* b1     = (const float*)d_in[3];
    const float* W2     = (const float*)d_in[4];
    const float* b2     = (const float*)d_in[5];
    const float* queue  = (const float*)d_in[6];
    const int*   qlab   = (const int*)  d_in[7];

    char* ws = (char*)d_ws;
    short*         Sbuf  = (short*)        (ws);              // 8388608 used (region 16 MB kept)
    unsigned char* codes = (unsigned char*)(ws + 16777216);   // 67108864
    short*         embb  = (short*)        (ws + 83886080);   // 3145728
    short*         hbf   = (short*)        (ws + 87031808);   // 3145728
    short*         zb    = (short*)        (ws + 90177536);   // 524288
    short*         qb    = (short*)        (ws + 90701824);   // 8388608
    short*         w1t   = (short*)        (ws + 99090432);   // 1179648
    short*         w2t   = (short*)        (ws + 100270080);  // 196608
    float*         lseq  = (float*)        (ws + 100466688);  // 8192
    int*           flag  = (int*)          (ws + 100474880);  // 8192
    int*           qcnt  = (int*)          (ws + 100483072);  // 64
    float*         partb = (float*)        (ws + 100483136);  // 8192
    int*           cntb  = (int*)          (ws + 100491328);  // 8192

    hipMemsetAsync(ws + 100474880, 0, 8192 + 64, stream);     // flag + qcnt

    dim3 blk(256);
    prep<<<dim3(5832), blk, 0, stream>>>(emb, embb, queue, qb, qlab, qcnt, W1, w1t, W2, w2t);
    mfma_h64<<<dim3(EMB_D_ / 128, BATCH_N / 64), blk, 0, stream>>>(embb, w1t, b1, hbf, EMB_D_, EMB_D_);
    mfma_z_norm64<<<dim3(BATCH_N / 64), blk, 0, stream>>>(hbf, w2t, b2, zb);
    mfma_mask8<<<dim3(QUEUE_N / 512, BATCH_N / 128), blk, 0, stream>>>(zb, qb, codes, labels, qlab);
    topk_lse_u8<<<BATCH_N, blk, 0, stream>>>(codes, qcnt, labels, lseq, flag);
    topk_lse_fallback<<<BATCH_N, blk, 0, stream>>>(zb, qb, labels, qlab, qcnt, flag, lseq);
    mfma_s_pack<<<dim3(BATCH_N / 128, BATCH_N / 128), blk, 0, stream>>>(zb, zb, Sbuf, BATCH_N);
    batch_row_loss<<<BATCH_N / 4, blk, 0, stream>>>(Sbuf, labels, lseq, partb, cntb);
    finalize_loss<<<1, blk, 0, stream>>>(partb, cntb, (float*)d_out);
}